// Round 1
// 516.566 us; speedup vs baseline: 1.0637x; 1.0637x over previous
//
#include <hip/hip_runtime.h>
#include <stdint.h>

typedef unsigned short u16;
typedef unsigned int u32;
typedef __attribute__((ext_vector_type(8))) short short8;
typedef __attribute__((ext_vector_type(4))) float floatx4;
typedef __attribute__((ext_vector_type(4))) unsigned short u16x4;

#define HN 12
#define DH 64
#define DM 768
#define NS 2048
#define NB 8
#define MF 256
#define BN (NB*NS)
#define BH (NB*HN)

#define NRM 0.35355339059327373f  /* 64^-0.25 */
#define RATIO 0.0625f             /* 256^-0.5 */
#define EPSV 1e-4f

__device__ __forceinline__ float b2f(u32 u){ union{u32 i; float f;} x; x.i=u<<16; return x.f; }
__device__ __forceinline__ u32 f2b(float v){ union{float f; u32 u;} x; x.f=v; return (x.u + 0x7FFFu + ((x.u>>16)&1u))>>16; }
__device__ __forceinline__ u32 fkey(float v){ union{float f; u32 u;} x; x.f=v; return (x.u&0x80000000u)? ~x.u : (x.u|0x80000000u); }
__device__ __forceinline__ float funkey(u32 k){ union{u32 u; float f;} x; x.u=(k&0x80000000u)? (k^0x80000000u) : ~k; return x.f; }
__device__ __forceinline__ void bld8(uint4 r, float s, float* f){
  f[0]=b2f(r.x&0xffffu)*s; f[1]=b2f(r.x>>16)*s;
  f[2]=b2f(r.y&0xffffu)*s; f[3]=b2f(r.y>>16)*s;
  f[4]=b2f(r.z&0xffffu)*s; f[5]=b2f(r.z>>16)*s;
  f[6]=b2f(r.w&0xffffu)*s; f[7]=b2f(r.w>>16)*s;
}
__device__ __forceinline__ void load8(const void* base, size_t idx, int isf32, float s, float* f){
  if(isf32){
    const float* p=(const float*)base + idx;
    const float4 u=((const float4*)p)[0], v=((const float4*)p)[1];
    f[0]=u.x*s; f[1]=u.y*s; f[2]=u.z*s; f[3]=u.w*s;
    f[4]=v.x*s; f[5]=v.y*s; f[6]=v.z*s; f[7]=v.w*s;
  }else{
    uint4 r=*(const uint4*)((const u16*)base+idx);
    bld8(r,s,f);
  }
}
__device__ __forceinline__ float ld1(const void* base, int idx, int isf32){
  return isf32 ? ((const float*)base)[idx] : b2f((u32)((const u16*)base)[idx]);
}
// async global->LDS, 16B/lane; l must be wave-uniform, data lands at l + lane*16B
__device__ __forceinline__ void gl16(const void* g, void* l){
  __builtin_amdgcn_global_load_lds(
    (const __attribute__((address_space(1))) u32*)g,
    (__attribute__((address_space(3))) u32*)l, 16, 0, 0);
}

// ---------------- K0: detect input dtype (0=bf16, 1=f32) ---------------------
__global__ __launch_bounds__(64) void k_detect(const u16* __restrict__ x, int* __restrict__ flag)
{
  __shared__ int w[64], z[64];
  const int t=threadIdx.x;
  int wild=0, zero=0;
  for(int i=t;i<256;i+=64){
    u32 u=(u32)x[2*i];
    u32 e=(u>>7)&0xFFu;
    if(e>=0x90u) wild++;
    if((u&0x7FFFu)==0u) zero++;
  }
  w[t]=wild; z[t]=zero; __syncthreads();
  if(t==0){
    int W=0,Z=0;
    for(int i=0;i<64;++i){W+=w[i];Z+=z[i];}
    flag[0]=(W>16||Z>200)?1:0;
  }
}

// ---------------- K0b: convert weights to bf16 (wb=[Wq;Wk;Wv], wob=Wo) ------
__global__ __launch_bounds__(256) void k_cvtw(const void* __restrict__ Wq,
    const void* __restrict__ Wk, const void* __restrict__ Wv, const void* __restrict__ Wo,
    u16* __restrict__ wb, u16* __restrict__ wob, const int* __restrict__ flagp)
{
  const int isf32=*flagp;
  const size_t WSZ=(size_t)DM*DM;
  size_t idx=((size_t)blockIdx.x*256+threadIdx.x)*8;
  const void* src; size_t off; u16* dst;
  if(idx<3*WSZ){ int w=(int)(idx/WSZ); src=(w==0)?Wq:((w==1)?Wk:Wv); off=idx-(size_t)w*WSZ; dst=wb+idx; }
  else { src=Wo; off=idx-3*WSZ; dst=wob+off; }
  if(isf32){
    const float* p=(const float*)src+off;
    float4 u=((const float4*)p)[0], v=((const float4*)p)[1];
    uint4 st;
    st.x=f2b(u.x)|(f2b(u.y)<<16); st.y=f2b(u.z)|(f2b(u.w)<<16);
    st.z=f2b(v.x)|(f2b(v.y)<<16); st.w=f2b(v.z)|(f2b(v.w)<<16);
    *(uint4*)dst=st;
  }else{
    *(uint4*)dst=*(const uint4*)((const u16*)src+off);
  }
}

// ---------------- K0c: pn = proj * NRM, bf16 [256][64] -----------------------
__global__ __launch_bounds__(256) void k_cvtp(const void* __restrict__ proj,
    u16* __restrict__ pn, const int* __restrict__ flagp)
{
  const int isf32=*flagp;
  const size_t idx=((size_t)blockIdx.x*256+threadIdx.x)*8;
  float pf[8];
  load8(proj, idx, isf32, NRM, pf);
  uint4 st;
  st.x=f2b(pf[0])|(f2b(pf[1])<<16); st.y=f2b(pf[2])|(f2b(pf[3])<<16);
  st.z=f2b(pf[4])|(f2b(pf[5])<<16); st.w=f2b(pf[6])|(f2b(pf[7])<<16);
  *(uint4*)(pn+idx)=st;
}

// ---------------- K0e: xb = bf16(x) ------------------------------------------
__global__ __launch_bounds__(256) void k_cvtx(const void* __restrict__ x,
    u16* __restrict__ xb, const int* __restrict__ flagp)
{
  const int isf32=*flagp;
  const size_t idx=((size_t)blockIdx.x*256+threadIdx.x)*8;   // over BN*DM
  float f[8];
  load8(x, idx, isf32, 1.0f, f);
  uint4 st;
  st.x=f2b(f[0])|(f2b(f[1])<<16); st.y=f2b(f[2])|(f2b(f[3])<<16);
  st.z=f2b(f[4])|(f2b(f[5])<<16); st.w=f2b(f[6])|(f2b(f[7])<<16);
  *(uint4*)(xb+idx)=st;
}

// ---------------- K0d: dk[row] = 0.5*NRM^2*sum(v^2) over DH ------------------
__global__ __launch_bounds__(256) void k_diag(const u16* __restrict__ src, float* __restrict__ dk)
{
  const size_t row=(size_t)blockIdx.x*256+threadIdx.x;
  const u16* p=src+row*DH;
  float s=0.f;
#pragma unroll
  for(int c=0;c<DH;c+=8){
    uint4 r=*(const uint4*)(p+c);
    float f[8]; bld8(r,1.0f,f);
#pragma unroll
    for(int j=0;j<8;++j) s+=f[j]*f[j];
  }
  dk[row]=0.5f*NRM*NRM*s;
}

// ======== shared epilogue for the two 128-tile MFMA GEMMs ====================
__device__ __forceinline__ void gemm_epilogue(const floatx4 acc[4][4], int mode, int oflag,
    int m0, int n0, int l, int wr4, int wc4,
    const void* bias0, const void* bias1, const void* bias2,
    u16* q, u16* k, u16* v, void* outv)
{
  const int rbase=(l>>4)*4, cl=l&15;
  if(mode==0){
    const int which=n0/DM;
    const void* bias=(which==0)?bias0:((which==1)?bias1:bias2);
    u16* outp=(which==0)?q:((which==1)?k:v);
    const int cb=n0-which*DM;
#pragma unroll
    for(int j=0;j<4;++j){
      const int col=cb+(wc4+j)*16+cl;
      const int h=col>>6, dd=col&63;
      const float bb=ld1(bias,col,oflag);
#pragma unroll
      for(int i=0;i<4;++i){
#pragma unroll
        for(int r=0;r<4;++r){
          const int grow=m0+(wr4+i)*16+rbase+r;
          const int b_=grow>>11, n=grow&2047;
          const u16 val=(u16)f2b(acc[i][j][r]+bb);
          if(which==2) outp[((size_t)(b_*HN+h)*DH+dd)*NS + n]=val;       // vT [bh][d][n]
          else         outp[((size_t)((b_*HN+h)*NS+n))*DH + dd]=val;     // [bh][n][d]
        }
      }
    }
  }else{
#pragma unroll
    for(int j=0;j<4;++j){
      const int col=n0+(wc4+j)*16+cl;
      const float bb=ld1(bias0,col,oflag);
#pragma unroll
      for(int i=0;i<4;++i){
#pragma unroll
        for(int r=0;r<4;++r){
          const int grow=m0+(wr4+i)*16+rbase+r;
          const float val=acc[i][j][r]+bb;
          if(oflag) ((float*)outv)[(size_t)grow*DM+col]=val;
          else      ((u16*)outv)[(size_t)grow*DM+col]=(u16)f2b(val);
        }
      }
    }
  }
}

// ---------------- K1: MFMA GEMM, 128-tile (fallback output GEMM) -------------
__global__ __launch_bounds__(256) void k_gemm2(const u16* __restrict__ A16,
    const u16* __restrict__ B16,
    const void* __restrict__ bias0, const void* __restrict__ bias1, const void* __restrict__ bias2,
    u16* __restrict__ q, u16* __restrict__ k, u16* __restrict__ v,
    void* __restrict__ outv, const int* __restrict__ flagp, const int mode)
{
  __shared__ short At[16*512];
  __shared__ short Bt[16*512];
  const int oflag=*flagp;
  const int t=threadIdx.x, l=t&63, w=t>>6;
  const int m0=blockIdx.x*128, n0=blockIdx.y*128;
  const int wr4=(w>>1)*4, wc4=(w&1)*4;
  const int srow=l&15, skg=l>>4;
  floatx4 acc[4][4]={};
  for(int k0=0;k0<DM;k0+=64){
    __syncthreads();
#pragma unroll
    for(int s=0;s<4;++s){
      const int bi=w*4+s, rb=bi>>1, kh=bi&1;
      const int kc=k0+kh*32+skg*8;
      gl16(A16 + (size_t)(m0+rb*16+srow)*DM + kc, &At[bi*512]);
      gl16(B16 + (size_t)(n0+rb*16+srow)*DM + kc, &Bt[bi*512]);
    }
    __syncthreads();
#pragma unroll
    for(int kh=0;kh<2;++kh){
      short8 af[4], bf[4];
#pragma unroll
      for(int i=0;i<4;++i) af[i]=*(short8*)&At[((wr4+i)*2+kh)*512+l*8];
#pragma unroll
      for(int j=0;j<4;++j) bf[j]=*(short8*)&Bt[((wc4+j)*2+kh)*512+l*8];
#pragma unroll
      for(int i=0;i<4;++i)
#pragma unroll
        for(int j=0;j<4;++j)
          acc[i][j]=__builtin_amdgcn_mfma_f32_16x16x32_bf16(af[i],bf[j],acc[i][j],0,0,0);
    }
  }
  gemm_epilogue(acc,mode,oflag,m0,n0,l,wr4,wc4,bias0,bias1,bias2,q,k,v,outv);
}

// ---------------- K1f: fallback MFMA GEMM, f32-capable A ---------------------
__global__ __launch_bounds__(256) void k_gemm_f(const void* __restrict__ Araw,
    const u16* __restrict__ B16,
    const void* __restrict__ bias0, const void* __restrict__ bias1, const void* __restrict__ bias2,
    u16* __restrict__ q, u16* __restrict__ k, u16* __restrict__ v,
    void* __restrict__ outv, const int* __restrict__ flagp, const int mode)
{
  __shared__ short At[16*512];
  __shared__ short Bt[16*512];
  const int oflag=*flagp;
  const int isf32=(mode==0)?oflag:0;
  const int t=threadIdx.x, l=t&63, w=t>>6;
  const int m0=blockIdx.x*128, n0=blockIdx.y*128;
  const int wr4=(w>>1)*4, wc4=(w&1)*4;
  const int srow=l&15, skg=l>>4;
  floatx4 acc[4][4]={};
  for(int k0=0;k0<DM;k0+=64){
    __syncthreads();
#pragma unroll
    for(int s=0;s<4;++s){
      const int bi=w*4+s, rb=bi>>1, kh=bi&1;
      const int kc=k0+kh*32+skg*8;
      uint4 va;
      if(isf32){
        const float* ap=(const float*)Araw + (size_t)(m0+rb*16+srow)*DM + kc;
        float4 u=((const float4*)ap)[0], vv=((const float4*)ap)[1];
        va.x=f2b(u.x)|(f2b(u.y)<<16);  va.y=f2b(u.z)|(f2b(u.w)<<16);
        va.z=f2b(vv.x)|(f2b(vv.y)<<16); va.w=f2b(vv.z)|(f2b(vv.w)<<16);
      }else{
        va=*(const uint4*)((const u16*)Araw + (size_t)(m0+rb*16+srow)*DM + kc);
      }
      const uint4 vb=*(const uint4*)(B16 + (size_t)(n0+rb*16+srow)*DM + kc);
      *(uint4*)&At[bi*512+l*8]=va;
      *(uint4*)&Bt[bi*512+l*8]=vb;
    }
    __syncthreads();
#pragma unroll
    for(int kh=0;kh<2;++kh){
      short8 af[4], bf[4];
#pragma unroll
      for(int i=0;i<4;++i) af[i]=*(short8*)&At[((wr4+i)*2+kh)*512+l*8];
#pragma unroll
      for(int j=0;j<4;++j) bf[j]=*(short8*)&Bt[((wc4+j)*2+kh)*512+l*8];
#pragma unroll
      for(int i=0;i<4;++i)
#pragma unroll
        for(int j=0;j<4;++j)
          acc[i][j]=__builtin_amdgcn_mfma_f32_16x16x32_bf16(af[i],bf[j],acc[i][j],0,0,0);
    }
  }
  gemm_epilogue(acc,mode,oflag,m0,n0,l,wr4,wc4,bias0,bias1,bias2,q,k,v,outv);
}

// ================= K1g: 256x256 8-phase pipelined MFMA GEMM ==================
// BM=BN=256, BK=64, 512 threads (8 waves: wr=w>>2, wc=w&3), K=768 (12 tiles).
// LDS: fragment-linear sub-blocks (1KB each, conflict-free linear ds_read),
// 2 tile-slots x 2 kh-halves x 16 sub-blocks for A and B = 128 KiB.
// Staging unit = (A|B, tile, kh) = 16 KB = 2 x global_load_lds(16B) per thread.
// Schedule (iteration computes tiles t=2i, t+1; one unit staged per phase):
//  ph1 A(t+1,k1) ph2 B(t+1,k1) ph3 A(t+2,k0) ph4 B(t+2,k0)
//  ph5 A(t+2,k1) ph6 B(t+2,k1) ph7 A(t+3,k0) ph8 B(t+3,k0)
// Counted waits vmcnt(8) at even phases drain exactly the unit first-used two
// phases later; never 0 until the peeled last iteration (8 -> 4 -> 0 -> none).
#define SBOFF(slot,kh,mf) ((((slot)*32)+((kh)*16)+(mf))*512)
#define STA(kt,kh) do{ \
  const int o_=SBOFF((kt)&1,(kh),0); \
  const size_t g_=(size_t)(kt)*64+(size_t)(kh)*32; \
  gl16(Ar0+g_, &As[o_+w*512]); \
  gl16(Ar0+(size_t)128*768+g_, &As[o_+(8+w)*512]); \
}while(0)
#define STB(kt,kh) do{ \
  const int o_=SBOFF((kt)&1,(kh),0); \
  const size_t g_=(size_t)(kt)*64+(size_t)(kh)*32; \
  gl16(Br0+g_, &Bs[o_+w*512]); \
  gl16(Br0+(size_t)128*768+g_, &Bs[o_+(8+w)*512]); \
}while(0)
#define LDA8(kt,kh) do{ const int o_=SBOFF((kt)&1,(kh),wr*8)+l*8; \
  _Pragma("unroll") for(int i_=0;i_<8;++i_) a[i_]=*(short8*)&As[o_+i_*512]; }while(0)
#define LDB2(kt,kh,np) do{ const int o_=SBOFF((kt)&1,(kh),wc*4+(np)*2)+l*8; \
  b[0]=*(short8*)&Bs[o_]; b[1]=*(short8*)&Bs[o_+512]; }while(0)
#define MM(np) do{ _Pragma("unroll") for(int i_=0;i_<8;++i_){ \
  acc[i_][(np)*2+0]=__builtin_amdgcn_mfma_f32_16x16x32_bf16(a[i_],b[0],acc[i_][(np)*2+0],0,0,0); \
  acc[i_][(np)*2+1]=__builtin_amdgcn_mfma_f32_16x16x32_bf16(a[i_],b[1],acc[i_][(np)*2+1],0,0,0); } }while(0)
#define FEN asm volatile("" ::: "memory")
#define BARR do{ FEN; __builtin_amdgcn_s_barrier(); FEN; }while(0)
#define WV8 asm volatile("s_waitcnt vmcnt(8)" ::: "memory")
#define WV4 asm volatile("s_waitcnt vmcnt(4)" ::: "memory")
#define WV0 asm volatile("s_waitcnt vmcnt(0)" ::: "memory")
#define WL0 do{ asm volatile("s_waitcnt lgkmcnt(0)" ::: "memory"); __builtin_amdgcn_sched_barrier(0); }while(0)
#define PH_O(kt,kh,SST) do{ LDA8(kt,kh); LDB2(kt,kh,0); SST; BARR; WL0; \
  __builtin_amdgcn_s_setprio(1); MM(0); __builtin_amdgcn_s_setprio(0); BARR; }while(0)
#define PH_E(kt,kh,SST,WST) do{ LDB2(kt,kh,1); SST; WST; BARR; WL0; \
  __builtin_amdgcn_s_setprio(1); MM(1); __builtin_amdgcn_s_setprio(0); BARR; }while(0)

__global__ __launch_bounds__(512,2) void k_gemm8(const u16* __restrict__ A16,
    const u16* __restrict__ B16,
    const void* __restrict__ bias0, const void* __restrict__ bias1, const void* __restrict__ bias2,
    u16* __restrict__ q, u16* __restrict__ k, u16* __restrict__ v,
    void* __restrict__ outv, const int* __restrict__ flagp, const int mode)
{
  __shared__ short As[2*2*16*512];   // 64 KiB
  __shared__ short Bs[2*2*16*512];   // 64 KiB
  const int oflag=*flagp;
  const int t=threadIdx.x, l=t&63, w=t>>6;
  const int wr=w>>2, wc=w&3;
  const int lrow=l&15, lk8=(l>>4)*8;
  // bijective XCD-aware swizzle (nwg % 8 == 0 for both launches)
  int bid = blockIdx.y*gridDim.x + blockIdx.x;
  const int nwg = gridDim.x*gridDim.y;
  bid = (bid&7)*(nwg>>3) + (bid>>3);
  const int m0 = (bid&63)*256;       // gridDim.x == 64 for both launches
  const int n0 = (bid>>6)*256;

  const u16* Ar0 = A16 + (size_t)(m0 + w*16 + lrow)*768 + lk8;
  const u16* Br0 = B16 + (size_t)(n0 + w*16 + lrow)*768 + lk8;
  floatx4 acc[8][4]={};
  short8 a[8], b[2];

  // prologue: tile0 (both kh) + tile1 kh0; drain tile0-kh0
  STA(0,0); STB(0,0); STA(0,1); STB(0,1); STA(1,0); STB(1,0);
  WV8; BARR;

  for(int i=0;i<5;++i){
    const int kt=2*i;
    PH_O(kt,0,   STA(kt+1,1));
    PH_E(kt,0,   STB(kt+1,1), WV8);
    PH_O(kt,1,   STA(kt+2,0));
    PH_E(kt,1,   STB(kt+2,0), WV8);
    PH_O(kt+1,0, STA(kt+2,1));
    PH_E(kt+1,0, STB(kt+2,1), WV8);
    PH_O(kt+1,1, STA(kt+3,0));
    PH_E(kt+1,1, STB(kt+3,0), WV8);
  }
  // peeled last iteration (tiles 10,11): no staging beyond tile 11
  PH_O(10,0, STA(11,1));
  PH_E(10,0, STB(11,1), WV8);
  PH_O(10,1, (void)0);
  PH_E(10,1, (void)0, WV4);
  PH_O(11,0, (void)0);
  PH_E(11,0, (void)0, WV0);
  PH_O(11,1, (void)0);
  PH_E(11,1, (void)0, (void)0);

  // ---------------- epilogue ----------------
  const int rb4=(l>>4)*4, cl=l&15;
  const int em0=m0+wr*128, en0=n0+wc*64;
  if(mode==0){
    const int which=en0/DM;
    const int cb0=en0-which*DM;
    const void* bias=(which==0)?bias0:((which==1)?bias1:bias2);
    u16* outp=(which==0)?q:((which==1)?k:v);
#pragma unroll
    for(int j=0;j<4;++j){
      const int col=cb0+j*16+cl;
      const int h=col>>6, dd=col&63;
      const float bb=ld1(bias,col,oflag);
      if(which==2){
#pragma unroll
        for(int i=0;i<8;++i){
          const int g0=em0+i*16+rb4;
          const int b_=g0>>11, n=g0&2047;
          u16x4 st;
#pragma unroll
          for(int r=0;r<4;++r) st[r]=(u16)f2b(acc[i][j][r]+bb);
          *(u16x4*)&outp[((size_t)(b_*HN+h)*DH+dd)*NS + n]=st;   // vT [bh][d][n]
        }
      }else{
#pragma unroll
        for(int i=0;i<8;++i){
#pragma unroll
          for(int r=0;r<4;++r){
            const int g=em0+i*16+rb4+r;
            const int b_=g>>11, n=g&2047;
            outp[((size_t)((b_*HN+h)*NS+n))*DH+dd]=(u16)f2b(acc[i][j][r]+bb);
          }
        }
      }
    }
  }else{
#pragma unroll
    for(int j=0;j<4;++j){
      const int col=en0+j*16+cl;
      const float bb=ld1(bias0,col,oflag);
#pragma unroll
      for(int i=0;i<8;++i){
#pragma unroll
        for(int r=0;r<4;++r){
          const int g=em0+i*16+rb4+r;
          const float val=acc[i][j][r]+bb;
          if(oflag) ((float*)outv)[(size_t)g*DM+col]=val;
          else      ((u16*)outv)[(size_t)g*DM+col]=(u16)f2b(val);
        }
      }
    }
  }
}

// ---------------- K2: MFMA xp_k + global max per bh --------------------------
__global__ __launch_bounds__(256) void k_xpk2(const u16* __restrict__ kb,
    const u16* __restrict__ pn, u32* __restrict__ kmax)
{
  __shared__ short Bt[32*512];
  __shared__ short At[8*512];
  __shared__ float red[256];
  const int t=threadIdx.x, l=t&63, w=t>>6;
  const int bh=blockIdx.y, nb0=blockIdx.x*256;
  for(int s=t;s<2048;s+=256){
    const int ub=s>>6, l2=s&63, mt=ub>>1, kh=ub&1;
    const int row=mt*16+(l2&15), kc=kh*32+(l2>>4)*8;
    *(uint4*)&Bt[ub*512+l2*8]=*(const uint4*)(pn + (size_t)row*DH + kc);
  }
  float vmax=-3.4e38f;
  for(int c=0;c<4;++c){
    const int n0=nb0+c*64;
    __syncthreads();
    for(int s=t;s<512;s+=256){
      const int ua=s>>6, l2=s&63, rb=ua>>1, kh=ua&1;
      const int n=n0+rb*16+(l2&15), kc=kh*32+(l2>>4)*8;
      *(uint4*)&At[ua*512+l2*8]=*(const uint4*)(kb + ((size_t)bh*NS+n)*DH + kc);
    }
    __syncthreads();
    const short8 af0=*(short8*)&At[(w*2+0)*512+l*8];
    const short8 af1=*(short8*)&At[(w*2+1)*512+l*8];
#pragma unroll
    for(int mt=0;mt<16;++mt){
      floatx4 a={};
      a=__builtin_amdgcn_mfma_f32_16x16x32_bf16(af0,*(short8*)&Bt[(mt*2+0)*512+l*8],a,0,0,0);
      a=__builtin_amdgcn_mfma_f32_16x16x32_bf16(af1,*(short8*)&Bt[(mt*2+1)*512+l*8],a,0,0,0);
      vmax=fmaxf(vmax,fmaxf(fmaxf(a[0],a[1]),fmaxf(a[2],a[3])));
    }
  }
  red[t]=vmax; __syncthreads();
  for(int s=128;s>0;s>>=1){ if(t<s) red[t]=fmaxf(red[t],red[t+s]); __syncthreads(); }
  if(t==0) atomicMax(kmax+bh, fkey(red[0]));
}

// ---------------- K3: MFMA fused kp -> ksum + ctx^T --------------------------
__global__ __launch_bounds__(256) void k_ctx2(const u16* __restrict__ kb,
    const u16* __restrict__ vT, const u16* __restrict__ pn,
    const float* __restrict__ dkbuf, const u32* __restrict__ kmax,
    float* __restrict__ ctxT, float* __restrict__ ksum)
{
  __shared__ short Bt[32*512];
  __shared__ u16   Ks[256*72];
  __shared__ short AtV[8*512];
  __shared__ float dg[64];
  const int t=threadIdx.x, l=t&63, w=t>>6;
  const int split=blockIdx.x, bh=blockIdx.y;
  for(int s=t;s<2048;s+=256){
    const int ub=s>>6, l2=s&63, mt=ub>>1, kh=ub&1;
    const int row=mt*16+(l2&15), kc=kh*32+(l2>>4)*8;
    *(uint4*)&Bt[ub*512+l2*8]=*(const uint4*)(pn + (size_t)row*DH + kc);
  }
  const float kM=funkey(kmax[bh]);
  float ksr=0.f;
  floatx4 acc2[4][4]={};
  for(int c=0;c<8;++c){
    const int n0=split*512+c*64;
    __syncthreads();
    for(int s=t;s<512;s+=256){
      const int ua=s>>6, l2=s&63, rb=ua>>1, kh=ua&1;
      const int n=n0+rb*16+(l2&15), kc=kh*32+(l2>>4)*8;
      *(uint4*)&AtV[ua*512+l2*8]=*(const uint4*)(kb + ((size_t)bh*NS+n)*DH + kc);
    }
    if(t<64) dg[t]=dkbuf[(size_t)bh*NS+n0+t];
    __syncthreads();
    short8 af[4][2];
#pragma unroll
    for(int rb=0;rb<4;++rb){
      af[rb][0]=*(short8*)&AtV[(rb*2+0)*512+l*8];
      af[rb][1]=*(short8*)&AtV[(rb*2+1)*512+l*8];
    }
    float dgl[16];
#pragma unroll
    for(int rb=0;rb<4;++rb)
#pragma unroll
      for(int r=0;r<4;++r) dgl[rb*4+r]=dg[rb*16+(l>>4)*4+r];
#pragma unroll
    for(int ml=0;ml<4;++ml){
      const int mt=w*4+ml;
      const short8 bf0=*(short8*)&Bt[(mt*2+0)*512+l*8];
      const short8 bf1=*(short8*)&Bt[(mt*2+1)*512+l*8];
      const int m=mt*16+(l&15);
#pragma unroll
      for(int rb=0;rb<4;++rb){
        floatx4 a={};
        a=__builtin_amdgcn_mfma_f32_16x16x32_bf16(af[rb][0],bf0,a,0,0,0);
        a=__builtin_amdgcn_mfma_f32_16x16x32_bf16(af[rb][1],bf1,a,0,0,0);
        const int nb=rb*16+(l>>4)*4;
        const float v0=RATIO*(__expf(a[0]-dgl[rb*4+0]-kM)+EPSV);
        const float v1=RATIO*(__expf(a[1]-dgl[rb*4+1]-kM)+EPSV);
        const float v2=RATIO*(__expf(a[2]-dgl[rb*4+2]-kM)+EPSV);
        const float v3=RATIO*(__expf(a[3]-dgl[rb*4+3]-kM)+EPSV);
        *(u32*)&Ks[m*72+nb]  =f2b(v0)|(f2b(v1)<<16);
        *(u32*)&Ks[m*72+nb+2]=f2b(v2)|(f2b(v3)<<16);
      }
    }
    __syncthreads();
    for(int s=t;s<512;s+=256){
      const int uv=s>>6, l2=s&63, dt=uv>>1, kh=uv&1;
      const int d=dt*16+(l2&15), nn=n0+kh*32+(l2>>4)*8;
      *(uint4*)&AtV[uv*512+l2*8]=*(const uint4*)(vT + ((size_t)bh*DH+d)*NS + nn);
    }
    {
      float s8=0.f;
#pragma unroll
      for(int j=0;j<8;++j){
        const uint4 kk=*(const uint4*)&Ks[t*72+j*8];
        s8+=b2f(kk.x&0xffffu)+b2f(kk.x>>16)+b2f(kk.y&0xffffu)+b2f(kk.y>>16)
           +b2f(kk.z&0xffffu)+b2f(kk.z>>16)+b2f(kk.w&0xffffu)+b2f(kk.w>>16);
      }
      ksr+=s8;
    }
    __syncthreads();
#pragma unroll
    for(int i=0;i<4;++i){
      const int row=(w*4+i)*16+(l&15);
      const short8 a0=*(short8*)&Ks[row*72 + 0*32+(l>>4)*8];
      const short8 a1=*(short8*)&Ks[row*72 + 1*32+(l>>4)*8];
#pragma unroll
      for(int dt=0;dt<4;++dt){
        acc2[i][dt]=__builtin_amdgcn_mfma_f32_16x16x32_bf16(a0,*(short8*)&AtV[(dt*2+0)*512+l*8],acc2[i][dt],0,0,0);
        acc2[i][dt]=__builtin_amdgcn_mfma_f32_16x16x32_bf16(a1,*(short8*)&AtV[(dt*2+1)*512+l*8],acc2[i][dt],0,0,0);
      }
    }
  }
#pragma unroll
  for(int i=0;i<4;++i){
#pragma unroll
    for(int dt=0;dt<4;++dt){
#pragma unroll
      for(int r=0;r<4;++r){
        const int m=(w*4+i)*16+(l>>4)*4+r;
        const int d=dt*16+(l&15);
        atomicAdd(&ctxT[((size_t)bh*DH+d)*MF+m], acc2[i][dt][r]);
      }
    }
  }
  atomicAdd(ksum+bh*MF+t, ksr);
}

// ---------------- K3b: split ctxT f32 -> hi/lo bf16, ecs=eps*colsum ----------
__global__ __launch_bounds__(256) void k_csplit(const float* __restrict__ ctxT,
    u16* __restrict__ chi, u16* __restrict__ clo, float* __restrict__ ecs)
{
  __shared__ float cred[256];
  const int bh=blockIdx.x, t=threadIdx.x;
  const int d=t>>2, part=t&3;
  const size_t base=((size_t)bh*DH+d)*MF + part*64;
  const float* src=ctxT + base;
  u16* ph=chi + base;
  u16* pl=clo + base;
  float cs=0.f;
  for(int m=0;m<64;m+=4){
    float4 v=*(const float4*)(src+m);
    float vv[4]={v.x,v.y,v.z,v.w};
    u32 h_[4], l_[4];
#pragma unroll
    for(int j=0;j<4;++j){
      cs+=vv[j];
      u32 hh=f2b(vv[j]);
      float rr=vv[j]-b2f(hh);
      h_[j]=hh; l_[j]=f2b(rr);
    }
    uint2 sh, sl;
    sh.x=h_[0]|(h_[1]<<16); sh.y=h_[2]|(h_[3]<<16);
    sl.x=l_[0]|(l_[1]<<16); sl.y=l_[2]|(l_[3]<<16);
    *(uint2*)(ph+m)=sh; *(uint2*)(pl+m)=sl;
  }
  cred[t]=cs; __syncthreads();
  if(part==0) ecs[bh*64+d]=EPSV*(cred[t]+cred[t+1]+cred[t+2]+cred[t+3]);
}

// ---------------- K4: MFMA fused qp + D_inv + attn ---------------------------
__global__ __launch_bounds__(256) void k_attn2(const u16* __restrict__ qb,
    const u16* __restrict__ pn, const float* __restrict__ dqbuf,
    const float* __restrict__ ksum, const u16* __restrict__ chi, const u16* __restrict__ clo,
    const float* __restrict__ ecs, u16* __restrict__ attn)
{
  __shared__ short At[8*512];
  __shared__ u16 Qf[32*512];
  __shared__ float ksums[256];
  __shared__ float dq_s[64];
  __shared__ float mxs[4][64];
  __shared__ float s1s[4][64];
  __shared__ float a_s[64], dinv_s[64], ec_s[64];
  __shared__ float red4[4];
  __shared__ float epkss;
  const int t=threadIdx.x, l=t&63, w=t>>6;
  const int bh=blockIdx.y, nb0=blockIdx.x*256;
  const int b_=bh/HN, h=bh%HN;
  {
    float kv=ksum[bh*MF+t];
    ksums[t]=kv;
    if(t<64) ec_s[t]=ecs[bh*64+t];
    float s=kv;
#pragma unroll
    for(int o=1;o<64;o<<=1) s+=__shfl_xor(s,o,64);
    if(l==0) red4[w]=s;
  }
  __syncthreads();
  if(t==0) epkss=EPSV*(red4[0]+red4[1]+red4[2]+red4[3]);
  short8 bhf[8], blf[8];
  {
    const int d=w*16+(l&15);
    const size_t base=((size_t)bh*DH+d)*MF;
#pragma unroll
    for(int kc=0;kc<8;++kc){
      const size_t off=base + kc*32+(l>>4)*8;
      bhf[kc]=*(const short8*)(chi+off);
      blf[kc]=*(const short8*)(clo+off);
    }
  }
  for(int c=0;c<4;++c){
    const int n0c=nb0+c*64;
    __syncthreads();
    for(int s=t;s<512;s+=256){
      const int ua=s>>6, l2=s&63, nt=ua>>1, kh=ua&1;
      const int n=n0c+nt*16+(l2&15), kc=kh*32+(l2>>4)*8;
      *(uint4*)&At[ua*512+l2*8]=*(const uint4*)(qb + ((size_t)bh*NS+n)*DH + kc);
    }
    if(t<64) dq_s[t]=dqbuf[(size_t)bh*NS+n0c+t];
    __syncthreads();
    float mxl[4]={-3.4e38f,-3.4e38f,-3.4e38f,-3.4e38f};
    float s1l[4]={0.f,0.f,0.f,0.f};
#pragma unroll
    for(int mt=0;mt<4;++mt){
      const int gm=w*4+mt;
      const u16* pr=pn + ((gm*16+(l&15))<<6) + (l>>4)*8;
      const short8 a0=*(const short8*)(pr);
      const short8 a1=*(const short8*)(pr+32);
      float k4[4];
#pragma unroll
      for(int r=0;r<4;++r) k4[r]=ksums[gm*16+(l>>4)*4+r];
      const int mbase=(gm&1)*16+(l>>4)*4;
      const int lane2=((mbase>>3)*16+(l&15))*8 + (mbase&7);
#pragma unroll
      for(int nt=0;nt<4;++nt){
        floatx4 xp={};
        xp=__builtin_amdgcn_mfma_f32_16x16x32_bf16(a0,*(short8*)&At[(nt*2+0)*512+l*8],xp,0,0,0);
        xp=__builtin_amdgcn_mfma_f32_16x16x32_bf16(a1,*(short8*)&At[(nt*2+1)*512+l*8],xp,0,0,0);
        const float dq=dq_s[nt*16+(l&15)];
        float ev[4];
#pragma unroll
        for(int r=0;r<4;++r){
          const float xv=xp[r];
          mxl[nt]=fmaxf(mxl[nt],xv);
          ev[r]=__expf(xv-dq);
          s1l[nt]+=ev[r]*k4[r];
        }
        u16* qp_=&Qf[(nt*8+(gm>>1))*512 + lane2];
        *(u32*)qp_    =f2b(ev[0])|(f2b(ev[1])<<16);
        *(u32*)(qp_+2)=f2b(ev[2])|(f2b(ev[3])<<16);
      }
    }
#pragma unroll
    for(int nt=0;nt<4;++nt){
      float m_=mxl[nt], s_=s1l[nt];
      m_=fmaxf(m_,__shfl_xor(m_,16,64)); s_+=__shfl_xor(s_,16,64);
      m_=fmaxf(m_,__shfl_xor(m_,32,64)); s_+=__shfl_xor(s_,32,64);
      if(l<16){ mxs[w][nt*16+l]=m_; s1s[w][nt*16+l]=s_; }
    }
    __syncthreads();
    if(t<64){
      float m_=fmaxf(fmaxf(mxs[0][t],mxs[1][t]),fmaxf(mxs[2][t],mxs[3][t]));
      float s_=s1s[0][t]+s1s[1][t]+s1s[2][t]+s1s[3][t];
      float a=__expf(-m_);
      a_s[t]=a;
      dinv_s[t]=1.0f/(a*s_+epkss);
    }
    __syncthreads();
    const int d=w*16+(l&15);
    const float ec=ec_s[d];
#pragma unroll
    for(int nt=0;nt<4;++nt){
      floatx4 y={};
#pragma unroll
      for(int kc=0;kc<8;++kc){
        const short8 e=*(short8*)&Qf[(nt*8+kc)*512+l*8];
        y=__builtin_amdgcn_mfma_f32_16x16x32_bf16(e,bhf[kc],y,0,0,0);
        y=__builtin_amdgcn_mfma_f32_16x16x32_bf16(e,blf[kc],y,0,0,0);
      }
#pragma unroll
      for(int r=0;r<4;++r){
        const int nl=nt*16+(l>>4)*4+r;
        const float val=(a_s[nl]*y[r]+ec)*dinv_s[nl];
        attn[((size_t)(b_*NS+n0c+nl))*DM + h*DH + d]=(u16)f2b(val);
      }
    }
  }
}

extern "C" void kernel_launch(void* const* d_in, const int* in_sizes, int n_in,
                              void* d_out, int out_size, void* d_ws, size_t ws_size,
                              hipStream_t stream)
{
  (void)in_sizes; (void)n_in; (void)out_size;
  const void* x =d_in[0];
  const void* Wq=d_in[1]; const void* bq=d_in[2];
  const void* Wk=d_in[3]; const void* bk=d_in[4];
  const void* Wv=d_in[5]; const void* bv=d_in[6];
  const void* Wo=d_in[7]; const void* bo=d_in[8];
  const void* proj=d_in[9];

  char* ws=(char*)d_ws;
  const size_t SZ=(size_t)BN*DM*2;               // 25,165,824 B
  const size_t AUXSZ=19030528;
  const bool big = ws_size >= 4*SZ + AUXSZ;      // ~119.7 MB
  u16*   qb  =(u16*)(ws);
  u16*   kb  =(u16*)(ws+SZ);
  u16*   vb  =(u16*)(ws+2*SZ);                   // v^T [bh][d][n]
  u16*   xb  =(u16*)(ws+3*SZ);                   // bf16 x (big path only)
  char*  aux = big ? (ws+4*SZ) : (ws+3*SZ);
  u16*   wb   =(u16*)(aux);                      // 3,538,944
  u16*   wob  =(u16*)(aux+3538944);              // -> 4,718,592
  float* ctxT =(float*)(aux+4718592);            // -> 11,010,048
  float* ksum =(float*)(aux+11010048);           // -> 11,108,352
  u32*   kmax =(u32*)(aux+11108352);             // -> 11,108,736
  int*   flag =(int*)(aux+11108736);             // -> 11,108,864
  float* dk   =(float*)(aux+11108864);           // -> 11,895,296
  float* dqq  =(float*)(aux+11895296);           // -> 12,681,728
  u16*   pn   =(u16*)(aux+12681728);             // -> 12,714,496
  u16*   chi  =(u16*)(aux+12714496);             // -> 15,860,224
  u16*   clo  =(u16*)(aux+15860224);             // -> 19,005,952
  float* ecs  =(float*)(aux+19005952);           // -> 19,030,528
  u16*   attnb = big ? xb : kb;                  // dead buffer reuse

  k_detect<<<1,64,0,stream>>>((const u16*)x, flag);
  hipMemsetAsync(ctxT, 0, 6291456+98304+384, stream);
  k_cvtw <<<1152, 256, 0, stream>>>(Wq,Wk,Wv,Wo,wb,wob,flag);
  k_cvtp <<<8, 256, 0, stream>>>(proj, pn, flag);
  if(big){
    k_cvtx <<<(BN*DM)/2048, 256, 0, stream>>>(x, xb, flag);
    k_gemm8<<<dim3(BN/256,2304/256), 512, 0, stream>>>(xb, wb, bq,bk,bv, qb,kb,vb, nullptr, flag, 0);
  }else{
    k_gemm_f<<<dim3(BN/128,2304/128), 256, 0, stream>>>(x, wb, bq,bk,bv, qb,kb,vb, nullptr, flag, 0);
  }
  k_diag <<<(BH*NS)/256, 256, 0, stream>>>(kb, dk);
  k_diag <<<(BH*NS)/256, 256, 0, stream>>>(qb, dqq);
  k_xpk2 <<<dim3(NS/256,BH), 256, 0, stream>>>(kb, pn, kmax);
  k_ctx2 <<<dim3(4,BH), 256, 0, stream>>>(kb, vb, pn, dk, kmax, ctxT, ksum);
  k_csplit<<<BH, 256, 0, stream>>>(ctxT, chi, clo, ecs);
  k_attn2<<<dim3(NS/256,BH), 256, 0, stream>>>(qb, pn, dqq, ksum, chi, clo, ecs, attnb);
  if(big){
    k_gemm8<<<dim3(BN/256,DM/256), 512, 0, stream>>>(attnb, wob, bo,bo,bo, nullptr,nullptr,nullptr, d_out, flag, 1);
  }else{
    k_gemm2<<<dim3(BN/128,DM/128), 256, 0, stream>>>(attnb, wob, bo,bo,bo, nullptr,nullptr,nullptr, d_out, flag, 1);
  }
}

// Round 2
// 489.924 us; speedup vs baseline: 1.1215x; 1.0544x over previous
//
#include <hip/hip_runtime.h>
#include <stdint.h>

typedef unsigned short u16;
typedef unsigned int u32;
typedef __attribute__((ext_vector_type(8))) short short8;
typedef __attribute__((ext_vector_type(4))) float floatx4;

#define HN 12
#define DH 64
#define DM 768
#define NS 2048
#define NB 8
#define MF 256
#define BN (NB*NS)
#define BH (NB*HN)

#define NRM 0.35355339059327373f  /* 64^-0.25 */
#define RATIO 0.0625f             /* 256^-0.5 */
#define EPSV 1e-4f

__device__ __forceinline__ float b2f(u32 u){ union{u32 i; float f;} x; x.i=u<<16; return x.f; }
__device__ __forceinline__ u32 f2b(float v){ union{float f; u32 u;} x; x.f=v; return (x.u + 0x7FFFu + ((x.u>>16)&1u))>>16; }
__device__ __forceinline__ u32 fkey(float v){ union{float f; u32 u;} x; x.f=v; return (x.u&0x80000000u)? ~x.u : (x.u|0x80000000u); }
__device__ __forceinline__ float funkey(u32 k){ union{u32 u; float f;} x; x.u=(k&0x80000000u)? (k^0x80000000u) : ~k; return x.f; }
__device__ __forceinline__ void bld8(uint4 r, float s, float* f){
  f[0]=b2f(r.x&0xffffu)*s; f[1]=b2f(r.x>>16)*s;
  f[2]=b2f(r.y&0xffffu)*s; f[3]=b2f(r.y>>16)*s;
  f[4]=b2f(r.z&0xffffu)*s; f[5]=b2f(r.z>>16)*s;
  f[6]=b2f(r.w&0xffffu)*s; f[7]=b2f(r.w>>16)*s;
}
__device__ __forceinline__ void load8(const void* base, size_t idx, int isf32, float s, float* f){
  if(isf32){
    const float* p=(const float*)base + idx;
    const float4 u=((const float4*)p)[0], v=((const float4*)p)[1];
    f[0]=u.x*s; f[1]=u.y*s; f[2]=u.z*s; f[3]=u.w*s;
    f[4]=v.x*s; f[5]=v.y*s; f[6]=v.z*s; f[7]=v.w*s;
  }else{
    uint4 r=*(const uint4*)((const u16*)base+idx);
    bld8(r,s,f);
  }
}
__device__ __forceinline__ float ld1(const void* base, int idx, int isf32){
  return isf32 ? ((const float*)base)[idx] : b2f((u32)((const u16*)base)[idx]);
}
// async global->LDS, 16B/lane; l must be wave-uniform, data lands at l + lane*16B
__device__ __forceinline__ void gl16(const void* g, void* l){
  __builtin_amdgcn_global_load_lds(
    (const __attribute__((address_space(1))) u32*)g,
    (__attribute__((address_space(3))) u32*)l, 16, 0, 0);
}

// ---------------- K0: detect input dtype (0=bf16, 1=f32) ---------------------
__global__ __launch_bounds__(64) void k_detect(const u16* __restrict__ x, int* __restrict__ flag)
{
  __shared__ int w[64], z[64];
  const int t=threadIdx.x;
  int wild=0, zero=0;
  for(int i=t;i<256;i+=64){
    u32 u=(u32)x[2*i];
    u32 e=(u>>7)&0xFFu;
    if(e>=0x90u) wild++;
    if((u&0x7FFFu)==0u) zero++;
  }
  w[t]=wild; z[t]=zero; __syncthreads();
  if(t==0){
    int W=0,Z=0;
    for(int i=0;i<64;++i){W+=w[i];Z+=z[i];}
    flag[0]=(W>16||Z>200)?1:0;
  }
}

// ---------------- K0b: convert weights to bf16 (wb=[Wq;Wk;Wv], wob=Wo) ------
__global__ __launch_bounds__(256) void k_cvtw(const void* __restrict__ Wq,
    const void* __restrict__ Wk, const void* __restrict__ Wv, const void* __restrict__ Wo,
    u16* __restrict__ wb, u16* __restrict__ wob, const int* __restrict__ flagp)
{
  const int isf32=*flagp;
  const size_t WSZ=(size_t)DM*DM;
  size_t idx=((size_t)blockIdx.x*256+threadIdx.x)*8;
  const void* src; size_t off; u16* dst;
  if(idx<3*WSZ){ int w=(int)(idx/WSZ); src=(w==0)?Wq:((w==1)?Wk:Wv); off=idx-(size_t)w*WSZ; dst=wb+idx; }
  else { src=Wo; off=idx-3*WSZ; dst=wob+off; }
  if(isf32){
    const float* p=(const float*)src+off;
    float4 u=((const float4*)p)[0], v=((const float4*)p)[1];
    uint4 st;
    st.x=f2b(u.x)|(f2b(u.y)<<16); st.y=f2b(u.z)|(f2b(u.w)<<16);
    st.z=f2b(v.x)|(f2b(v.y)<<16); st.w=f2b(v.z)|(f2b(v.w)<<16);
    *(uint4*)dst=st;
  }else{
    *(uint4*)dst=*(const uint4*)((const u16*)src+off);
  }
}

// ---------------- K0c: pn = proj * NRM, bf16 [256][64] -----------------------
__global__ __launch_bounds__(256) void k_cvtp(const void* __restrict__ proj,
    u16* __restrict__ pn, const int* __restrict__ flagp)
{
  const int isf32=*flagp;
  const size_t idx=((size_t)blockIdx.x*256+threadIdx.x)*8;
  float pf[8];
  load8(proj, idx, isf32, NRM, pf);
  uint4 st;
  st.x=f2b(pf[0])|(f2b(pf[1])<<16); st.y=f2b(pf[2])|(f2b(pf[3])<<16);
  st.z=f2b(pf[4])|(f2b(pf[5])<<16); st.w=f2b(pf[6])|(f2b(pf[7])<<16);
  *(uint4*)(pn+idx)=st;
}

// ---------------- K0e: xb = bf16(x) ------------------------------------------
__global__ __launch_bounds__(256) void k_cvtx(const void* __restrict__ x,
    u16* __restrict__ xb, const int* __restrict__ flagp)
{
  const int isf32=*flagp;
  const size_t idx=((size_t)blockIdx.x*256+threadIdx.x)*8;   // over BN*DM
  float f[8];
  load8(x, idx, isf32, 1.0f, f);
  uint4 st;
  st.x=f2b(f[0])|(f2b(f[1])<<16); st.y=f2b(f[2])|(f2b(f[3])<<16);
  st.z=f2b(f[4])|(f2b(f[5])<<16); st.w=f2b(f[6])|(f2b(f[7])<<16);
  *(uint4*)(xb+idx)=st;
}

// ---------------- K0d: dk[row] = 0.5*NRM^2*sum(v^2) over DH (fallback path) --
__global__ __launch_bounds__(256) void k_diag(const u16* __restrict__ src, float* __restrict__ dk)
{
  const size_t row=(size_t)blockIdx.x*256+threadIdx.x;
  const u16* p=src+row*DH;
  float s=0.f;
#pragma unroll
  for(int c=0;c<DH;c+=8){
    uint4 r=*(const uint4*)(p+c);
    float f[8]; bld8(r,1.0f,f);
#pragma unroll
    for(int j=0;j<8;++j) s+=f[j]*f[j];
  }
  dk[row]=0.5f*NRM*NRM*s;
}

// ======== shared epilogue for the two 128-tile fallback MFMA GEMMs ===========
__device__ __forceinline__ void gemm_epilogue(const floatx4 acc[4][4], int mode, int oflag,
    int m0, int n0, int l, int wr4, int wc4,
    const void* bias0, const void* bias1, const void* bias2,
    u16* q, u16* k, u16* v, void* outv)
{
  const int rbase=(l>>4)*4, cl=l&15;
  if(mode==0){
    const int which=n0/DM;
    const void* bias=(which==0)?bias0:((which==1)?bias1:bias2);
    u16* outp=(which==0)?q:((which==1)?k:v);
    const int cb=n0-which*DM;
#pragma unroll
    for(int j=0;j<4;++j){
      const int col=cb+(wc4+j)*16+cl;
      const int h=col>>6, dd=col&63;
      const float bb=ld1(bias,col,oflag);
#pragma unroll
      for(int i=0;i<4;++i){
#pragma unroll
        for(int r=0;r<4;++r){
          const int grow=m0+(wr4+i)*16+rbase+r;
          const int b_=grow>>11, n=grow&2047;
          const u16 val=(u16)f2b(acc[i][j][r]+bb);
          if(which==2) outp[((size_t)(b_*HN+h)*DH+dd)*NS + n]=val;       // vT [bh][d][n]
          else         outp[((size_t)((b_*HN+h)*NS+n))*DH + dd]=val;     // [bh][n][d]
        }
      }
    }
  }else{
#pragma unroll
    for(int j=0;j<4;++j){
      const int col=n0+(wc4+j)*16+cl;
      const float bb=ld1(bias0,col,oflag);
#pragma unroll
      for(int i=0;i<4;++i){
#pragma unroll
        for(int r=0;r<4;++r){
          const int grow=m0+(wr4+i)*16+rbase+r;
          const float val=acc[i][j][r]+bb;
          if(oflag) ((float*)outv)[(size_t)grow*DM+col]=val;
          else      ((u16*)outv)[(size_t)grow*DM+col]=(u16)f2b(val);
        }
      }
    }
  }
}

// ---------------- K1: MFMA GEMM, 128-tile (fallback) -------------------------
__global__ __launch_bounds__(256) void k_gemm2(const u16* __restrict__ A16,
    const u16* __restrict__ B16,
    const void* __restrict__ bias0, const void* __restrict__ bias1, const void* __restrict__ bias2,
    u16* __restrict__ q, u16* __restrict__ k, u16* __restrict__ v,
    void* __restrict__ outv, const int* __restrict__ flagp, const int mode)
{
  __shared__ short At[16*512];
  __shared__ short Bt[16*512];
  const int oflag=*flagp;
  const int t=threadIdx.x, l=t&63, w=t>>6;
  const int m0=blockIdx.x*128, n0=blockIdx.y*128;
  const int wr4=(w>>1)*4, wc4=(w&1)*4;
  const int srow=l&15, skg=l>>4;
  floatx4 acc[4][4]={};
  for(int k0=0;k0<DM;k0+=64){
    __syncthreads();
#pragma unroll
    for(int s=0;s<4;++s){
      const int bi=w*4+s, rb=bi>>1, kh=bi&1;
      const int kc=k0+kh*32+skg*8;
      gl16(A16 + (size_t)(m0+rb*16+srow)*DM + kc, &At[bi*512]);
      gl16(B16 + (size_t)(n0+rb*16+srow)*DM + kc, &Bt[bi*512]);
    }
    __syncthreads();
#pragma unroll
    for(int kh=0;kh<2;++kh){
      short8 af[4], bf[4];
#pragma unroll
      for(int i=0;i<4;++i) af[i]=*(short8*)&At[((wr4+i)*2+kh)*512+l*8];
#pragma unroll
      for(int j=0;j<4;++j) bf[j]=*(short8*)&Bt[((wc4+j)*2+kh)*512+l*8];
#pragma unroll
      for(int i=0;i<4;++i)
#pragma unroll
        for(int j=0;j<4;++j)
          acc[i][j]=__builtin_amdgcn_mfma_f32_16x16x32_bf16(af[i],bf[j],acc[i][j],0,0,0);
    }
  }
  gemm_epilogue(acc,mode,oflag,m0,n0,l,wr4,wc4,bias0,bias1,bias2,q,k,v,outv);
}

// ---------------- K1f: fallback MFMA GEMM, f32-capable A ---------------------
__global__ __launch_bounds__(256) void k_gemm_f(const void* __restrict__ Araw,
    const u16* __restrict__ B16,
    const void* __restrict__ bias0, const void* __restrict__ bias1, const void* __restrict__ bias2,
    u16* __restrict__ q, u16* __restrict__ k, u16* __restrict__ v,
    void* __restrict__ outv, const int* __restrict__ flagp, const int mode)
{
  __shared__ short At[16*512];
  __shared__ short Bt[16*512];
  const int oflag=*flagp;
  const int isf32=(mode==0)?oflag:0;
  const int t=threadIdx.x, l=t&63, w=t>>6;
  const int m0=blockIdx.x*128, n0=blockIdx.y*128;
  const int wr4=(w>>1)*4, wc4=(w&1)*4;
  const int srow=l&15, skg=l>>4;
  floatx4 acc[4][4]={};
  for(int k0=0;k0<DM;k0+=64){
    __syncthreads();
#pragma unroll
    for(int s=0;s<4;++s){
      const int bi=w*4+s, rb=bi>>1, kh=bi&1;
      const int kc=k0+kh*32+skg*8;
      uint4 va;
      if(isf32){
        const float* ap=(const float*)Araw + (size_t)(m0+rb*16+srow)*DM + kc;
        float4 u=((const float4*)ap)[0], vv=((const float4*)ap)[1];
        va.x=f2b(u.x)|(f2b(u.y)<<16);  va.y=f2b(u.z)|(f2b(u.w)<<16);
        va.z=f2b(vv.x)|(f2b(vv.y)<<16); va.w=f2b(vv.z)|(f2b(vv.w)<<16);
      }else{
        va=*(const uint4*)((const u16*)Araw + (size_t)(m0+rb*16+srow)*DM + kc);
      }
      const uint4 vb=*(const uint4*)(B16 + (size_t)(n0+rb*16+srow)*DM + kc);
      *(uint4*)&At[bi*512+l*8]=va;
      *(uint4*)&Bt[bi*512+l*8]=vb;
    }
    __syncthreads();
#pragma unroll
    for(int kh=0;kh<2;++kh){
      short8 af[4], bf[4];
#pragma unroll
      for(int i=0;i<4;++i) af[i]=*(short8*)&At[((wr4+i)*2+kh)*512+l*8];
#pragma unroll
      for(int j=0;j<4;++j) bf[j]=*(short8*)&Bt[((wc4+j)*2+kh)*512+l*8];
#pragma unroll
      for(int i=0;i<4;++i)
#pragma unroll
        for(int j=0;j<4;++j)
          acc[i][j]=__builtin_amdgcn_mfma_f32_16x16x32_bf16(af[i],bf[j],acc[i][j],0,0,0);
    }
  }
  gemm_epilogue(acc,mode,oflag,m0,n0,l,wr4,wc4,bias0,bias1,bias2,q,k,v,outv);
}

// ================= K1g: 256x256 8-phase pipelined MFMA GEMM ==================
// Schedule identical to round-1 (verified). New: n-fast XCD chunk mapping
// (A-panel + B working set become L2-resident per XCD) and LDS-restaged
// coalesced epilogue with fused diag computation.
#define SBOFF(slot,kh,mf) ((((slot)*32)+((kh)*16)+(mf))*512)
#define STA(kt,kh) do{ \
  const int o_=SBOFF((kt)&1,(kh),0); \
  const size_t g_=(size_t)(kt)*64+(size_t)(kh)*32; \
  gl16(Ar0+g_, &As[o_+w*512]); \
  gl16(Ar0+(size_t)128*768+g_, &As[o_+(8+w)*512]); \
}while(0)
#define STB(kt,kh) do{ \
  const int o_=SBOFF((kt)&1,(kh),0); \
  const size_t g_=(size_t)(kt)*64+(size_t)(kh)*32; \
  gl16(Br0+g_, &Bs[o_+w*512]); \
  gl16(Br0+(size_t)128*768+g_, &Bs[o_+(8+w)*512]); \
}while(0)
#define LDA8(kt,kh) do{ const int o_=SBOFF((kt)&1,(kh),wr*8)+l*8; \
  _Pragma("unroll") for(int i_=0;i_<8;++i_) a[i_]=*(short8*)&As[o_+i_*512]; }while(0)
#define LDB2(kt,kh,np) do{ const int o_=SBOFF((kt)&1,(kh),wc*4+(np)*2)+l*8; \
  b[0]=*(short8*)&Bs[o_]; b[1]=*(short8*)&Bs[o_+512]; }while(0)
#define MM(np) do{ _Pragma("unroll") for(int i_=0;i_<8;++i_){ \
  acc[i_][(np)*2+0]=__builtin_amdgcn_mfma_f32_16x16x32_bf16(a[i_],b[0],acc[i_][(np)*2+0],0,0,0); \
  acc[i_][(np)*2+1]=__builtin_amdgcn_mfma_f32_16x16x32_bf16(a[i_],b[1],acc[i_][(np)*2+1],0,0,0); } }while(0)
#define FEN asm volatile("" ::: "memory")
#define BARR do{ FEN; __builtin_amdgcn_s_barrier(); FEN; }while(0)
#define WV8 asm volatile("s_waitcnt vmcnt(8)" ::: "memory")
#define WV4 asm volatile("s_waitcnt vmcnt(4)" ::: "memory")
#define WV0 asm volatile("s_waitcnt vmcnt(0)" ::: "memory")
#define WL0 do{ asm volatile("s_waitcnt lgkmcnt(0)" ::: "memory"); __builtin_amdgcn_sched_barrier(0); }while(0)
#define PH_O(kt,kh,SST) do{ LDA8(kt,kh); LDB2(kt,kh,0); SST; BARR; WL0; \
  __builtin_amdgcn_s_setprio(1); MM(0); __builtin_amdgcn_s_setprio(0); BARR; }while(0)
#define PH_E(kt,kh,SST,WST) do{ LDB2(kt,kh,1); SST; WST; BARR; WL0; \
  __builtin_amdgcn_s_setprio(1); MM(1); __builtin_amdgcn_s_setprio(0); BARR; }while(0)

__global__ __launch_bounds__(512,2) void k_gemm8(const u16* __restrict__ A16,
    const u16* __restrict__ B16,
    const void* __restrict__ bias0, const void* __restrict__ bias1, const void* __restrict__ bias2,
    u16* __restrict__ q, u16* __restrict__ k, u16* __restrict__ v,
    void* __restrict__ outv, const int* __restrict__ flagp, const int mode,
    float* __restrict__ dq_, float* __restrict__ dk_)
{
  __shared__ short As[2*2*16*512];   // 64 KiB
  __shared__ short Bs[2*2*16*512];   // 64 KiB
  const int oflag=*flagp;
  const int t=threadIdx.x, l=t&63, w=t>>6;
  const int wr=w>>2, wc=w&3;
  const int lrow=l&15, lk8=(l>>4)*8;
  // XCD-aware swizzle, n-FAST within each XCD chunk: the nN n-blocks sharing
  // one A-panel co-run on one XCD -> A panel + B working set are L2-resident.
  int bid = blockIdx.y*gridDim.x + blockIdx.x;
  const int nwg = gridDim.x*gridDim.y;       // 576 (mode0) / 192 (mode1), %8==0
  const int nN  = gridDim.y;                 // 9 / 3
  bid = (bid&7)*(nwg>>3) + (bid>>3);
  const int mi = bid/nN;
  const int m0 = mi*256;
  const int n0 = (bid - mi*nN)*256;

  const u16* Ar0 = A16 + (size_t)(m0 + w*16 + lrow)*768 + lk8;
  const u16* Br0 = B16 + (size_t)(n0 + w*16 + lrow)*768 + lk8;
  floatx4 acc[8][4]={};
  short8 a[8], b[2];

  // prologue: tile0 (both kh) + tile1 kh0; drain tile0-kh0
  STA(0,0); STB(0,0); STA(0,1); STB(0,1); STA(1,0); STB(1,0);
  WV8; BARR;

  for(int i=0;i<5;++i){
    const int kt=2*i;
    PH_O(kt,0,   STA(kt+1,1));
    PH_E(kt,0,   STB(kt+1,1), WV8);
    PH_O(kt,1,   STA(kt+2,0));
    PH_E(kt,1,   STB(kt+2,0), WV8);
    PH_O(kt+1,0, STA(kt+2,1));
    PH_E(kt+1,0, STB(kt+2,1), WV8);
    PH_O(kt+1,1, STA(kt+3,0));
    PH_E(kt+1,1, STB(kt+3,0), WV8);
  }
  // peeled last iteration (tiles 10,11)
  PH_O(10,0, STA(11,1));
  PH_E(10,0, STB(11,1), WV8);
  PH_O(10,1, (void)0);
  PH_E(10,1, (void)0, WV4);
  PH_O(11,0, (void)0);
  PH_E(11,0, (void)0, WV0);
  PH_O(11,1, (void)0);
  PH_E(11,1, (void)0, (void)0);

  // ============ epilogue: LDS restage -> coalesced wide stores ===============
  // As/Bs (128 KiB) are free after the final barrier above.
  const int cl=l&15, q4=l>>4;
  if(mode==0){
    const int which=n0/DM;
    const int cb0=n0-which*DM;
    const void* bias=(which==0)?bias0:((which==1)?bias1:bias2);
    u16* outp=(which==0)?q:((which==1)?k:v);
    if(which==2){
      // ---- v: col-major restage [col][row], XOR swizzle by (col&7)<<4 ----
#pragma unroll
      for(int j=0;j<4;++j){
        const int col=wc*64+j*16+cl;
        const float bb=ld1(bias,cb0+col,oflag);
        char* cbase=(char*)((col<128)? (void*)(As+col*256) : (void*)(Bs+(col-128)*256));
        const int X=(col&7)<<4;
#pragma unroll
        for(int i=0;i<8;++i){
          const int rowb=wr*128+i*16+q4*4;
          uint2 pk;
          pk.x=f2b(acc[i][j][0]+bb)|(f2b(acc[i][j][1]+bb)<<16);
          pk.y=f2b(acc[i][j][2]+bb)|(f2b(acc[i][j][3]+bb)<<16);
          *(uint2*)(cbase + ((rowb*2)^X)) = pk;
        }
      }
      __syncthreads();
      const int b_=m0>>11, nbase=m0&2047;
#pragma unroll
      for(int tt=0;tt<16;++tt){
        const int task=tt*8+w;               // 128 tasks: 32 colgroups x 4 row-quarters
        const int colg=task>>2, qq=task&3;
        const int col=colg*8+(l>>3), sub=l&7;
        char* cbase=(char*)((col<128)? (void*)(As+col*256) : (void*)(Bs+(col-128)*256));
        const uint4 d4=*(const uint4*)(cbase + ((qq*128+sub*16)^((col&7)<<4)));
        const int gcol=cb0+col, h=gcol>>6, dd=gcol&63;
        const int n=nbase+qq*64+sub*8;
        *(uint4*)&outp[((size_t)(b_*HN+h)*DH+dd)*NS + n]=d4;   // vT [bh][d][n]
      }
    } else {
      // ---- q/k: row-major restage [row][col], XOR by (row&3)<<4; fused diag ----
      float bb4[4];
#pragma unroll
      for(int j=0;j<4;++j) bb4[j]=ld1(bias, cb0+wc*64+j*16+cl, oflag);
      float* dptr=(which==0)? dq_ : dk_;
#pragma unroll
      for(int i=0;i<8;++i){
#pragma unroll
        for(int r=0;r<4;++r){
          const int row=wr*128+i*16+q4*4+r;
          char* rbase=(char*)((row<128)? (void*)(As+row*256) : (void*)(Bs+(row-128)*256));
          const int X=(row&3)<<4;
          float s=0.f;
#pragma unroll
          for(int j=0;j<4;++j){
            const int col=wc*64+j*16+cl;
            const u16 hv=(u16)f2b(acc[i][j][r]+bb4[j]);
            *(u16*)(rbase + ((col*2)^X)) = hv;
            const float fv=b2f(hv);
            s+=fv*fv;
          }
          // head-wide (64 cols = 16 lanes x 4 j) sum of squares -> diag
          s+=__shfl_xor(s,1,64); s+=__shfl_xor(s,2,64);
          s+=__shfl_xor(s,4,64); s+=__shfl_xor(s,8,64);
          if(cl==0){
            const int grow=m0+row, b_=grow>>11, n=grow&2047;
            dptr[(size_t)(b_*HN + (cb0>>6)+wc)*NS + n]=0.5f*NRM*NRM*s;
          }
        }
      }
      __syncthreads();
      const int hb=cb0>>6;
#pragma unroll
      for(int tt=0;tt<16;++tt){
        const int task=tt*8+w;               // 128 tasks: 32 rowgroups x 4 col-quarters
        const int rowg=task>>2, qq=task&3;
        const int row=rowg*8+(l>>3), sub=l&7;
        char* rbase=(char*)((row<128)? (void*)(As+row*256) : (void*)(Bs+(row-128)*256));
        const uint4 d4=*(const uint4*)(rbase + ((qq*128+sub*16)^((row&3)<<4)));
        const int grow=m0+row, b_=grow>>11, n=grow&2047;
        *(uint4*)&outp[((size_t)(b_*HN+hb+qq)*NS+n)*DH + sub*8]=d4;  // [bh][n][d]
      }
    }
  } else {
    if(oflag){
      // ---- f32 row-major output, two half-tile passes (rows 128 each) ----
#pragma unroll
      for(int p=0;p<2;++p){
        if(wr==p){
#pragma unroll
          for(int j=0;j<4;++j){
            const int col=wc*64+j*16+cl;
            const float bb=ld1(bias0,n0+col,oflag);
#pragma unroll
            for(int i=0;i<8;++i){
#pragma unroll
              for(int r=0;r<4;++r){
                const int row=i*16+q4*4+r;     // 0..127
                char* rbase=(char*)((row<64)? (void*)(As+row*512) : (void*)(Bs+(row-64)*512));
                *(float*)(rbase + ((col*4)^((row&3)<<4))) = acc[i][j][r]+bb;
              }
            }
          }
        }
        __syncthreads();
#pragma unroll
        for(int tt=0;tt<16;++tt){
          const int task=tt*8+w;             // 128 tasks: 16 rowgroups x 8 chunks
          const int rowg=task>>3, qq=task&7;
          const int row=rowg*8+(l>>3), sub=l&7;
          char* rbase=(char*)((row<64)? (void*)(As+row*512) : (void*)(Bs+(row-64)*512));
          const uint4 d4=*(const uint4*)(rbase + ((qq*128+sub*16)^((row&3)<<4)));
          const size_t grow=(size_t)m0+p*128+row;
          *(uint4*)((char*)outv + (grow*DM+n0)*4 + qq*128 + sub*16)=d4;
        }
        __syncthreads();
      }
    } else {
      // ---- bf16 row-major output ----
#pragma unroll
      for(int j=0;j<4;++j){
        const int col=wc*64+j*16+cl;
        const float bb=ld1(bias0,n0+col,oflag);
#pragma unroll
        for(int i=0;i<8;++i){
#pragma unroll
          for(int r=0;r<4;++r){
            const int row=wr*128+i*16+q4*4+r;
            char* rbase=(char*)((row<128)? (void*)(As+row*256) : (void*)(Bs+(row-128)*256));
            *(u16*)(rbase + ((col*2)^((row&3)<<4))) = (u16)f2b(acc[i][j][r]+bb);
          }
        }
      }
      __syncthreads();
#pragma unroll
      for(int tt=0;tt<16;++tt){
        const int task=tt*8+w;
        const int rowg=task>>2, qq=task&3;
        const int row=rowg*8+(l>>3), sub=l&7;
        char* rbase=(char*)((row<128)? (void*)(As+row*256) : (void*)(Bs+(row-128)*256));
        const uint4 d4=*(const uint4*)(rbase + ((qq*128+sub*16)^((row&3)<<4)));
        const int grow=m0+row;
        *(uint4*)((u16*)outv + (size_t)grow*DM + n0 + qq*64 + sub*8)=d4;
      }
    }
  }
}

// ---------------- K2: MFMA xp_k + global max per bh --------------------------
__global__ __launch_bounds__(256) void k_xpk2(const u16* __restrict__ kb,
    const u16* __restrict__ pn, u32* __restrict__ kmax)
{
  __shared__ short Bt[32*512];
  __shared__ short At[8*512];
  __shared__ float red[256];
  const int t=threadIdx.x, l=t&63, w=t>>6;
  const int bh=blockIdx.y, nb0=blockIdx.x*256;
  for(int s=t;s<2048;s+=256){
    const int ub=s>>6, l2=s&63, mt=ub>>1, kh=ub&1;
    const int row=mt*16+(l2&15), kc=kh*32+(l2>>4)*8;
    *(uint4*)&Bt[ub*512+l2*8]=*(const uint4*)(pn + (size_t)row*DH + kc);
  }
  float vmax=-3.4e38f;
  for(int c=0;c<4;++c){
    const int n0=nb0+c*64;
    __syncthreads();
    for(int s=t;s<512;s+=256){
      const int ua=s>>6, l2=s&63, rb=ua>>1, kh=ua&1;
      const int n=n0+rb*16+(l2&15), kc=kh*32+(l2>>4)*8;
      *(uint4*)&At[ua*512+l2*8]=*(const uint4*)(kb + ((size_t)bh*NS+n)*DH + kc);
    }
    __syncthreads();
    const short8 af0=*(short8*)&At[(w*2+0)*512+l*8];
    const short8 af1=*(short8*)&At[(w*2+1)*512+l*8];
#pragma unroll
    for(int mt=0;mt<16;++mt){
      floatx4 a={};
      a=__builtin_amdgcn_mfma_f32_16x16x32_bf16(af0,*(short8*)&Bt[(mt*2+0)*512+l*8],a,0,0,0);
      a=__builtin_amdgcn_mfma_f32_16x16x32_bf16(af1,*(short8*)&Bt[(mt*2+1)*512+l*8],a,0,0,0);
      vmax=fmaxf(vmax,fmaxf(fmaxf(a[0],a[1]),fmaxf(a[2],a[3])));
    }
  }
  red[t]=vmax; __syncthreads();
  for(int s=128;s>0;s>>=1){ if(t<s) red[t]=fmaxf(red[t],red[t+s]); __syncthreads(); }
  if(t==0) atomicMax(kmax+bh, fkey(red[0]));
}

// ---------------- K3: MFMA fused kp -> ksum + ctx^T --------------------------
__global__ __launch_bounds__(256) void k_ctx2(const u16* __restrict__ kb,
    const u16* __restrict__ vT, const u16* __restrict__ pn,
    const float* __restrict__ dkbuf, const u32* __restrict__ kmax,
    float* __restrict__ ctxT, float* __restrict__ ksum)
{
  __shared__ short Bt[32*512];
  __shared__ u16   Ks[256*72];
  __shared__ short AtV[8*512];
  __shared__ float dg[64];
  const int t=threadIdx.x, l=t&63, w=t>>6;
  const int split=blockIdx.x, bh=blockIdx.y;
  for(int s=t;s<2048;s+=256){
    const int ub=s>>6, l2=s&63, mt=ub>>1, kh=ub&1;
    const int row=mt*16+(l2&15), kc=kh*32+(l2>>4)*8;
    *(uint4*)&Bt[ub*512+l2*8]=*(const uint4*)(pn + (size_t)row*DH + kc);
  }
  const float kM=funkey(kmax[bh]);
  float ksr=0.f;
  floatx4 acc2[4][4]={};
  for(int c=0;c<8;++c){
    const int n0=split*512+c*64;
    __syncthreads();
    for(int s=t;s<512;s+=256){
      const int ua=s>>6, l2=s&63, rb=ua>>1, kh=ua&1;
      const int n=n0+rb*16+(l2&15), kc=kh*32+(l2>>4)*8;
      *(uint4*)&AtV[ua*512+l2*8]=*(const uint4*)(kb + ((size_t)bh*NS+n)*DH + kc);
    }
    if(t<64) dg[t]=dkbuf[(size_t)bh*NS+n0+t];
    __syncthreads();
    short8 af[4][2];
#pragma unroll
    for(int rb=0;rb<4;++rb){
      af[rb][0]=*(short8*)&AtV[(rb*2+0)*512+l*8];
      af[rb][1]=*(short8*)&AtV[(rb*2+1)*512+l*8];
    }
    float dgl[16];
#pragma unroll
    for(int rb=0;rb<4;++rb)
#pragma unroll
      for(int r=0;r<4;++r) dgl[rb*4+r]=dg[rb*16+(l>>4)*4+r];
#pragma unroll
    for(int ml=0;ml<4;++ml){
      const int mt=w*4+ml;
      const short8 bf0=*(short8*)&Bt[(mt*2+0)*512+l*8];
      const short8 bf1=*(short8*)&Bt[(mt*2+1)*512+l*8];
      const int m=mt*16+(l&15);
#pragma unroll
      for(int rb=0;rb<4;++rb){
        floatx4 a={};
        a=__builtin_amdgcn_mfma_f32_16x16x32_bf16(af[rb][0],bf0,a,0,0,0);
        a=__builtin_amdgcn_mfma_f32_16x16x32_bf16(af[rb][1],bf1,a,0,0,0);
        const int nb=rb*16+(l>>4)*4;
        const float v0=RATIO*(__expf(a[0]-dgl[rb*4+0]-kM)+EPSV);
        const float v1=RATIO*(__expf(a[1]-dgl[rb*4+1]-kM)+EPSV);
        const float v2=RATIO*(__expf(a[2]-dgl[rb*4+2]-kM)+EPSV);
        const float v3=RATIO*(__expf(a[3]-dgl[rb*4+3]-kM)+EPSV);
        *(u32*)&Ks[m*72+nb]  =f2b(v0)|(f2b(v1)<<16);
        *(u32*)&Ks[m*72+nb+2]=f2b(v2)|(f2b(v3)<<16);
      }
    }
    __syncthreads();
    for(int s=t;s<512;s+=256){
      const int uv=s>>6, l2=s&63, dt=uv>>1, kh=uv&1;
      const int d=dt*16+(l2&15), nn=n0+kh*32+(l2>>4)*8;
      *(uint4*)&AtV[uv*512+l2*8]=*(const uint4*)(vT + ((size_t)bh*DH+d)*NS + nn);
    }
    {
      float s8=0.f;
#pragma unroll
      for(int j=0;j<8;++j){
        const uint4 kk=*(const uint4*)&Ks[t*72+j*8];
        s8+=b2f(kk.x&0xffffu)+b2f(kk.x>>16)+b2f(kk.y&0xffffu)+b2f(kk.y>>16)
           +b2f(kk.z&0xffffu)+b2f(kk.z>>16)+b2f(kk.w&0xffffu)+b2f(kk.w>>16);
      }
      ksr+=s8;
    }
    __syncthreads();
#pragma unroll
    for(int i=0;i<4;++i){
      const int row=(w*4+i)*16+(l&15);
      const short8 a0=*(short8*)&Ks[row*72 + 0*32+(l>>4)*8];
      const short8 a1=*(short8*)&Ks[row*72 + 1*32+(l>>4)*8];
#pragma unroll
      for(int dt=0;dt<4;++dt){
        acc2[i][dt]=__builtin_amdgcn_mfma_f32_16x16x32_bf16(a0,*(short8*)&AtV[(dt*2+0)*512+l*8],acc2[i][dt],0,0,0);
        acc2[i][dt]=__builtin_amdgcn_mfma_f32_16x16x32_bf16(a1,*(short8*)&AtV[(dt*2+1)*512+l*8],acc2[i][dt],0,0,0);
      }
    }
  }
#pragma unroll
  for(int i=0;i<4;++i){
#pragma unroll
    for(int dt=0;dt<4;++dt){
#pragma unroll
      for(int r=0;r<4;++r){
        const int m=(w*4+i)*16+(l>>4)*4+r;
        const int d=dt*16+(l&15);
        atomicAdd(&ctxT[((size_t)bh*DH+d)*MF+m], acc2[i][dt][r]);
      }
    }
  }
  atomicAdd(ksum+bh*MF+t, ksr);
}

// ---------------- K3b: split ctxT f32 -> hi/lo bf16, ecs=eps*colsum ----------
__global__ __launch_bounds__(256) void k_csplit(const float* __restrict__ ctxT,
    u16* __restrict__ chi, u16* __restrict__ clo, float* __restrict__ ecs)
{
  __shared__ float cred[256];
  const int bh=blockIdx.x, t=threadIdx.x;
  const int d=t>>2, part=t&3;
  const size_t base=((size_t)bh*DH+d)*MF + part*64;
  const float* src=ctxT + base;
  u16* ph=chi + base;
  u16* pl=clo + base;
  float cs=0.f;
  for(int m=0;m<64;m+=4){
    float4 v=*(const float4*)(src+m);
    float vv[4]={v.x,v.y,v.z,v.w};
    u32 h_[4], l_[4];
#pragma unroll
    for(int j=0;j<4;++j){
      cs+=vv[j];
      u32 hh=f2b(vv[j]);
      float rr=vv[j]-b2f(hh);
      h_[j]=hh; l_[j]=f2b(rr);
    }
    uint2 sh, sl;
    sh.x=h_[0]|(h_[1]<<16); sh.y=h_[2]|(h_[3]<<16);
    sl.x=l_[0]|(l_[1]<<16); sl.y=l_[2]|(l_[3]<<16);
    *(uint2*)(ph+m)=sh; *(uint2*)(pl+m)=sl;
  }
  cred[t]=cs; __syncthreads();
  if(part==0) ecs[bh*64+d]=EPSV*(cred[t]+cred[t+1]+cred[t+2]+cred[t+3]);
}

// ---------------- K4: MFMA fused qp + D_inv + attn ---------------------------
__global__ __launch_bounds__(256) void k_attn2(const u16* __restrict__ qb,
    const u16* __restrict__ pn, const float* __restrict__ dqbuf,
    const float* __restrict__ ksum, const u16* __restrict__ chi, const u16* __restrict__ clo,
    const float* __restrict__ ecs, u16* __restrict__ attn)
{
  __shared__ short At[8*512];
  __shared__ u16 Qf[32*512];
  __shared__ float ksums[256];
  __shared__ float dq_s[64];
  __shared__ float mxs[4][64];
  __shared__ float s1s[4][64];
  __shared__ float a_s[64], dinv_s[64], ec_s[64];
  __shared__ float red4[4];
  __shared__ float epkss;
  const int t=threadIdx.x, l=t&63, w=t>>6;
  const int bh=blockIdx.y, nb0=blockIdx.x*256;
  const int b_=bh/HN, h=bh%HN;
  {
    float kv=ksum[bh*MF+t];
    ksums[t]=kv;
    if(t<64) ec_s[t]=ecs[bh*64+t];
    float s=kv;
#pragma unroll
    for(int o=1;o<64;o<<=1) s+=__shfl_xor(s,o,64);
    if(l==0) red4[w]=s;
  }
  __syncthreads();
  if(t==0) epkss=EPSV*(red4[0]+red4[1]+red4[2]+red4[3]);
  short8 bhf[8], blf[8];
  {
    const int d=w*16+(l&15);
    const size_t base=((size_t)bh*DH+d)*MF;
#pragma unroll
    for(int kc=0;kc<8;++kc){
      const size_t off=base + kc*32+(l>>4)*8;
      bhf[kc]=*(const short8*)(chi+off);
      blf[kc]=*(const short8*)(clo+off);
    }
  }
  for(int c=0;c<4;++c){
    const int n0c=nb0+c*64;
    __syncthreads();
    for(int s=t;s<512;s+=256){
      const int ua=s>>6, l2=s&63, nt=ua>>1, kh=ua&1;
      const int n=n0c+nt*16+(l2&15), kc=kh*32+(l2>>4)*8;
      *(uint4*)&At[ua*512+l2*8]=*(const uint4*)(qb + ((size_t)bh*NS+n)*DH + kc);
    }
    if(t<64) dq_s[t]=dqbuf[(size_t)bh*NS+n0c+t];
    __syncthreads();
    float mxl[4]={-3.4e38f,-3.4e38f,-3.4e38f,-3.4e38f};
    float s1l[4]={0.f,0.f,0.f,0.f};
#pragma unroll
    for(int mt=0;mt<4;++mt){
      const int gm=w*4+mt;
      const u16* pr=pn + ((gm*16+(l&15))<<6) + (l>>4)*8;
      const short8 a0=*(const short8*)(pr);
      const short8 a1=*(const short8*)(pr+32);
      float k4[4];
#pragma unroll
      for(int r=0;r<4;++r) k4[r]=ksums[gm*16+(l>>4)*4+r];
      const int mbase=(gm&1)*16+(l>>4)*4;
      const int lane2=((mbase>>3)*16+(l&15))*8 + (mbase&7);
#pragma unroll
      for(int nt=0;nt<4;++nt){
        floatx4 xp={};
        xp=__builtin_amdgcn_mfma_f32_16x16x32_bf16(a0,*(short8*)&At[(nt*2+0)*512+l*8],xp,0,0,0);
        xp=__builtin_amdgcn_mfma_f32_16x16x32_bf16(a1,*(short8*)&At[(nt*2+1)*512+l*8],xp,0,0,0);
        const float dq=dq_s[nt*16+(l&15)];
        float ev[4];
#pragma unroll
        for(int r=0;r<4;++r){
          const float xv=xp[r];
          mxl[nt]=fmaxf(mxl[nt],xv);
          ev[r]=__expf(xv-dq);
          s1l[nt]+=ev[r]*k4[r];
        }
        u16* qp_=&Qf[(nt*8+(gm>>1))*512 + lane2];
        *(u32*)qp_    =f2b(ev[0])|(f2b(ev[1])<<16);
        *(u32*)(qp_+2)=f2b(ev[2])|(f2b(ev[3])<<16);
      }
    }
#pragma unroll
    for(int nt=0;nt<4;++nt){
      float m_=mxl[nt], s_=s1l[nt];
      m_=fmaxf(m_,__shfl_xor(m_,16,64)); s_+=__shfl_xor(s_,16,64);
      m_=fmaxf(m_,__shfl_xor(m_,32,64)); s_+=__shfl_xor(s_,32,64);
      if(l<16){ mxs[w][nt*16+l]=m_; s1s[w][nt*16+l]=s_; }
    }
    __syncthreads();
    if(t<64){
      float m_=fmaxf(fmaxf(mxs[0][t],mxs[1][t]),fmaxf(mxs[2][t],mxs[3][t]));
      float s_=s1s[0][t]+s1s[1][t]+s1s[2][t]+s1s[3][t];
      float a=__expf(-m_);
      a_s[t]=a;
      dinv_s[t]=1.0f/(a*s_+epkss);
    }
    __syncthreads();
    const int d=w*16+(l&15);
    const float ec=ec_s[d];
#pragma unroll
    for(int nt=0;nt<4;++nt){
      floatx4 y={};
#pragma unroll
      for(int kc=0;kc<8;++kc){
        const short8 e=*(short8*)&Qf[(nt*8+kc)*512+l*8];
        y=__builtin_amdgcn_mfma_f32_16x16x32_bf16(e,bhf[kc],y,0,0,0);
        y=__builtin_amdgcn_mfma_f32_16x16x32_bf16(e,blf[kc],y,0,0,0);
      }
#pragma unroll
      for(int r=0;r<4;++r){
        const int nl=nt*16+(l>>4)*4+r;
        const float val=(a_s[nl]*y[r]+ec)*dinv_s[nl];
        attn[((size_t)(b_*NS+n0c+nl))*DM + h*DH + d]=(u16)f2b(val);
      }
    }
  }
}

extern "C" void kernel_launch(void* const* d_in, const int* in_sizes, int n_in,
                              void* d_out, int out_size, void* d_ws, size_t ws_size,
                              hipStream_t stream)
{
  (void)in_sizes; (void)n_in; (void)out_size;
  const void* x =d_in[0];
  const void* Wq=d_in[1]; const void* bq=d_in[2];
  const void* Wk=d_in[3]; const void* bk=d_in[4];
  const void* Wv=d_in[5]; const void* bv=d_in[6];
  const void* Wo=d_in[7]; const void* bo=d_in[8];
  const void* proj=d_in[9];

  char* ws=(char*)d_ws;
  const size_t SZ=(size_t)BN*DM*2;               // 25,165,824 B
  const size_t AUXSZ=19030528;
  const bool big = ws_size >= 4*SZ + AUXSZ;      // ~119.7 MB
  u16*   qb  =(u16*)(ws);
  u16*   kb  =(u16*)(ws+SZ);
  u16*   vb  =(u16*)(ws+2*SZ);                   // v^T [bh][d][n]
  u16*   xb  =(u16*)(ws+3*SZ);                   // bf16 x (big path only)
  char*  aux = big ? (ws+4*SZ) : (ws+3*SZ);
  u16*   wb   =(u16*)(aux);                      // 3,538,944
  u16*   wob  =(u16*)(aux+3538944);              // -> 4,718,592
  float* ctxT =(float*)(aux+4718592);            // -> 11,010,048
  float* ksum =(float*)(aux+11010048);           // -> 11,108,352
  u32*   kmax =(u32*)(aux+11108352);             // -> 11,108,736
  int*   flag =(int*)(aux+11108736);             // -> 11,108,864
  float* dk   =(float*)(aux+11108864);           // -> 11,895,296
  float* dqq  =(float*)(aux+11895296);           // -> 12,681,728
  u16*   pn   =(u16*)(aux+12681728);             // -> 12,714,496
  u16*   chi  =(u16*)(aux+12714496);             // -> 15,860,224
  u16*   clo  =(u16*)(aux+15860224);             // -> 19,005,952
  float* ecs  =(float*)(aux+19005952);           // -> 19,030,528
  u16*   attnb = big ? xb : kb;                  // dead buffer reuse

  k_detect<<<1,64,0,stream>>>((const u16*)x, flag);
  hipMemsetAsync(ctxT, 0, 6291456+98304+384, stream);
  k_cvtw <<<1152, 256, 0, stream>>>(Wq,Wk,Wv,Wo,wb,wob,flag);
  k_cvtp <<<8, 256, 0, stream>>>(proj, pn, flag);
  if(big){
    k_cvtx <<<(BN*DM)/2048, 256, 0, stream>>>(x, xb, flag);
    k_gemm8<<<dim3(BN/256,2304/256), 512, 0, stream>>>(xb, wb, bq,bk,bv, qb,kb,vb, nullptr, flag, 0, dqq, dk);
  }else{
    k_gemm_f<<<dim3(BN/128,2304/128), 256, 0, stream>>>(x, wb, bq,bk,bv, qb,kb,vb, nullptr, flag, 0);
    k_diag <<<(BH*NS)/256, 256, 0, stream>>>(kb, dk);
    k_diag <<<(BH*NS)/256, 256, 0, stream>>>(qb, dqq);
  }
  k_xpk2 <<<dim3(NS/256,BH), 256, 0, stream>>>(kb, pn, kmax);
  k_ctx2 <<<dim3(4,BH), 256, 0, stream>>>(kb, vb, pn, dk, kmax, ctxT, ksum);
  k_csplit<<<BH, 256, 0, stream>>>(ctxT, chi, clo, ecs);
  k_attn2<<<dim3(NS/256,BH), 256, 0, stream>>>(qb, pn, dqq, ksum, chi, clo, ecs, attnb);
  if(big){
    k_gemm8<<<dim3(BN/256,DM/256), 512, 0, stream>>>(attnb, wob, bo,bo,bo, nullptr,nullptr,nullptr, d_out, flag, 1, nullptr, nullptr);
  }else{
    k_gemm2<<<dim3(BN/128,DM/128), 256, 0, stream>>>(attnb, wob, bo,bo,bo, nullptr,nullptr,nullptr, d_out, flag, 1);
  }
}

// Round 3
// 415.395 us; speedup vs baseline: 1.3227x; 1.1794x over previous
//
#include <hip/hip_runtime.h>
#include <stdint.h>

typedef unsigned short u16;
typedef unsigned int u32;
typedef __attribute__((ext_vector_type(8))) short short8;
typedef __attribute__((ext_vector_type(4))) float floatx4;

#define HN 12
#define DH 64
#define DM 768
#define NS 2048
#define NB 8
#define MF 256
#define BN (NB*NS)
#define BH (NB*HN)

#define NRM 0.35355339059327373f  /* 64^-0.25 */
#define RATIO 0.0625f             /* 256^-0.5 */
#define EPSV 1e-4f

__device__ __forceinline__ float b2f(u32 u){ union{u32 i; float f;} x; x.i=u<<16; return x.f; }
__device__ __forceinline__ u32 f2b(float v){ union{float f; u32 u;} x; x.f=v; return (x.u + 0x7FFFu + ((x.u>>16)&1u))>>16; }
__device__ __forceinline__ u32 fkey(float v){ union{float f; u32 u;} x; x.f=v; return (x.u&0x80000000u)? ~x.u : (x.u|0x80000000u); }
__device__ __forceinline__ float funkey(u32 k){ union{u32 u; float f;} x; x.u=(k&0x80000000u)? (k^0x80000000u) : ~k; return x.f; }
__device__ __forceinline__ void bld8(uint4 r, float s, float* f){
  f[0]=b2f(r.x&0xffffu)*s; f[1]=b2f(r.x>>16)*s;
  f[2]=b2f(r.y&0xffffu)*s; f[3]=b2f(r.y>>16)*s;
  f[4]=b2f(r.z&0xffffu)*s; f[5]=b2f(r.z>>16)*s;
  f[6]=b2f(r.w&0xffffu)*s; f[7]=b2f(r.w>>16)*s;
}
__device__ __forceinline__ void load8(const void* base, size_t idx, int isf32, float s, float* f){
  if(isf32){
    const float* p=(const float*)base + idx;
    const float4 u=((const float4*)p)[0], v=((const float4*)p)[1];
    f[0]=u.x*s; f[1]=u.y*s; f[2]=u.z*s; f[3]=u.w*s;
    f[4]=v.x*s; f[5]=v.y*s; f[6]=v.z*s; f[7]=v.w*s;
  }else{
    uint4 r=*(const uint4*)((const u16*)base+idx);
    bld8(r,s,f);
  }
}
__device__ __forceinline__ float ld1(const void* base, int idx, int isf32){
  return isf32 ? ((const float*)base)[idx] : b2f((u32)((const u16*)base)[idx]);
}
// async global->LDS, 16B/lane; l must be wave-uniform, data lands at l + lane*16B
__device__ __forceinline__ void gl16(const void* g, void* l){
  __builtin_amdgcn_global_load_lds(
    (const __attribute__((address_space(1))) u32*)g,
    (__attribute__((address_space(3))) u32*)l, 16, 0, 0);
}

// ---------------- K0: detect input dtype (0=bf16, 1=f32) ---------------------
__global__ __launch_bounds__(64) void k_detect(const u16* __restrict__ x, int* __restrict__ flag)
{
  __shared__ int w[64], z[64];
  const int t=threadIdx.x;
  int wild=0, zero=0;
  for(int i=t;i<256;i+=64){
    u32 u=(u32)x[2*i];
    u32 e=(u>>7)&0xFFu;
    if(e>=0x90u) wild++;
    if((u&0x7FFFu)==0u) zero++;
  }
  w[t]=wild; z[t]=zero; __syncthreads();
  if(t==0){
    int W=0,Z=0;
    for(int i=0;i<64;++i){W+=w[i];Z+=z[i];}
    flag[0]=(W>16||Z>200)?1:0;
  }
}

// ---------------- K0b: convert weights to bf16 (wb=[Wq;Wk;Wv], wob=Wo) ------
__global__ __launch_bounds__(256) void k_cvtw(const void* __restrict__ Wq,
    const void* __restrict__ Wk, const void* __restrict__ Wv, const void* __restrict__ Wo,
    u16* __restrict__ wb, u16* __restrict__ wob, const int* __restrict__ flagp)
{
  const int isf32=*flagp;
  const size_t WSZ=(size_t)DM*DM;
  size_t idx=((size_t)blockIdx.x*256+threadIdx.x)*8;
  const void* src; size_t off; u16* dst;
  if(idx<3*WSZ){ int w=(int)(idx/WSZ); src=(w==0)?Wq:((w==1)?Wk:Wv); off=idx-(size_t)w*WSZ; dst=wb+idx; }
  else { src=Wo; off=idx-3*WSZ; dst=wob+off; }
  if(isf32){
    const float* p=(const float*)src+off;
    float4 u=((const float4*)p)[0], v=((const float4*)p)[1];
    uint4 st;
    st.x=f2b(u.x)|(f2b(u.y)<<16); st.y=f2b(u.z)|(f2b(u.w)<<16);
    st.z=f2b(v.x)|(f2b(v.y)<<16); st.w=f2b(v.z)|(f2b(v.w)<<16);
    *(uint4*)dst=st;
  }else{
    *(uint4*)dst=*(const uint4*)((const u16*)src+off);
  }
}

// ---------------- K0c: pn = proj * NRM, bf16 [256][64] -----------------------
__global__ __launch_bounds__(256) void k_cvtp(const void* __restrict__ proj,
    u16* __restrict__ pn, const int* __restrict__ flagp)
{
  const int isf32=*flagp;
  const size_t idx=((size_t)blockIdx.x*256+threadIdx.x)*8;
  float pf[8];
  load8(proj, idx, isf32, NRM, pf);
  uint4 st;
  st.x=f2b(pf[0])|(f2b(pf[1])<<16); st.y=f2b(pf[2])|(f2b(pf[3])<<16);
  st.z=f2b(pf[4])|(f2b(pf[5])<<16); st.w=f2b(pf[6])|(f2b(pf[7])<<16);
  *(uint4*)(pn+idx)=st;
}

// ---------------- K0e: xb = bf16(x) ------------------------------------------
__global__ __launch_bounds__(256) void k_cvtx(const void* __restrict__ x,
    u16* __restrict__ xb, const int* __restrict__ flagp)
{
  const int isf32=*flagp;
  const size_t idx=((size_t)blockIdx.x*256+threadIdx.x)*8;   // over BN*DM
  float f[8];
  load8(x, idx, isf32, 1.0f, f);
  uint4 st;
  st.x=f2b(f[0])|(f2b(f[1])<<16); st.y=f2b(f[2])|(f2b(f[3])<<16);
  st.z=f2b(f[4])|(f2b(f[5])<<16); st.w=f2b(f[6])|(f2b(f[7])<<16);
  *(uint4*)(xb+idx)=st;
}

// ---------------- K0d: dk[row] = 0.5*NRM^2*sum(v^2) over DH (fallback path) --
__global__ __launch_bounds__(256) void k_diag(const u16* __restrict__ src, float* __restrict__ dk)
{
  const size_t row=(size_t)blockIdx.x*256+threadIdx.x;
  const u16* p=src+row*DH;
  float s=0.f;
#pragma unroll
  for(int c=0;c<DH;c+=8){
    uint4 r=*(const uint4*)(p+c);
    float f[8]; bld8(r,1.0f,f);
#pragma unroll
    for(int j=0;j<8;++j) s+=f[j]*f[j];
  }
  dk[row]=0.5f*NRM*NRM*s;
}

// ======== shared epilogue for the two 128-tile fallback MFMA GEMMs ===========
__device__ __forceinline__ void gemm_epilogue(const floatx4 acc[4][4], int mode, int oflag,
    int m0, int n0, int l, int wr4, int wc4,
    const void* bias0, const void* bias1, const void* bias2,
    u16* q, u16* k, u16* v, void* outv)
{
  const int rbase=(l>>4)*4, cl=l&15;
  if(mode==0){
    const int which=n0/DM;
    const void* bias=(which==0)?bias0:((which==1)?bias1:bias2);
    u16* outp=(which==0)?q:((which==1)?k:v);
    const int cb=n0-which*DM;
#pragma unroll
    for(int j=0;j<4;++j){
      const int col=cb+(wc4+j)*16+cl;
      const int h=col>>6, dd=col&63;
      const float bb=ld1(bias,col,oflag);
#pragma unroll
      for(int i=0;i<4;++i){
#pragma unroll
        for(int r=0;r<4;++r){
          const int grow=m0+(wr4+i)*16+rbase+r;
          const int b_=grow>>11, n=grow&2047;
          const u16 val=(u16)f2b(acc[i][j][r]+bb);
          if(which==2) outp[((size_t)(b_*HN+h)*DH+dd)*NS + n]=val;       // vT [bh][d][n]
          else         outp[((size_t)((b_*HN+h)*NS+n))*DH + dd]=val;     // [bh][n][d]
        }
      }
    }
  }else{
#pragma unroll
    for(int j=0;j<4;++j){
      const int col=n0+(wc4+j)*16+cl;
      const float bb=ld1(bias0,col,oflag);
#pragma unroll
      for(int i=0;i<4;++i){
#pragma unroll
        for(int r=0;r<4;++r){
          const int grow=m0+(wr4+i)*16+rbase+r;
          const float val=acc[i][j][r]+bb;
          if(oflag) ((float*)outv)[(size_t)grow*DM+col]=val;
          else      ((u16*)outv)[(size_t)grow*DM+col]=(u16)f2b(val);
        }
      }
    }
  }
}

// ---------------- K1: MFMA GEMM, 128-tile (fallback) -------------------------
__global__ __launch_bounds__(256) void k_gemm2(const u16* __restrict__ A16,
    const u16* __restrict__ B16,
    const void* __restrict__ bias0, const void* __restrict__ bias1, const void* __restrict__ bias2,
    u16* __restrict__ q, u16* __restrict__ k, u16* __restrict__ v,
    void* __restrict__ outv, const int* __restrict__ flagp, const int mode)
{
  __shared__ short At[16*512];
  __shared__ short Bt[16*512];
  const int oflag=*flagp;
  const int t=threadIdx.x, l=t&63, w=t>>6;
  const int m0=blockIdx.x*128, n0=blockIdx.y*128;
  const int wr4=(w>>1)*4, wc4=(w&1)*4;
  const int srow=l&15, skg=l>>4;
  floatx4 acc[4][4]={};
  for(int k0=0;k0<DM;k0+=64){
    __syncthreads();
#pragma unroll
    for(int s=0;s<4;++s){
      const int bi=w*4+s, rb=bi>>1, kh=bi&1;
      const int kc=k0+kh*32+skg*8;
      gl16(A16 + (size_t)(m0+rb*16+srow)*DM + kc, &At[bi*512]);
      gl16(B16 + (size_t)(n0+rb*16+srow)*DM + kc, &Bt[bi*512]);
    }
    __syncthreads();
#pragma unroll
    for(int kh=0;kh<2;++kh){
      short8 af[4], bf[4];
#pragma unroll
      for(int i=0;i<4;++i) af[i]=*(short8*)&At[((wr4+i)*2+kh)*512+l*8];
#pragma unroll
      for(int j=0;j<4;++j) bf[j]=*(short8*)&Bt[((wc4+j)*2+kh)*512+l*8];
#pragma unroll
      for(int i=0;i<4;++i)
#pragma unroll
        for(int j=0;j<4;++j)
          acc[i][j]=__builtin_amdgcn_mfma_f32_16x16x32_bf16(af[i],bf[j],acc[i][j],0,0,0);
    }
  }
  gemm_epilogue(acc,mode,oflag,m0,n0,l,wr4,wc4,bias0,bias1,bias2,q,k,v,outv);
}

// ---------------- K1f: fallback MFMA GEMM, f32-capable A ---------------------
__global__ __launch_bounds__(256) void k_gemm_f(const void* __restrict__ Araw,
    const u16* __restrict__ B16,
    const void* __restrict__ bias0, const void* __restrict__ bias1, const void* __restrict__ bias2,
    u16* __restrict__ q, u16* __restrict__ k, u16* __restrict__ v,
    void* __restrict__ outv, const int* __restrict__ flagp, const int mode)
{
  __shared__ short At[16*512];
  __shared__ short Bt[16*512];
  const int oflag=*flagp;
  const int isf32=(mode==0)?oflag:0;
  const int t=threadIdx.x, l=t&63, w=t>>6;
  const int m0=blockIdx.x*128, n0=blockIdx.y*128;
  const int wr4=(w>>1)*4, wc4=(w&1)*4;
  const int srow=l&15, skg=l>>4;
  floatx4 acc[4][4]={};
  for(int k0=0;k0<DM;k0+=64){
    __syncthreads();
#pragma unroll
    for(int s=0;s<4;++s){
      const int bi=w*4+s, rb=bi>>1, kh=bi&1;
      const int kc=k0+kh*32+skg*8;
      uint4 va;
      if(isf32){
        const float* ap=(const float*)Araw + (size_t)(m0+rb*16+srow)*DM + kc;
        float4 u=((const float4*)ap)[0], vv=((const float4*)ap)[1];
        va.x=f2b(u.x)|(f2b(u.y)<<16);  va.y=f2b(u.z)|(f2b(u.w)<<16);
        va.z=f2b(vv.x)|(f2b(vv.y)<<16); va.w=f2b(vv.z)|(f2b(vv.w)<<16);
      }else{
        va=*(const uint4*)((const u16*)Araw + (size_t)(m0+rb*16+srow)*DM + kc);
      }
      const uint4 vb=*(const uint4*)(B16 + (size_t)(n0+rb*16+srow)*DM + kc);
      *(uint4*)&At[bi*512+l*8]=va;
      *(uint4*)&Bt[bi*512+l*8]=vb;
    }
    __syncthreads();
#pragma unroll
    for(int kh=0;kh<2;++kh){
      short8 af[4], bf[4];
#pragma unroll
      for(int i=0;i<4;++i) af[i]=*(short8*)&At[((wr4+i)*2+kh)*512+l*8];
#pragma unroll
      for(int j=0;j<4;++j) bf[j]=*(short8*)&Bt[((wc4+j)*2+kh)*512+l*8];
#pragma unroll
      for(int i=0;i<4;++i)
#pragma unroll
        for(int j=0;j<4;++j)
          acc[i][j]=__builtin_amdgcn_mfma_f32_16x16x32_bf16(af[i],bf[j],acc[i][j],0,0,0);
    }
  }
  gemm_epilogue(acc,mode,oflag,m0,n0,l,wr4,wc4,bias0,bias1,bias2,q,k,v,outv);
}

// ================= K1g: 256x256 8-phase pipelined MFMA GEMM ==================
#define SBOFF(slot,kh,mf) ((((slot)*32)+((kh)*16)+(mf))*512)
#define STA(kt,kh) do{ \
  const int o_=SBOFF((kt)&1,(kh),0); \
  const size_t g_=(size_t)(kt)*64+(size_t)(kh)*32; \
  gl16(Ar0+g_, &As[o_+w*512]); \
  gl16(Ar0+(size_t)128*768+g_, &As[o_+(8+w)*512]); \
}while(0)
#define STB(kt,kh) do{ \
  const int o_=SBOFF((kt)&1,(kh),0); \
  const size_t g_=(size_t)(kt)*64+(size_t)(kh)*32; \
  gl16(Br0+g_, &Bs[o_+w*512]); \
  gl16(Br0+(size_t)128*768+g_, &Bs[o_+(8+w)*512]); \
}while(0)
#define LDA8(kt,kh) do{ const int o_=SBOFF((kt)&1,(kh),wr*8)+l*8; \
  _Pragma("unroll") for(int i_=0;i_<8;++i_) a[i_]=*(short8*)&As[o_+i_*512]; }while(0)
#define LDB2(kt,kh,np) do{ const int o_=SBOFF((kt)&1,(kh),wc*4+(np)*2)+l*8; \
  b[0]=*(short8*)&Bs[o_]; b[1]=*(short8*)&Bs[o_+512]; }while(0)
#define MM(np) do{ _Pragma("unroll") for(int i_=0;i_<8;++i_){ \
  acc[i_][(np)*2+0]=__builtin_amdgcn_mfma_f32_16x16x32_bf16(a[i_],b[0],acc[i_][(np)*2+0],0,0,0); \
  acc[i_][(np)*2+1]=__builtin_amdgcn_mfma_f32_16x16x32_bf16(a[i_],b[1],acc[i_][(np)*2+1],0,0,0); } }while(0)
#define FEN asm volatile("" ::: "memory")
#define BARR do{ FEN; __builtin_amdgcn_s_barrier(); FEN; }while(0)
#define WV8 asm volatile("s_waitcnt vmcnt(8)" ::: "memory")
#define WV4 asm volatile("s_waitcnt vmcnt(4)" ::: "memory")
#define WV0 asm volatile("s_waitcnt vmcnt(0)" ::: "memory")
#define WL0 do{ asm volatile("s_waitcnt lgkmcnt(0)" ::: "memory"); __builtin_amdgcn_sched_barrier(0); }while(0)
#define PH_O(kt,kh,SST) do{ LDA8(kt,kh); LDB2(kt,kh,0); SST; BARR; WL0; \
  __builtin_amdgcn_s_setprio(1); MM(0); __builtin_amdgcn_s_setprio(0); BARR; }while(0)
#define PH_E(kt,kh,SST,WST) do{ LDB2(kt,kh,1); SST; WST; BARR; WL0; \
  __builtin_amdgcn_s_setprio(1); MM(1); __builtin_amdgcn_s_setprio(0); BARR; }while(0)

__global__ __launch_bounds__(512,2) void k_gemm8(const u16* __restrict__ A16,
    const u16* __restrict__ B16,
    const void* __restrict__ bias0, const void* __restrict__ bias1, const void* __restrict__ bias2,
    u16* __restrict__ q, u16* __restrict__ k, u16* __restrict__ v,
    void* __restrict__ outv, const int* __restrict__ flagp, const int mode,
    float* __restrict__ dq_, float* __restrict__ dk_)
{
  __shared__ short As[2*2*16*512];   // 64 KiB
  __shared__ short Bs[2*2*16*512];   // 64 KiB
  const int oflag=*flagp;
  const int t=threadIdx.x, l=t&63, w=t>>6;
  const int wr=w>>2, wc=w&3;
  const int lrow=l&15, lk8=(l>>4)*8;
  int bid = blockIdx.y*gridDim.x + blockIdx.x;
  const int nwg = gridDim.x*gridDim.y;       // 576 (mode0) / 192 (mode1), %8==0
  const int nN  = gridDim.y;                 // 9 / 3
  bid = (bid&7)*(nwg>>3) + (bid>>3);
  const int mi = bid/nN;
  const int m0 = mi*256;
  const int n0 = (bid - mi*nN)*256;

  const u16* Ar0 = A16 + (size_t)(m0 + w*16 + lrow)*768 + lk8;
  const u16* Br0 = B16 + (size_t)(n0 + w*16 + lrow)*768 + lk8;
  floatx4 acc[8][4]={};
  short8 a[8], b[2];

  STA(0,0); STB(0,0); STA(0,1); STB(0,1); STA(1,0); STB(1,0);
  WV8; BARR;

  for(int i=0;i<5;++i){
    const int kt=2*i;
    PH_O(kt,0,   STA(kt+1,1));
    PH_E(kt,0,   STB(kt+1,1), WV8);
    PH_O(kt,1,   STA(kt+2,0));
    PH_E(kt,1,   STB(kt+2,0), WV8);
    PH_O(kt+1,0, STA(kt+2,1));
    PH_E(kt+1,0, STB(kt+2,1), WV8);
    PH_O(kt+1,1, STA(kt+3,0));
    PH_E(kt+1,1, STB(kt+3,0), WV8);
  }
  PH_O(10,0, STA(11,1));
  PH_E(10,0, STB(11,1), WV8);
  PH_O(10,1, (void)0);
  PH_E(10,1, (void)0, WV4);
  PH_O(11,0, (void)0);
  PH_E(11,0, (void)0, WV0);
  PH_O(11,1, (void)0);
  PH_E(11,1, (void)0, (void)0);

  // ============ epilogue: LDS restage -> coalesced wide stores ===============
  const int cl=l&15, q4=l>>4;
  if(mode==0){
    const int which=n0/DM;
    const int cb0=n0-which*DM;
    const void* bias=(which==0)?bias0:((which==1)?bias1:bias2);
    u16* outp=(which==0)?q:((which==1)?k:v);
    if(which==2){
#pragma unroll
      for(int j=0;j<4;++j){
        const int col=wc*64+j*16+cl;
        const float bb=ld1(bias,cb0+col,oflag);
        char* cbase=(char*)((col<128)? (void*)(As+col*256) : (void*)(Bs+(col-128)*256));
        const int X=(col&7)<<4;
#pragma unroll
        for(int i=0;i<8;++i){
          const int rowb=wr*128+i*16+q4*4;
          uint2 pk;
          pk.x=f2b(acc[i][j][0]+bb)|(f2b(acc[i][j][1]+bb)<<16);
          pk.y=f2b(acc[i][j][2]+bb)|(f2b(acc[i][j][3]+bb)<<16);
          *(uint2*)(cbase + ((rowb*2)^X)) = pk;
        }
      }
      __syncthreads();
      const int b_=m0>>11, nbase=m0&2047;
#pragma unroll
      for(int tt=0;tt<16;++tt){
        const int task=tt*8+w;
        const int colg=task>>2, qq=task&3;
        const int col=colg*8+(l>>3), sub=l&7;
        char* cbase=(char*)((col<128)? (void*)(As+col*256) : (void*)(Bs+(col-128)*256));
        const uint4 d4=*(const uint4*)(cbase + ((qq*128+sub*16)^((col&7)<<4)));
        const int gcol=cb0+col, h=gcol>>6, dd=gcol&63;
        const int n=nbase+qq*64+sub*8;
        *(uint4*)&outp[((size_t)(b_*HN+h)*DH+dd)*NS + n]=d4;   // vT [bh][d][n]
      }
    } else {
      float bb4[4];
#pragma unroll
      for(int j=0;j<4;++j) bb4[j]=ld1(bias, cb0+wc*64+j*16+cl, oflag);
      float* dptr=(which==0)? dq_ : dk_;
#pragma unroll
      for(int i=0;i<8;++i){
#pragma unroll
        for(int r=0;r<4;++r){
          const int row=wr*128+i*16+q4*4+r;
          char* rbase=(char*)((row<128)? (void*)(As+row*256) : (void*)(Bs+(row-128)*256));
          const int X=(row&3)<<4;
          float s=0.f;
#pragma unroll
          for(int j=0;j<4;++j){
            const int col=wc*64+j*16+cl;
            const u16 hv=(u16)f2b(acc[i][j][r]+bb4[j]);
            *(u16*)(rbase + ((col*2)^X)) = hv;
            const float fv=b2f(hv);
            s+=fv*fv;
          }
          s+=__shfl_xor(s,1,64); s+=__shfl_xor(s,2,64);
          s+=__shfl_xor(s,4,64); s+=__shfl_xor(s,8,64);
          if(cl==0){
            const int grow=m0+row, b_=grow>>11, n=grow&2047;
            dptr[(size_t)(b_*HN + (cb0>>6)+wc)*NS + n]=0.5f*NRM*NRM*s;
          }
        }
      }
      __syncthreads();
      const int hb=cb0>>6;
#pragma unroll
      for(int tt=0;tt<16;++tt){
        const int task=tt*8+w;
        const int rowg=task>>2, qq=task&3;
        const int row=rowg*8+(l>>3), sub=l&7;
        char* rbase=(char*)((row<128)? (void*)(As+row*256) : (void*)(Bs+(row-128)*256));
        const uint4 d4=*(const uint4*)(rbase + ((qq*128+sub*16)^((row&3)<<4)));
        const int grow=m0+row, b_=grow>>11, n=grow&2047;
        *(uint4*)&outp[((size_t)(b_*HN+hb+qq)*NS+n)*DH + sub*8]=d4;  // [bh][n][d]
      }
    }
  } else {
    if(oflag){
#pragma unroll
      for(int p=0;p<2;++p){
        if(wr==p){
#pragma unroll
          for(int j=0;j<4;++j){
            const int col=wc*64+j*16+cl;
            const float bb=ld1(bias0,n0+col,oflag);
#pragma unroll
            for(int i=0;i<8;++i){
#pragma unroll
              for(int r=0;r<4;++r){
                const int row=i*16+q4*4+r;     // 0..127
                char* rbase=(char*)((row<64)? (void*)(As+row*512) : (void*)(Bs+(row-64)*512));
                *(float*)(rbase + ((col*4)^((row&3)<<4))) = acc[i][j][r]+bb;
              }
            }
          }
        }
        __syncthreads();
#pragma unroll
        for(int tt=0;tt<16;++tt){
          const int task=tt*8+w;
          const int rowg=task>>3, qq=task&7;
          const int row=rowg*8+(l>>3), sub=l&7;
          char* rbase=(char*)((row<64)? (void*)(As+row*512) : (void*)(Bs+(row-64)*512));
          const uint4 d4=*(const uint4*)(rbase + ((qq*128+sub*16)^((row&3)<<4)));
          const size_t grow=(size_t)m0+p*128+row;
          *(uint4*)((char*)outv + (grow*DM+n0)*4 + qq*128 + sub*16)=d4;
        }
        __syncthreads();
      }
    } else {
#pragma unroll
      for(int j=0;j<4;++j){
        const int col=wc*64+j*16+cl;
        const float bb=ld1(bias0,n0+col,oflag);
#pragma unroll
        for(int i=0;i<8;++i){
#pragma unroll
          for(int r=0;r<4;++r){
            const int row=wr*128+i*16+q4*4+r;
            char* rbase=(char*)((row<128)? (void*)(As+row*256) : (void*)(Bs+(row-128)*256));
            *(u16*)(rbase + ((col*2)^((row&3)<<4))) = (u16)f2b(acc[i][j][r]+bb);
          }
        }
      }
      __syncthreads();
#pragma unroll
      for(int tt=0;tt<16;++tt){
        const int task=tt*8+w;
        const int rowg=task>>2, qq=task&3;
        const int row=rowg*8+(l>>3), sub=l&7;
        char* rbase=(char*)((row<128)? (void*)(As+row*256) : (void*)(Bs+(row-128)*256));
        const uint4 d4=*(const uint4*)(rbase + ((qq*128+sub*16)^((row&3)<<4)));
        const int grow=m0+row;
        *(uint4*)((u16*)outv + (size_t)grow*DM + n0 + qq*64 + sub*8)=d4;
      }
    }
  }
}

// ---------------- K2: MFMA xp_k + global max per bh --------------------------
__global__ __launch_bounds__(256) void k_xpk2(const u16* __restrict__ kb,
    const u16* __restrict__ pn, u32* __restrict__ kmax)
{
  __shared__ short Bt[32*512];
  __shared__ short At[8*512];
  __shared__ float red[256];
  const int t=threadIdx.x, l=t&63, w=t>>6;
  const int bh=blockIdx.y, nb0=blockIdx.x*256;
  for(int s=t;s<2048;s+=256){
    const int ub=s>>6, l2=s&63, mt=ub>>1, kh=ub&1;
    const int row=mt*16+(l2&15), kc=kh*32+(l2>>4)*8;
    *(uint4*)&Bt[ub*512+l2*8]=*(const uint4*)(pn + (size_t)row*DH + kc);
  }
  float vmax=-3.4e38f;
  for(int c=0;c<4;++c){
    const int n0=nb0+c*64;
    __syncthreads();
    for(int s=t;s<512;s+=256){
      const int ua=s>>6, l2=s&63, rb=ua>>1, kh=ua&1;
      const int n=n0+rb*16+(l2&15), kc=kh*32+(l2>>4)*8;
      *(uint4*)&At[ua*512+l2*8]=*(const uint4*)(kb + ((size_t)bh*NS+n)*DH + kc);
    }
    __syncthreads();
    const short8 af0=*(short8*)&At[(w*2+0)*512+l*8];
    const short8 af1=*(short8*)&At[(w*2+1)*512+l*8];
#pragma unroll
    for(int mt=0;mt<16;++mt){
      floatx4 a={};
      a=__builtin_amdgcn_mfma_f32_16x16x32_bf16(af0,*(short8*)&Bt[(mt*2+0)*512+l*8],a,0,0,0);
      a=__builtin_amdgcn_mfma_f32_16x16x32_bf16(af1,*(short8*)&Bt[(mt*2+1)*512+l*8],a,0,0,0);
      vmax=fmaxf(vmax,fmaxf(fmaxf(a[0],a[1]),fmaxf(a[2],a[3])));
    }
  }
  red[t]=vmax; __syncthreads();
  for(int s=128;s>0;s>>=1){ if(t<s) red[t]=fmaxf(red[t],red[t+s]); __syncthreads(); }
  if(t==0) atomicMax(kmax+bh, fkey(red[0]));
}

// ---------------- K3 (fallback small path): atomic ctx -----------------------
__global__ __launch_bounds__(256) void k_ctx2(const u16* __restrict__ kb,
    const u16* __restrict__ vT, const u16* __restrict__ pn,
    const float* __restrict__ dkbuf, const u32* __restrict__ kmax,
    float* __restrict__ ctxT, float* __restrict__ ksum)
{
  __shared__ short Bt[32*512];
  __shared__ u16   Ks[256*72];
  __shared__ short AtV[8*512];
  __shared__ float dg[64];
  const int t=threadIdx.x, l=t&63, w=t>>6;
  const int split=blockIdx.x, bh=blockIdx.y;
  for(int s=t;s<2048;s+=256){
    const int ub=s>>6, l2=s&63, mt=ub>>1, kh=ub&1;
    const int row=mt*16+(l2&15), kc=kh*32+(l2>>4)*8;
    *(uint4*)&Bt[ub*512+l2*8]=*(const uint4*)(pn + (size_t)row*DH + kc);
  }
  const float kM=funkey(kmax[bh]);
  float ksr=0.f;
  floatx4 acc2[4][4]={};
  for(int c=0;c<8;++c){
    const int n0=split*512+c*64;
    __syncthreads();
    for(int s=t;s<512;s+=256){
      const int ua=s>>6, l2=s&63, rb=ua>>1, kh=ua&1;
      const int n=n0+rb*16+(l2&15), kc=kh*32+(l2>>4)*8;
      *(uint4*)&AtV[ua*512+l2*8]=*(const uint4*)(kb + ((size_t)bh*NS+n)*DH + kc);
    }
    if(t<64) dg[t]=dkbuf[(size_t)bh*NS+n0+t];
    __syncthreads();
    short8 af[4][2];
#pragma unroll
    for(int rb=0;rb<4;++rb){
      af[rb][0]=*(short8*)&AtV[(rb*2+0)*512+l*8];
      af[rb][1]=*(short8*)&AtV[(rb*2+1)*512+l*8];
    }
    float dgl[16];
#pragma unroll
    for(int rb=0;rb<4;++rb)
#pragma unroll
      for(int r=0;r<4;++r) dgl[rb*4+r]=dg[rb*16+(l>>4)*4+r];
#pragma unroll
    for(int ml=0;ml<4;++ml){
      const int mt=w*4+ml;
      const short8 bf0=*(short8*)&Bt[(mt*2+0)*512+l*8];
      const short8 bf1=*(short8*)&Bt[(mt*2+1)*512+l*8];
      const int m=mt*16+(l&15);
#pragma unroll
      for(int rb=0;rb<4;++rb){
        floatx4 a={};
        a=__builtin_amdgcn_mfma_f32_16x16x32_bf16(af[rb][0],bf0,a,0,0,0);
        a=__builtin_amdgcn_mfma_f32_16x16x32_bf16(af[rb][1],bf1,a,0,0,0);
        const int nb=rb*16+(l>>4)*4;
        const float v0=RATIO*(__expf(a[0]-dgl[rb*4+0]-kM)+EPSV);
        const float v1=RATIO*(__expf(a[1]-dgl[rb*4+1]-kM)+EPSV);
        const float v2=RATIO*(__expf(a[2]-dgl[rb*4+2]-kM)+EPSV);
        const float v3=RATIO*(__expf(a[3]-dgl[rb*4+3]-kM)+EPSV);
        *(u32*)&Ks[m*72+nb]  =f2b(v0)|(f2b(v1)<<16);
        *(u32*)&Ks[m*72+nb+2]=f2b(v2)|(f2b(v3)<<16);
      }
    }
    __syncthreads();
    for(int s=t;s<512;s+=256){
      const int uv=s>>6, l2=s&63, dt=uv>>1, kh=uv&1;
      const int d=dt*16+(l2&15), nn=n0+kh*32+(l2>>4)*8;
      *(uint4*)&AtV[uv*512+l2*8]=*(const uint4*)(vT + ((size_t)bh*DH+d)*NS + nn);
    }
    {
      float s8=0.f;
#pragma unroll
      for(int j=0;j<8;++j){
        const uint4 kk=*(const uint4*)&Ks[t*72+j*8];
        s8+=b2f(kk.x&0xffffu)+b2f(kk.x>>16)+b2f(kk.y&0xffffu)+b2f(kk.y>>16)
           +b2f(kk.z&0xffffu)+b2f(kk.z>>16)+b2f(kk.w&0xffffu)+b2f(kk.w>>16);
      }
      ksr+=s8;
    }
    __syncthreads();
#pragma unroll
    for(int i=0;i<4;++i){
      const int row=(w*4+i)*16+(l&15);
      const short8 a0=*(short8*)&Ks[row*72 + 0*32+(l>>4)*8];
      const short8 a1=*(short8*)&Ks[row*72 + 1*32+(l>>4)*8];
#pragma unroll
      for(int dt=0;dt<4;++dt){
        acc2[i][dt]=__builtin_amdgcn_mfma_f32_16x16x32_bf16(a0,*(short8*)&AtV[(dt*2+0)*512+l*8],acc2[i][dt],0,0,0);
        acc2[i][dt]=__builtin_amdgcn_mfma_f32_16x16x32_bf16(a1,*(short8*)&AtV[(dt*2+1)*512+l*8],acc2[i][dt],0,0,0);
      }
    }
  }
#pragma unroll
  for(int i=0;i<4;++i){
#pragma unroll
    for(int dt=0;dt<4;++dt){
#pragma unroll
      for(int r=0;r<4;++r){
        const int m=(w*4+i)*16+(l>>4)*4+r;
        const int d=dt*16+(l&15);
        atomicAdd(&ctxT[((size_t)bh*DH+d)*MF+m], acc2[i][dt][r]);
      }
    }
  }
  atomicAdd(ksum+bh*MF+t, ksr);
}

// ========== K3n: pipelined non-atomic ctx (big path) =========================
// 4 splits/bh. pn fragments in registers; K/V double-buffered via gl16 prefetch;
// Ks XOR-swizzled (no pad); per-split coalesced f32 slab out (ctxP = dead xb).
__global__ __launch_bounds__(256,2) void k_ctx3(const u16* __restrict__ kb,
    const u16* __restrict__ vT, const u16* __restrict__ pn,
    const float* __restrict__ dkbuf, const u32* __restrict__ kmax,
    float* __restrict__ ctxP, float* __restrict__ ksumP)
{
  __shared__ __align__(16) char SM[66048];
  short* Ks=(short*)SM;                 // 256 x 64 u16, row-xor-swizzled (32768)
  short* Kb=(short*)(SM+32768);         // 2 x 8 x 512 shorts (16384)
  short* Vb=(short*)(SM+49152);         // 2 x 8 x 512 shorts (16384)
  float* dgb=(float*)(SM+65536);        // 2 x 64 f32
  const int t=threadIdx.x, l=t&63, w=t>>6;
  const int split=blockIdx.x, bh=blockIdx.y;
  const int n00=split*512;
  const int lrow=l&15, lk8=(l>>4)*8;
  const u16* kbase = kb + (size_t)bh*NS*DH;
  const u16* vbase = vT + (size_t)bh*DH*NS;
  // pn fragments -> registers (per-wave m range)
  short8 bf[4][2];
#pragma unroll
  for(int ml=0;ml<4;++ml)
#pragma unroll
    for(int kh=0;kh<2;++kh)
      bf[ml][kh]=*(const short8*)(pn + (size_t)((w*4+ml)*16+lrow)*DH + kh*32 + lk8);
  const float kM=funkey(kmax[bh]);
  // prologue: stage c=0
  {
#pragma unroll
    for(int p=0;p<2;++p){
      const int u=w+4*p, rb=u>>1, kh=u&1;
      gl16(kbase + (size_t)(n00+rb*16+lrow)*DH + kh*32+lk8, &Kb[u*512]);
    }
#pragma unroll
    for(int p=0;p<2;++p){
      const int u=w+4*p, dt=u>>1, kh=u&1;
      gl16(vbase + (size_t)(dt*16+lrow)*NS + n00+kh*32+lk8, &Vb[u*512]);
    }
    if(t<64) dgb[t]=dkbuf[(size_t)bh*NS+n00+t];
  }
  __syncthreads();
  float ksr=0.f;
  floatx4 acc2[4][4]={};
  for(int c=0;c<8;++c){
    const int cur=c&1, nxt=cur^1;
    // issue next-tile prefetch first (covered by kp phase)
    if(c<7){
      const int n1=n00+(c+1)*64;
#pragma unroll
      for(int p=0;p<2;++p){
        const int u=w+4*p, rb=u>>1, kh=u&1;
        gl16(kbase + (size_t)(n1+rb*16+lrow)*DH + kh*32+lk8, &Kb[nxt*4096+u*512]);
      }
#pragma unroll
      for(int p=0;p<2;++p){
        const int u=w+4*p, dt=u>>1, kh=u&1;
        gl16(vbase + (size_t)(dt*16+lrow)*NS + n1+kh*32+lk8, &Vb[nxt*4096+u*512]);
      }
    }
    float dgnv=0.f;
    if(c<7 && t<64) dgnv=dkbuf[(size_t)bh*NS+n00+(c+1)*64+t];
    // K fragments + diag
    short8 af[4][2];
#pragma unroll
    for(int rb=0;rb<4;++rb){
      af[rb][0]=*(short8*)&Kb[cur*4096+(rb*2+0)*512+l*8];
      af[rb][1]=*(short8*)&Kb[cur*4096+(rb*2+1)*512+l*8];
    }
    float dgl[16];
#pragma unroll
    for(int rb=0;rb<4;++rb){
      const float4 dv=*(const float4*)&dgb[cur*64+rb*16+(l>>4)*4];
      dgl[rb*4+0]=dv.x; dgl[rb*4+1]=dv.y; dgl[rb*4+2]=dv.z; dgl[rb*4+3]=dv.w;
    }
    // kp = ratio*(exp(xp - diag - kmax)+eps) -> Ks (swizzled)
#pragma unroll
    for(int ml=0;ml<4;++ml){
      const int m=(w*4+ml)*16+lrow;
      char* krow=(char*)Ks + m*128;
      const int xr=(m&7)<<4;
#pragma unroll
      for(int rb=0;rb<4;++rb){
        floatx4 a={};
        a=__builtin_amdgcn_mfma_f32_16x16x32_bf16(af[rb][0],bf[ml][0],a,0,0,0);
        a=__builtin_amdgcn_mfma_f32_16x16x32_bf16(af[rb][1],bf[ml][1],a,0,0,0);
        const float v0=RATIO*(__expf(a[0]-dgl[rb*4+0]-kM)+EPSV);
        const float v1=RATIO*(__expf(a[1]-dgl[rb*4+1]-kM)+EPSV);
        const float v2=RATIO*(__expf(a[2]-dgl[rb*4+2]-kM)+EPSV);
        const float v3=RATIO*(__expf(a[3]-dgl[rb*4+3]-kM)+EPSV);
        const int nb=rb*16+(l>>4)*4;
        const u32 bo=((u32)(nb*2)) ^ xr;
        *(u32*)(krow+bo)  =f2b(v0)|(f2b(v1)<<16);
        *(u32*)(krow+bo+4)=f2b(v2)|(f2b(v3)<<16);
      }
    }
    __syncthreads();
    // ksum over own row
    {
      char* krow=(char*)Ks + t*128;
      const int xr=(t&7)<<4;
      float s8=0.f;
#pragma unroll
      for(int j=0;j<8;++j){
        const uint4 kk=*(const uint4*)(krow + ((j*16)^xr));
        s8+=b2f(kk.x&0xffffu)+b2f(kk.x>>16)+b2f(kk.y&0xffffu)+b2f(kk.y>>16)
           +b2f(kk.z&0xffffu)+b2f(kk.z>>16)+b2f(kk.w&0xffffu)+b2f(kk.w>>16);
      }
      ksr+=s8;
    }
    // ctx += Ks^T x V
#pragma unroll
    for(int i=0;i<4;++i){
      const int row=(w*4+i)*16+lrow;
      char* krow=(char*)Ks + row*128;
      const int xr=(row&7)<<4;
      const short8 a0=*(short8*)(krow + (((l>>4)*16)^xr));
      const short8 a1=*(short8*)(krow + ((64+(l>>4)*16)^xr));
#pragma unroll
      for(int dt=0;dt<4;++dt){
        acc2[i][dt]=__builtin_amdgcn_mfma_f32_16x16x32_bf16(a0,*(short8*)&Vb[cur*4096+(dt*2+0)*512+l*8],acc2[i][dt],0,0,0);
        acc2[i][dt]=__builtin_amdgcn_mfma_f32_16x16x32_bf16(a1,*(short8*)&Vb[cur*4096+(dt*2+1)*512+l*8],acc2[i][dt],0,0,0);
      }
    }
    if(c<7 && t<64) dgb[nxt*64+t]=dgnv;
    __syncthreads();
  }
  // restage acc2 -> LDS (aliases Ks/Kb/Vb) -> coalesced slab out
  {
    float* OUT=(float*)SM;
#pragma unroll
    for(int i=0;i<4;++i){
      const int mb=(w*4+i)*16+(l>>4)*4;
#pragma unroll
      for(int dt=0;dt<4;++dt){
        const int d=dt*16+lrow;
        float4 o; o.x=acc2[i][dt][0]; o.y=acc2[i][dt][1]; o.z=acc2[i][dt][2]; o.w=acc2[i][dt][3];
        *(float4*)((char*)OUT + d*1024 + ((mb*4)^((d&15)<<4))) = o;
      }
    }
    __syncthreads();
    float* gout = ctxP + (size_t)(split*BH+bh)*64*256;
#pragma unroll
    for(int s=0;s<16;++s){
      const int d=s*4+w;
      const uint4 o4=*(const uint4*)((char*)OUT + d*1024 + ((l*16)^((d&15)<<4)));
      *(uint4*)(gout + (size_t)d*256 + l*4)=o4;
    }
    ksumP[(size_t)(split*BH+bh)*256 + t]=ksr;
  }
}

// ---------------- K3b (fallback small path) ----------------------------------
__global__ __launch_bounds__(256) void k_csplit(const float* __restrict__ ctxT,
    u16* __restrict__ chi, u16* __restrict__ clo, float* __restrict__ ecs)
{
  __shared__ float cred[256];
  const int bh=blockIdx.x, t=threadIdx.x;
  const int d=t>>2, part=t&3;
  const size_t base=((size_t)bh*DH+d)*MF + part*64;
  const float* src=ctxT + base;
  u16* ph=chi + base;
  u16* pl=clo + base;
  float cs=0.f;
  for(int m=0;m<64;m+=4){
    float4 v=*(const float4*)(src+m);
    float vv[4]={v.x,v.y,v.z,v.w};
    u32 h_[4], l_[4];
#pragma unroll
    for(int j=0;j<4;++j){
      cs+=vv[j];
      u32 hh=f2b(vv[j]);
      float rr=vv[j]-b2f(hh);
      h_[j]=hh; l_[j]=f2b(rr);
    }
    uint2 sh, sl;
    sh.x=h_[0]|(h_[1]<<16); sh.y=h_[2]|(h_[3]<<16);
    sl.x=l_[0]|(l_[1]<<16); sl.y=l_[2]|(l_[3]<<16);
    *(uint2*)(ph+m)=sh; *(uint2*)(pl+m)=sl;
  }
  cred[t]=cs; __syncthreads();
  if(part==0) ecs[bh*64+d]=EPSV*(cred[t]+cred[t+1]+cred[t+2]+cred[t+3]);
}

// ---------------- K3c: reduce 4 split partials -> chi/clo/ecs/ksum -----------
__global__ __launch_bounds__(256) void k_csplit3(const float* __restrict__ ctxP,
    const float* __restrict__ ksumP,
    u16* __restrict__ chi, u16* __restrict__ clo, float* __restrict__ ecs,
    float* __restrict__ ksum)
{
  __shared__ float wred[16][4];
  const int bh=blockIdx.y, dq=blockIdx.x;
  const int t=threadIdx.x, l=t&63, w=t>>6;
  if(dq==0){
    float kv=0.f;
#pragma unroll
    for(int s=0;s<4;++s) kv+=ksumP[(size_t)(s*BH+bh)*256+t];
    ksum[bh*MF+t]=kv;
  }
#pragma unroll
  for(int d16=0;d16<16;++d16){
    const int d=dq*16+d16;
    float v=0.f;
#pragma unroll
    for(int s=0;s<4;++s) v+=ctxP[((size_t)(s*BH+bh)*64+d)*256+t];
    const u32 hh=f2b(v);
    const float rr=v-b2f(hh);
    const size_t ob=((size_t)bh*DH+d)*MF+t;
    chi[ob]=(u16)hh; clo[ob]=(u16)f2b(rr);
    float s_=v;
    s_+=__shfl_xor(s_,1,64); s_+=__shfl_xor(s_,2,64); s_+=__shfl_xor(s_,4,64);
    s_+=__shfl_xor(s_,8,64); s_+=__shfl_xor(s_,16,64); s_+=__shfl_xor(s_,32,64);
    if(l==0) wred[d16][w]=s_;
  }
  __syncthreads();
  if(t<16) ecs[bh*64+dq*16+t]=EPSV*(wred[t][0]+wred[t][1]+wred[t][2]+wred[t][3]);
}

// ---------------- K4: MFMA fused qp + D_inv + attn ---------------------------
__global__ __launch_bounds__(256) void k_attn2(const u16* __restrict__ qb,
    const u16* __restrict__ pn, const float* __restrict__ dqbuf,
    const float* __restrict__ ksum, const u16* __restrict__ chi, const u16* __restrict__ clo,
    const float* __restrict__ ecs, u16* __restrict__ attn)
{
  __shared__ short At[8*512];
  __shared__ u16 Qf[32*512];
  __shared__ float ksums[256];
  __shared__ float dq_s[64];
  __shared__ float mxs[4][64];
  __shared__ float s1s[4][64];
  __shared__ float a_s[64], dinv_s[64], ec_s[64];
  __shared__ float red4[4];
  __shared__ float epkss;
  const int t=threadIdx.x, l=t&63, w=t>>6;
  const int bh=blockIdx.y, nb0=blockIdx.x*256;
  const int b_=bh/HN, h=bh%HN;
  {
    float kv=ksum[bh*MF+t];
    ksums[t]=kv;
    if(t<64) ec_s[t]=ecs[bh*64+t];
    float s=kv;
#pragma unroll
    for(int o=1;o<64;o<<=1) s+=__shfl_xor(s,o,64);
    if(l==0) red4[w]=s;
  }
  __syncthreads();
  if(t==0) epkss=EPSV*(red4[0]+red4[1]+red4[2]+red4[3]);
  short8 bhf[8], blf[8];
  {
    const int d=w*16+(l&15);
    const size_t base=((size_t)bh*DH+d)*MF;
#pragma unroll
    for(int kc=0;kc<8;++kc){
      const size_t off=base + kc*32+(l>>4)*8;
      bhf[kc]=*(const short8*)(chi+off);
      blf[kc]=*(const short8*)(clo+off);
    }
  }
  for(int c=0;c<4;++c){
    const int n0c=nb0+c*64;
    __syncthreads();
    for(int s=t;s<512;s+=256){
      const int ua=s>>6, l2=s&63, nt=ua>>1, kh=ua&1;
      const int n=n0c+nt*16+(l2&15), kc=kh*32+(l2>>4)*8;
      *(uint4*)&At[ua*512+l2*8]=*(const uint4*)(qb + ((size_t)bh*NS+n)*DH + kc);
    }
    if(t<64) dq_s[t]=dqbuf[(size_t)bh*NS+n0c+t];
    __syncthreads();
    float mxl[4]={-3.4e38f,-3.4e38f,-3.4e38f,-3.4e38f};
    float s1l[4]={0.f,0.f,0.f,0.f};
#pragma unroll
    for(int mt=0;mt<4;++mt){
      const int gm=w*4+mt;
      const u16* pr=pn + ((gm*16+(l&15))<<6) + (l>>4)*8;
      const short8 a0=*(const short8*)(pr);
      const short8 a1=*(const short8*)(pr+32);
      float k4[4];
#pragma unroll
      for(int r=0;r<4;++r) k4[r]=ksums[gm*16+(l>>4)*4+r];
      const int mbase=(gm&1)*16+(l>>4)*4;
      const int lane2=((mbase>>3)*16+(l&15))*8 + (mbase&7);
#pragma unroll
      for(int nt=0;nt<4;++nt){
        floatx4 xp={};
        xp=__builtin_amdgcn_mfma_f32_16x16x32_bf16(a0,*(short8*)&At[(nt*2+0)*512+l*8],xp,0,0,0);
        xp=__builtin_amdgcn_mfma_f32_16x16x32_bf16(a1,*(short8*)&At[(nt*2+1)*512+l*8],xp,0,0,0);
        const float dq=dq_s[nt*16+(l&15)];
        float ev[4];
#pragma unroll
        for(int r=0;r<4;++r){
          const float xv=xp[r];
          mxl[nt]=fmaxf(mxl[nt],xv);
          ev[r]=__expf(xv-dq);
          s1l[nt]+=ev[r]*k4[r];
        }
        u16* qp_=&Qf[(nt*8+(gm>>1))*512 + lane2];
        *(u32*)qp_    =f2b(ev[0])|(f2b(ev[1])<<16);
        *(u32*)(qp_+2)=f2b(ev[2])|(f2b(ev[3])<<16);
      }
    }
#pragma unroll
    for(int nt=0;nt<4;++nt){
      float m_=mxl[nt], s_=s1l[nt];
      m_=fmaxf(m_,__shfl_xor(m_,16,64)); s_+=__shfl_xor(s_,16,64);
      m_=fmaxf(m_,__shfl_xor(m_,32,64)); s_+=__shfl_xor(s_,32,64);
      if(l<16){ mxs[w][nt*16+l]=m_; s1s[w][nt*16+l]=s_; }
    }
    __syncthreads();
    if(t<64){
      float m_=fmaxf(fmaxf(mxs[0][t],mxs[1][t]),fmaxf(mxs[2][t],mxs[3][t]));
      float s_=s1s[0][t]+s1s[1][t]+s1s[2][t]+s1s[3][t];
      float a=__expf(-m_);
      a_s[t]=a;
      dinv_s[t]=1.0f/(a*s_+epkss);
    }
    __syncthreads();
    const int d=w*16+(l&15);
    const float ec=ec_s[d];
#pragma unroll
    for(int nt=0;nt<4;++nt){
      floatx4 y={};
#pragma unroll
      for(int kc=0;kc<8;++kc){
        const short8 e=*(short8*)&Qf[(nt*8+kc)*512+l*8];
        y=__builtin_amdgcn_mfma_f32_16x16x32_bf16(e,bhf[kc],y,0,0,0);
        y=__builtin_amdgcn_mfma_f32_16x16x32_bf16(e,blf[kc],y,0,0,0);
      }
#pragma unroll
      for(int r=0;r<4;++r){
        const int nl=nt*16+(l>>4)*4+r;
        const float val=(a_s[nl]*y[r]+ec)*dinv_s[nl];
        attn[((size_t)(b_*NS+n0c+nl))*DM + h*DH + d]=(u16)f2b(val);
      }
    }
  }
}

extern "C" void kernel_launch(void* const* d_in, const int* in_sizes, int n_in,
                              void* d_out, int out_size, void* d_ws, size_t ws_size,
                              hipStream_t stream)
{
  (void)in_sizes; (void)n_in; (void)out_size;
  const void* x =d_in[0];
  const void* Wq=d_in[1]; const void* bq=d_in[2];
  const void* Wk=d_in[3]; const void* bk=d_in[4];
  const void* Wv=d_in[5]; const void* bv=d_in[6];
  const void* Wo=d_in[7]; const void* bo=d_in[8];
  const void* proj=d_in[9];

  char* ws=(char*)d_ws;
  const size_t SZ=(size_t)BN*DM*2;               // 25,165,824 B
  const size_t AUXSZ=19030528;
  const bool big = ws_size >= 4*SZ + AUXSZ;      // ~119.7 MB
  u16*   qb  =(u16*)(ws);
  u16*   kb  =(u16*)(ws+SZ);
  u16*   vb  =(u16*)(ws+2*SZ);                   // v^T [bh][d][n]
  u16*   xb  =(u16*)(ws+3*SZ);                   // bf16 x (big path only)
  char*  aux = big ? (ws+4*SZ) : (ws+3*SZ);
  u16*   wb   =(u16*)(aux);                      // 3,538,944
  u16*   wob  =(u16*)(aux+3538944);              // -> 4,718,592
  float* ctxT =(float*)(aux+4718592);            // -> 11,010,048
  float* ksum =(float*)(aux+11010048);           // -> 11,108,352
  u32*   kmax =(u32*)(aux+11108352);             // -> 11,108,736
  int*   flag =(int*)(aux+11108736);             // -> 11,108,864
  float* dk   =(float*)(aux+11108864);           // -> 11,895,296
  float* dqq  =(float*)(aux+11895296);           // -> 12,681,728
  u16*   pn   =(u16*)(aux+12681728);             // -> 12,714,496
  u16*   chi  =(u16*)(aux+12714496);             // -> 15,860,224
  u16*   clo  =(u16*)(aux+15860224);             // -> 19,005,952
  float* ecs  =(float*)(aux+19005952);           // -> 19,030,528
  u16*   attnb = big ? xb : kb;                  // dead buffer reuse

  k_detect<<<1,64,0,stream>>>((const u16*)x, flag);
  if(big) hipMemsetAsync(kmax, 0, 384, stream);
  else    hipMemsetAsync(ctxT, 0, 6291456+98304+384, stream);
  k_cvtw <<<1152, 256, 0, stream>>>(Wq,Wk,Wv,Wo,wb,wob,flag);
  k_cvtp <<<8, 256, 0, stream>>>(proj, pn, flag);
  if(big){
    k_cvtx <<<(BN*DM)/2048, 256, 0, stream>>>(x, xb, flag);
    k_gemm8<<<dim3(BN/256,2304/256), 512, 0, stream>>>(xb, wb, bq,bk,bv, qb,kb,vb, nullptr, flag, 0, dqq, dk);
  }else{
    k_gemm_f<<<dim3(BN/128,2304/128), 256, 0, stream>>>(x, wb, bq,bk,bv, qb,kb,vb, nullptr, flag, 0);
    k_diag <<<(BH*NS)/256, 256, 0, stream>>>(kb, dk);
    k_diag <<<(BH*NS)/256, 256, 0, stream>>>(qb, dqq);
  }
  k_xpk2 <<<dim3(NS/256,BH), 256, 0, stream>>>(kb, pn, kmax);
  if(big){
    float* ctxP =(float*)xb;     // xb dead between qkv-gemm and attn2: exactly 4*96*64*256*4 B
    float* ksumP=ctxT;           // reuse aux ctxT region (393,216 B needed)
    k_ctx3 <<<dim3(4,BH), 256, 0, stream>>>(kb, vb, pn, dk, kmax, ctxP, ksumP);
    k_csplit3<<<dim3(4,BH), 256, 0, stream>>>(ctxP, ksumP, chi, clo, ecs, ksum);
  }else{
    k_ctx2 <<<dim3(4,BH), 256, 0, stream>>>(kb, vb, pn, dk, kmax, ctxT, ksum);
    k_csplit<<<BH, 256, 0, stream>>>(ctxT, chi, clo, ecs);
  }
  k_attn2<<<dim3(NS/256,BH), 256, 0, stream>>>(qb, pn, dqq, ksum, chi, clo, ecs, attnb);
  if(big){
    k_gemm8<<<dim3(BN/256,DM/256), 512, 0, stream>>>(attnb, wob, bo,bo,bo, nullptr,nullptr,nullptr, d_out, flag, 1, nullptr, nullptr);
  }else{
    k_gemm2<<<dim3(BN/128,DM/128), 256, 0, stream>>>(attnb, wob, bo,bo,bo, nullptr,nullptr,nullptr, d_out, flag, 1);
  }
}

// Round 5
// 412.878 us; speedup vs baseline: 1.3308x; 1.0061x over previous
//
#include <hip/hip_runtime.h>
#include <stdint.h>

typedef unsigned short u16;
typedef unsigned int u32;
typedef __attribute__((ext_vector_type(8))) short short8;
typedef __attribute__((ext_vector_type(4))) float floatx4;

#define HN 12
#define DH 64
#define DM 768
#define NS 2048
#define NB 8
#define MF 256
#define BN (NB*NS)
#define BH (NB*HN)

#define NRM 0.35355339059327373f  /* 64^-0.25 */
#define RATIO 0.0625f             /* 256^-0.5 */
#define EPSV 1e-4f

__device__ __forceinline__ float b2f(u32 u){ union{u32 i; float f;} x; x.i=u<<16; return x.f; }
__device__ __forceinline__ u32 f2b(float v){ union{float f; u32 u;} x; x.f=v; return (x.u + 0x7FFFu + ((x.u>>16)&1u))>>16; }
__device__ __forceinline__ u32 fkey(float v){ union{float f; u32 u;} x; x.f=v; return (x.u&0x80000000u)? ~x.u : (x.u|0x80000000u); }
__device__ __forceinline__ float funkey(u32 k){ union{u32 u; float f;} x; x.u=(k&0x80000000u)? (k^0x80000000u) : ~k; return x.f; }
__device__ __forceinline__ void bld8(uint4 r, float s, float* f){
  f[0]=b2f(r.x&0xffffu)*s; f[1]=b2f(r.x>>16)*s;
  f[2]=b2f(r.y&0xffffu)*s; f[3]=b2f(r.y>>16)*s;
  f[4]=b2f(r.z&0xffffu)*s; f[5]=b2f(r.z>>16)*s;
  f[6]=b2f(r.w&0xffffu)*s; f[7]=b2f(r.w>>16)*s;
}
__device__ __forceinline__ void load8(const void* base, size_t idx, int isf32, float s, float* f){
  if(isf32){
    const float* p=(const float*)base + idx;
    const float4 u=((const float4*)p)[0], v=((const float4*)p)[1];
    f[0]=u.x*s; f[1]=u.y*s; f[2]=u.z*s; f[3]=u.w*s;
    f[4]=v.x*s; f[5]=v.y*s; f[6]=v.z*s; f[7]=v.w*s;
  }else{
    uint4 r=*(const uint4*)((const u16*)base+idx);
    bld8(r,s,f);
  }
}
__device__ __forceinline__ float ld1(const void* base, int idx, int isf32){
  return isf32 ? ((const float*)base)[idx] : b2f((u32)((const u16*)base)[idx]);
}
// async global->LDS, 16B/lane; l must be wave-uniform, data lands at l + lane*16B
__device__ __forceinline__ void gl16(const void* g, void* l){
  __builtin_amdgcn_global_load_lds(
    (const __attribute__((address_space(1))) u32*)g,
    (__attribute__((address_space(3))) u32*)l, 16, 0, 0);
}

// ---------------- K0: detect input dtype (0=bf16, 1=f32) ---------------------
__global__ __launch_bounds__(64) void k_detect(const u16* __restrict__ x, int* __restrict__ flag)
{
  __shared__ int w[64], z[64];
  const int t=threadIdx.x;
  int wild=0, zero=0;
  for(int i=t;i<256;i+=64){
    u32 u=(u32)x[2*i];
    u32 e=(u>>7)&0xFFu;
    if(e>=0x90u) wild++;
    if((u&0x7FFFu)==0u) zero++;
  }
  w[t]=wild; z[t]=zero; __syncthreads();
  if(t==0){
    int W=0,Z=0;
    for(int i=0;i<64;++i){W+=w[i];Z+=z[i];}
    flag[0]=(W>16||Z>200)?1:0;
  }
}

// ---------------- K0b: convert weights to bf16 (wb=[Wq;Wk;Wv], wob=Wo) ------
__global__ __launch_bounds__(256) void k_cvtw(const void* __restrict__ Wq,
    const void* __restrict__ Wk, const void* __restrict__ Wv, const void* __restrict__ Wo,
    u16* __restrict__ wb, u16* __restrict__ wob, const int* __restrict__ flagp)
{
  const int isf32=*flagp;
  const size_t WSZ=(size_t)DM*DM;
  size_t idx=((size_t)blockIdx.x*256+threadIdx.x)*8;
  const void* src; size_t off; u16* dst;
  if(idx<3*WSZ){ int w=(int)(idx/WSZ); src=(w==0)?Wq:((w==1)?Wk:Wv); off=idx-(size_t)w*WSZ; dst=wb+idx; }
  else { src=Wo; off=idx-3*WSZ; dst=wob+off; }
  if(isf32){
    const float* p=(const float*)src+off;
    float4 u=((const float4*)p)[0], v=((const float4*)p)[1];
    uint4 st;
    st.x=f2b(u.x)|(f2b(u.y)<<16); st.y=f2b(u.z)|(f2b(u.w)<<16);
    st.z=f2b(v.x)|(f2b(v.y)<<16); st.w=f2b(v.z)|(f2b(v.w)<<16);
    *(uint4*)dst=st;
  }else{
    *(uint4*)dst=*(const uint4*)((const u16*)src+off);
  }
}

// ---------------- K0c: pn = proj * NRM, bf16 [256][64] -----------------------
__global__ __launch_bounds__(256) void k_cvtp(const void* __restrict__ proj,
    u16* __restrict__ pn, const int* __restrict__ flagp)
{
  const int isf32=*flagp;
  const size_t idx=((size_t)blockIdx.x*256+threadIdx.x)*8;
  float pf[8];
  load8(proj, idx, isf32, NRM, pf);
  uint4 st;
  st.x=f2b(pf[0])|(f2b(pf[1])<<16); st.y=f2b(pf[2])|(f2b(pf[3])<<16);
  st.z=f2b(pf[4])|(f2b(pf[5])<<16); st.w=f2b(pf[6])|(f2b(pf[7])<<16);
  *(uint4*)(pn+idx)=st;
}

// ---------------- K0e: xb = bf16(x) ------------------------------------------
__global__ __launch_bounds__(256) void k_cvtx(const void* __restrict__ x,
    u16* __restrict__ xb, const int* __restrict__ flagp)
{
  const int isf32=*flagp;
  const size_t idx=((size_t)blockIdx.x*256+threadIdx.x)*8;   // over BN*DM
  float f[8];
  load8(x, idx, isf32, 1.0f, f);
  uint4 st;
  st.x=f2b(f[0])|(f2b(f[1])<<16); st.y=f2b(f[2])|(f2b(f[3])<<16);
  st.z=f2b(f[4])|(f2b(f[5])<<16); st.w=f2b(f[6])|(f2b(f[7])<<16);
  *(uint4*)(xb+idx)=st;
}

// ---------------- K0d: dk[row] = 0.5*NRM^2*sum(v^2) over DH (fallback path) --
__global__ __launch_bounds__(256) void k_diag(const u16* __restrict__ src, float* __restrict__ dk)
{
  const size_t row=(size_t)blockIdx.x*256+threadIdx.x;
  const u16* p=src+row*DH;
  float s=0.f;
#pragma unroll
  for(int c=0;c<DH;c+=8){
    uint4 r=*(const uint4*)(p+c);
    float f[8]; bld8(r,1.0f,f);
#pragma unroll
    for(int j=0;j<8;++j) s+=f[j]*f[j];
  }
  dk[row]=0.5f*NRM*NRM*s;
}

// ======== shared epilogue for the two 128-tile fallback MFMA GEMMs ===========
__device__ __forceinline__ void gemm_epilogue(const floatx4 acc[4][4], int mode, int oflag,
    int m0, int n0, int l, int wr4, int wc4,
    const void* bias0, const void* bias1, const void* bias2,
    u16* q, u16* k, u16* v, void* outv)
{
  const int rbase=(l>>4)*4, cl=l&15;
  if(mode==0){
    const int which=n0/DM;
    const void* bias=(which==0)?bias0:((which==1)?bias1:bias2);
    u16* outp=(which==0)?q:((which==1)?k:v);
    const int cb=n0-which*DM;
#pragma unroll
    for(int j=0;j<4;++j){
      const int col=cb+(wc4+j)*16+cl;
      const int h=col>>6, dd=col&63;
      const float bb=ld1(bias,col,oflag);
#pragma unroll
      for(int i=0;i<4;++i){
#pragma unroll
        for(int r=0;r<4;++r){
          const int grow=m0+(wr4+i)*16+rbase+r;
          const int b_=grow>>11, n=grow&2047;
          const u16 val=(u16)f2b(acc[i][j][r]+bb);
          if(which==2) outp[((size_t)(b_*HN+h)*DH+dd)*NS + n]=val;       // vT [bh][d][n]
          else         outp[((size_t)((b_*HN+h)*NS+n))*DH + dd]=val;     // [bh][n][d]
        }
      }
    }
  }else{
#pragma unroll
    for(int j=0;j<4;++j){
      const int col=n0+(wc4+j)*16+cl;
      const float bb=ld1(bias0,col,oflag);
#pragma unroll
      for(int i=0;i<4;++i){
#pragma unroll
        for(int r=0;r<4;++r){
          const int grow=m0+(wr4+i)*16+rbase+r;
          const float val=acc[i][j][r]+bb;
          if(oflag) ((float*)outv)[(size_t)grow*DM+col]=val;
          else      ((u16*)outv)[(size_t)grow*DM+col]=(u16)f2b(val);
        }
      }
    }
  }
}

// ---------------- K1: MFMA GEMM, 128-tile (fallback) -------------------------
__global__ __launch_bounds__(256) void k_gemm2(const u16* __restrict__ A16,
    const u16* __restrict__ B16,
    const void* __restrict__ bias0, const void* __restrict__ bias1, const void* __restrict__ bias2,
    u16* __restrict__ q, u16* __restrict__ k, u16* __restrict__ v,
    void* __restrict__ outv, const int* __restrict__ flagp, const int mode)
{
  __shared__ short At[16*512];
  __shared__ short Bt[16*512];
  const int oflag=*flagp;
  const int t=threadIdx.x, l=t&63, w=t>>6;
  const int m0=blockIdx.x*128, n0=blockIdx.y*128;
  const int wr4=(w>>1)*4, wc4=(w&1)*4;
  const int srow=l&15, skg=l>>4;
  floatx4 acc[4][4]={};
  for(int k0=0;k0<DM;k0+=64){
    __syncthreads();
#pragma unroll
    for(int s=0;s<4;++s){
      const int bi=w*4+s, rb=bi>>1, kh=bi&1;
      const int kc=k0+kh*32+skg*8;
      gl16(A16 + (size_t)(m0+rb*16+srow)*DM + kc, &At[bi*512]);
      gl16(B16 + (size_t)(n0+rb*16+srow)*DM + kc, &Bt[bi*512]);
    }
    __syncthreads();
#pragma unroll
    for(int kh=0;kh<2;++kh){
      short8 af[4], bf[4];
#pragma unroll
      for(int i=0;i<4;++i) af[i]=*(short8*)&At[((wr4+i)*2+kh)*512+l*8];
#pragma unroll
      for(int j=0;j<4;++j) bf[j]=*(short8*)&Bt[((wc4+j)*2+kh)*512+l*8];
#pragma unroll
      for(int i=0;i<4;++i)
#pragma unroll
        for(int j=0;j<4;++j)
          acc[i][j]=__builtin_amdgcn_mfma_f32_16x16x32_bf16(af[i],bf[j],acc[i][j],0,0,0);
    }
  }
  gemm_epilogue(acc,mode,oflag,m0,n0,l,wr4,wc4,bias0,bias1,bias2,q,k,v,outv);
}

// ---------------- K1f: fallback MFMA GEMM, f32-capable A ---------------------
__global__ __launch_bounds__(256) void k_gemm_f(const void* __restrict__ Araw,
    const u16* __restrict__ B16,
    const void* __restrict__ bias0, const void* __restrict__ bias1, const void* __restrict__ bias2,
    u16* __restrict__ q, u16* __restrict__ k, u16* __restrict__ v,
    void* __restrict__ outv, const int* __restrict__ flagp, const int mode)
{
  __shared__ short At[16*512];
  __shared__ short Bt[16*512];
  const int oflag=*flagp;
  const int isf32=(mode==0)?oflag:0;
  const int t=threadIdx.x, l=t&63, w=t>>6;
  const int m0=blockIdx.x*128, n0=blockIdx.y*128;
  const int wr4=(w>>1)*4, wc4=(w&1)*4;
  const int srow=l&15, skg=l>>4;
  floatx4 acc[4][4]={};
  for(int k0=0;k0<DM;k0+=64){
    __syncthreads();
#pragma unroll
    for(int s=0;s<4;++s){
      const int bi=w*4+s, rb=bi>>1, kh=bi&1;
      const int kc=k0+kh*32+skg*8;
      uint4 va;
      if(isf32){
        const float* ap=(const float*)Araw + (size_t)(m0+rb*16+srow)*DM + kc;
        float4 u=((const float4*)ap)[0], vv=((const float4*)ap)[1];
        va.x=f2b(u.x)|(f2b(u.y)<<16);  va.y=f2b(u.z)|(f2b(u.w)<<16);
        va.z=f2b(vv.x)|(f2b(vv.y)<<16); va.w=f2b(vv.z)|(f2b(vv.w)<<16);
      }else{
        va=*(const uint4*)((const u16*)Araw + (size_t)(m0+rb*16+srow)*DM + kc);
      }
      const uint4 vb=*(const uint4*)(B16 + (size_t)(n0+rb*16+srow)*DM + kc);
      *(uint4*)&At[bi*512+l*8]=va;
      *(uint4*)&Bt[bi*512+l*8]=vb;
    }
    __syncthreads();
#pragma unroll
    for(int kh=0;kh<2;++kh){
      short8 af[4], bf[4];
#pragma unroll
      for(int i=0;i<4;++i) af[i]=*(short8*)&At[((wr4+i)*2+kh)*512+l*8];
#pragma unroll
      for(int j=0;j<4;++j) bf[j]=*(short8*)&Bt[((wc4+j)*2+kh)*512+l*8];
#pragma unroll
      for(int i=0;i<4;++i)
#pragma unroll
        for(int j=0;j<4;++j)
          acc[i][j]=__builtin_amdgcn_mfma_f32_16x16x32_bf16(af[i],bf[j],acc[i][j],0,0,0);
    }
  }
  gemm_epilogue(acc,mode,oflag,m0,n0,l,wr4,wc4,bias0,bias1,bias2,q,k,v,outv);
}

// ================= K1g: 256x256 4-phase pipelined MFMA GEMM ==================
// Same verified gl16-unit order + vmcnt(8/4/0) stream as round-1; (O,E) phase
// pairs merged: 24 phases of {12 ds_read || stage 1 unit (A+B) -> WV -> barrier
// -> lgkm0 -> 32 MFMA -> barrier}. Halves barrier/drain count per block.
#define SBOFF(slot,kh,mf) ((((slot)*32)+((kh)*16)+(mf))*512)
#define STA(kt,kh) do{ \
  const int o_=SBOFF((kt)&1,(kh),0); \
  const size_t g_=(size_t)(kt)*64+(size_t)(kh)*32; \
  gl16(Ar0+g_, &As[o_+w*512]); \
  gl16(Ar0+(size_t)128*768+g_, &As[o_+(8+w)*512]); \
}while(0)
#define STB(kt,kh) do{ \
  const int o_=SBOFF((kt)&1,(kh),0); \
  const size_t g_=(size_t)(kt)*64+(size_t)(kh)*32; \
  gl16(Br0+g_, &Bs[o_+w*512]); \
  gl16(Br0+(size_t)128*768+g_, &Bs[o_+(8+w)*512]); \
}while(0)
#define STAB(kt,kh) do{ STA(kt,kh); STB(kt,kh); }while(0)
#define LDA8(kt,kh) do{ const int o_=SBOFF((kt)&1,(kh),wr*8)+l*8; \
  _Pragma("unroll") for(int i_=0;i_<8;++i_) a[i_]=*(short8*)&As[o_+i_*512]; }while(0)
#define LDB4(kt,kh) do{ const int o_=SBOFF((kt)&1,(kh),wc*4)+l*8; \
  b[0]=*(short8*)&Bs[o_]; b[1]=*(short8*)&Bs[o_+512]; \
  b[2]=*(short8*)&Bs[o_+1024]; b[3]=*(short8*)&Bs[o_+1536]; }while(0)
#define MM(np) do{ _Pragma("unroll") for(int i_=0;i_<8;++i_){ \
  acc[i_][(np)*2+0]=__builtin_amdgcn_mfma_f32_16x16x32_bf16(a[i_],b[(np)*2+0],acc[i_][(np)*2+0],0,0,0); \
  acc[i_][(np)*2+1]=__builtin_amdgcn_mfma_f32_16x16x32_bf16(a[i_],b[(np)*2+1],acc[i_][(np)*2+1],0,0,0); } }while(0)
#define FEN asm volatile("" ::: "memory")
#define BARR do{ FEN; __builtin_amdgcn_s_barrier(); FEN; }while(0)
#define WV8 asm volatile("s_waitcnt vmcnt(8)" ::: "memory")
#define WV4 asm volatile("s_waitcnt vmcnt(4)" ::: "memory")
#define WV0 asm volatile("s_waitcnt vmcnt(0)" ::: "memory")
#define WL0 do{ asm volatile("s_waitcnt lgkmcnt(0)" ::: "memory"); __builtin_amdgcn_sched_barrier(0); }while(0)
#define PH4(kt,kh,SST,WST) do{ LDA8(kt,kh); LDB4(kt,kh); SST; WST; BARR; WL0; \
  __builtin_amdgcn_s_setprio(1); MM(0); MM(1); __builtin_amdgcn_s_setprio(0); BARR; }while(0)

__global__ __launch_bounds__(512,2) void k_gemm8(const u16* __restrict__ A16,
    const u16* __restrict__ B16,
    const void* __restrict__ bias0, const void* __restrict__ bias1, const void* __restrict__ bias2,
    u16* __restrict__ q, u16* __restrict__ k, u16* __restrict__ v,
    void* __restrict__ outv, const int* __restrict__ flagp, const int mode,
    float* __restrict__ dq_, float* __restrict__ dk_)
{
  __shared__ short As[2*2*16*512];   // 64 KiB
  __shared__ short Bs[2*2*16*512];   // 64 KiB
  const int oflag=*flagp;
  const int t=threadIdx.x, l=t&63, w=t>>6;
  const int wr=w>>2, wc=w&3;
  const int lrow=l&15, lk8=(l>>4)*8;
  int bid = blockIdx.y*gridDim.x + blockIdx.x;
  const int nwg = gridDim.x*gridDim.y;       // 576 (mode0) / 192 (mode1), %8==0
  const int nN  = gridDim.y;                 // 9 / 3
  bid = (bid&7)*(nwg>>3) + (bid>>3);
  const int mi = bid/nN;
  const int m0 = mi*256;
  const int n0 = (bid - mi*nN)*256;

  const u16* Ar0 = A16 + (size_t)(m0 + w*16 + lrow)*768 + lk8;
  const u16* Br0 = B16 + (size_t)(n0 + w*16 + lrow)*768 + lk8;
  floatx4 acc[8][4]={};
  short8 a[8], b[4];

  STA(0,0); STB(0,0); STA(0,1); STB(0,1); STA(1,0); STB(1,0);
  WV8; BARR;

  for(int i=0;i<5;++i){
    const int kt=2*i;
    PH4(kt,0,   STAB(kt+1,1), WV8);
    PH4(kt,1,   STAB(kt+2,0), WV8);
    PH4(kt+1,0, STAB(kt+2,1), WV8);
    PH4(kt+1,1, STAB(kt+3,0), WV8);
  }
  PH4(10,0, STAB(11,1), WV8);
  PH4(10,1, (void)0, WV4);
  PH4(11,0, (void)0, WV0);
  PH4(11,1, (void)0, (void)0);

  // ============ epilogue: LDS restage -> coalesced wide stores ===============
  const int cl=l&15, q4=l>>4;
  if(mode==0){
    const int which=n0/DM;
    const int cb0=n0-which*DM;
    const void* bias=(which==0)?bias0:((which==1)?bias1:bias2);
    u16* outp=(which==0)?q:((which==1)?k:v);
    if(which==2){
#pragma unroll
      for(int j=0;j<4;++j){
        const int col=wc*64+j*16+cl;
        const float bb=ld1(bias,cb0+col,oflag);
        char* cbase=(char*)((col<128)? (void*)(As+col*256) : (void*)(Bs+(col-128)*256));
        const int X=(col&7)<<4;
#pragma unroll
        for(int i=0;i<8;++i){
          const int rowb=wr*128+i*16+q4*4;
          uint2 pk;
          pk.x=f2b(acc[i][j][0]+bb)|(f2b(acc[i][j][1]+bb)<<16);
          pk.y=f2b(acc[i][j][2]+bb)|(f2b(acc[i][j][3]+bb)<<16);
          *(uint2*)(cbase + ((rowb*2)^X)) = pk;
        }
      }
      __syncthreads();
      const int b_=m0>>11, nbase=m0&2047;
#pragma unroll
      for(int tt=0;tt<16;++tt){
        const int task=tt*8+w;
        const int colg=task>>2, qq=task&3;
        const int col=colg*8+(l>>3), sub=l&7;
        char* cbase=(char*)((col<128)? (void*)(As+col*256) : (void*)(Bs+(col-128)*256));
        const uint4 d4=*(const uint4*)(cbase + ((qq*128+sub*16)^((col&7)<<4)));
        const int gcol=cb0+col, h=gcol>>6, dd=gcol&63;
        const int n=nbase+qq*64+sub*8;
        *(uint4*)&outp[((size_t)(b_*HN+h)*DH+dd)*NS + n]=d4;   // vT [bh][d][n]
      }
    } else {
      float bb4[4];
#pragma unroll
      for(int j=0;j<4;++j) bb4[j]=ld1(bias, cb0+wc*64+j*16+cl, oflag);
      float* dptr=(which==0)? dq_ : dk_;
#pragma unroll
      for(int i=0;i<8;++i){
#pragma unroll
        for(int r=0;r<4;++r){
          const int row=wr*128+i*16+q4*4+r;
          char* rbase=(char*)((row<128)? (void*)(As+row*256) : (void*)(Bs+(row-128)*256));
          const int X=(row&3)<<4;
          float s=0.f;
#pragma unroll
          for(int j=0;j<4;++j){
            const int col=wc*64+j*16+cl;
            const u16 hv=(u16)f2b(acc[i][j][r]+bb4[j]);
            *(u16*)(rbase + ((col*2)^X)) = hv;
            const float fv=b2f(hv);
            s+=fv*fv;
          }
          s+=__shfl_xor(s,1,64); s+=__shfl_xor(s,2,64);
          s+=__shfl_xor(s,4,64); s+=__shfl_xor(s,8,64);
          if(cl==0){
            const int grow=m0+row, b_=grow>>11, n=grow&2047;
            dptr[(size_t)(b_*HN + (cb0>>6)+wc)*NS + n]=0.5f*NRM*NRM*s;
          }
        }
      }
      __syncthreads();
      const int hb=cb0>>6;
#pragma unroll
      for(int tt=0;tt<16;++tt){
        const int task=tt*8+w;
        const int rowg=task>>2, qq=task&3;
        const int row=rowg*8+(l>>3), sub=l&7;
        char* rbase=(char*)((row<128)? (void*)(As+row*256) : (void*)(Bs+(row-128)*256));
        const uint4 d4=*(const uint4*)(rbase + ((qq*128+sub*16)^((row&3)<<4)));
        const int grow=m0+row, b_=grow>>11, n=grow&2047;
        *(uint4*)&outp[((size_t)(b_*HN+hb+qq)*NS+n)*DH + sub*8]=d4;  // [bh][n][d]
      }
    }
  } else {
    if(oflag){
#pragma unroll
      for(int p=0;p<2;++p){
        if(wr==p){
#pragma unroll
          for(int j=0;j<4;++j){
            const int col=wc*64+j*16+cl;
            const float bb=ld1(bias0,n0+col,oflag);
#pragma unroll
            for(int i=0;i<8;++i){
#pragma unroll
              for(int r=0;r<4;++r){
                const int row=i*16+q4*4+r;     // 0..127
                char* rbase=(char*)((row<64)? (void*)(As+row*512) : (void*)(Bs+(row-64)*512));
                *(float*)(rbase + ((col*4)^((row&3)<<4))) = acc[i][j][r]+bb;
              }
            }
          }
        }
        __syncthreads();
#pragma unroll
        for(int tt=0;tt<16;++tt){
          const int task=tt*8+w;
          const int rowg=task>>3, qq=task&7;
          const int row=rowg*8+(l>>3), sub=l&7;
          char* rbase=(char*)((row<64)? (void*)(As+row*512) : (void*)(Bs+(row-64)*512));
          const uint4 d4=*(const uint4*)(rbase + ((qq*128+sub*16)^((row&3)<<4)));
          const size_t grow=(size_t)m0+p*128+row;
          *(uint4*)((char*)outv + (grow*DM+n0)*4 + qq*128 + sub*16)=d4;
        }
        __syncthreads();
      }
    } else {
#pragma unroll
      for(int j=0;j<4;++j){
        const int col=wc*64+j*16+cl;
        const float bb=ld1(bias0,n0+col,oflag);
#pragma unroll
        for(int i=0;i<8;++i){
#pragma unroll
          for(int r=0;r<4;++r){
            const int row=wr*128+i*16+q4*4+r;
            char* rbase=(char*)((row<128)? (void*)(As+row*256) : (void*)(Bs+(row-128)*256));
            *(u16*)(rbase + ((col*2)^((row&3)<<4))) = (u16)f2b(acc[i][j][r]+bb);
          }
        }
      }
      __syncthreads();
#pragma unroll
      for(int tt=0;tt<16;++tt){
        const int task=tt*8+w;
        const int rowg=task>>2, qq=task&3;
        const int row=rowg*8+(l>>3), sub=l&7;
        char* rbase=(char*)((row<128)? (void*)(As+row*256) : (void*)(Bs+(row-128)*256));
        const uint4 d4=*(const uint4*)(rbase + ((qq*128+sub*16)^((row&3)<<4)));
        const int grow=m0+row;
        *(uint4*)((u16*)outv + (size_t)grow*DM + n0 + qq*64 + sub*8)=d4;
      }
    }
  }
}

// ---------------- K2: MFMA xp_k + global max per bh --------------------------
__global__ __launch_bounds__(256) void k_xpk2(const u16* __restrict__ kb,
    const u16* __restrict__ pn, u32* __restrict__ kmax)
{
  __shared__ short Bt[32*512];
  __shared__ short At[8*512];
  __shared__ float red[256];
  const int t=threadIdx.x, l=t&63, w=t>>6;
  const int bh=blockIdx.y, nb0=blockIdx.x*256;
  for(int s=t;s<2048;s+=256){
    const int ub=s>>6, l2=s&63, mt=ub>>1, kh=ub&1;
    const int row=mt*16+(l2&15), kc=kh*32+(l2>>4)*8;
    *(uint4*)&Bt[ub*512+l2*8]=*(const uint4*)(pn + (size_t)row*DH + kc);
  }
  float vmax=-3.4e38f;
  for(int c=0;c<4;++c){
    const int n0=nb0+c*64;
    __syncthreads();
    for(int s=t;s<512;s+=256){
      const int ua=s>>6, l2=s&63, rb=ua>>1, kh=ua&1;
      const int n=n0+rb*16+(l2&15), kc=kh*32+(l2>>4)*8;
      *(uint4*)&At[ua*512+l2*8]=*(const uint4*)(kb + ((size_t)bh*NS+n)*DH + kc);
    }
    __syncthreads();
    const short8 af0=*(short8*)&At[(w*2+0)*512+l*8];
    const short8 af1=*(short8*)&At[(w*2+1)*512+l*8];
#pragma unroll
    for(int mt=0;mt<16;++mt){
      floatx4 a={};
      a=__builtin_amdgcn_mfma_f32_16x16x32_bf16(af0,*(short8*)&Bt[(mt*2+0)*512+l*8],a,0,0,0);
      a=__builtin_amdgcn_mfma_f32_16x16x32_bf16(af1,*(short8*)&Bt[(mt*2+1)*512+l*8],a,0,0,0);
      vmax=fmaxf(vmax,fmaxf(fmaxf(a[0],a[1]),fmaxf(a[2],a[3])));
    }
  }
  red[t]=vmax; __syncthreads();
  for(int s=128;s>0;s>>=1){ if(t<s) red[t]=fmaxf(red[t],red[t+s]); __syncthreads(); }
  if(t==0) atomicMax(kmax+bh, fkey(red[0]));
}

// ---------------- K3 (fallback small path): atomic ctx -----------------------
__global__ __launch_bounds__(256) void k_ctx2(const u16* __restrict__ kb,
    const u16* __restrict__ vT, const u16* __restrict__ pn,
    const float* __restrict__ dkbuf, const u32* __restrict__ kmax,
    float* __restrict__ ctxT, float* __restrict__ ksum)
{
  __shared__ short Bt[32*512];
  __shared__ u16   Ks[256*72];
  __shared__ short AtV[8*512];
  __shared__ float dg[64];
  const int t=threadIdx.x, l=t&63, w=t>>6;
  const int split=blockIdx.x, bh=blockIdx.y;
  for(int s=t;s<2048;s+=256){
    const int ub=s>>6, l2=s&63, mt=ub>>1, kh=ub&1;
    const int row=mt*16+(l2&15), kc=kh*32+(l2>>4)*8;
    *(uint4*)&Bt[ub*512+l2*8]=*(const uint4*)(pn + (size_t)row*DH + kc);
  }
  const float kM=funkey(kmax[bh]);
  float ksr=0.f;
  floatx4 acc2[4][4]={};
  for(int c=0;c<8;++c){
    const int n0=split*512+c*64;
    __syncthreads();
    for(int s=t;s<512;s+=256){
      const int ua=s>>6, l2=s&63, rb=ua>>1, kh=ua&1;
      const int n=n0+rb*16+(l2&15), kc=kh*32+(l2>>4)*8;
      *(uint4*)&AtV[ua*512+l2*8]=*(const uint4*)(kb + ((size_t)bh*NS+n)*DH + kc);
    }
    if(t<64) dg[t]=dkbuf[(size_t)bh*NS+n0+t];
    __syncthreads();
    short8 af[4][2];
#pragma unroll
    for(int rb=0;rb<4;++rb){
      af[rb][0]=*(short8*)&AtV[(rb*2+0)*512+l*8];
      af[rb][1]=*(short8*)&AtV[(rb*2+1)*512+l*8];
    }
    float dgl[16];
#pragma unroll
    for(int rb=0;rb<4;++rb)
#pragma unroll
      for(int r=0;r<4;++r) dgl[rb*4+r]=dg[rb*16+(l>>4)*4+r];
#pragma unroll
    for(int ml=0;ml<4;++ml){
      const int mt=w*4+ml;
      const short8 bf0=*(short8*)&Bt[(mt*2+0)*512+l*8];
      const short8 bf1=*(short8*)&Bt[(mt*2+1)*512+l*8];
      const int m=mt*16+(l&15);
#pragma unroll
      for(int rb=0;rb<4;++rb){
        floatx4 a={};
        a=__builtin_amdgcn_mfma_f32_16x16x32_bf16(af[rb][0],bf0,a,0,0,0);
        a=__builtin_amdgcn_mfma_f32_16x16x32_bf16(af[rb][1],bf1,a,0,0,0);
        const int nb=rb*16+(l>>4)*4;
        const float v0=RATIO*(__expf(a[0]-dgl[rb*4+0]-kM)+EPSV);
        const float v1=RATIO*(__expf(a[1]-dgl[rb*4+1]-kM)+EPSV);
        const float v2=RATIO*(__expf(a[2]-dgl[rb*4+2]-kM)+EPSV);
        const float v3=RATIO*(__expf(a[3]-dgl[rb*4+3]-kM)+EPSV);
        *(u32*)&Ks[m*72+nb]  =f2b(v0)|(f2b(v1)<<16);
        *(u32*)&Ks[m*72+nb+2]=f2b(v2)|(f2b(v3)<<16);
      }
    }
    __syncthreads();
    for(int s=t;s<512;s+=256){
      const int uv=s>>6, l2=s&63, dt=uv>>1, kh=uv&1;
      const int d=dt*16+(l2&15), nn=n0+kh*32+(l2>>4)*8;
      *(uint4*)&AtV[uv*512+l2*8]=*(const uint4*)(vT + ((size_t)bh*DH+d)*NS + nn);
    }
    {
      float s8=0.f;
#pragma unroll
      for(int j=0;j<8;++j){
        const uint4 kk=*(const uint4*)&Ks[t*72+j*8];
        s8+=b2f(kk.x&0xffffu)+b2f(kk.x>>16)+b2f(kk.y&0xffffu)+b2f(kk.y>>16)
           +b2f(kk.z&0xffffu)+b2f(kk.z>>16)+b2f(kk.w&0xffffu)+b2f(kk.w>>16);
      }
      ksr+=s8;
    }
    __syncthreads();
#pragma unroll
    for(int i=0;i<4;++i){
      const int row=(w*4+i)*16+(l&15);
      const short8 a0=*(short8*)&Ks[row*72 + 0*32+(l>>4)*8];
      const short8 a1=*(short8*)&Ks[row*72 + 1*32+(l>>4)*8];
#pragma unroll
      for(int dt=0;dt<4;++dt){
        acc2[i][dt]=__builtin_amdgcn_mfma_f32_16x16x32_bf16(a0,*(short8*)&AtV[(dt*2+0)*512+l*8],acc2[i][dt],0,0,0);
        acc2[i][dt]=__builtin_amdgcn_mfma_f32_16x16x32_bf16(a1,*(short8*)&AtV[(dt*2+1)*512+l*8],acc2[i][dt],0,0,0);
      }
    }
  }
#pragma unroll
  for(int i=0;i<4;++i){
#pragma unroll
    for(int dt=0;dt<4;++dt){
#pragma unroll
      for(int r=0;r<4;++r){
        const int m=(w*4+i)*16+(l>>4)*4+r;
        const int d=dt*16+(l&15);
        atomicAdd(&ctxT[((size_t)bh*DH+d)*MF+m], acc2[i][dt][r]);
      }
    }
  }
  atomicAdd(ksum+bh*MF+t, ksr);
}

// ========== K3n: pipelined non-atomic ctx (big path) =========================
__global__ __launch_bounds__(256,2) void k_ctx3(const u16* __restrict__ kb,
    const u16* __restrict__ vT, const u16* __restrict__ pn,
    const float* __restrict__ dkbuf, const u32* __restrict__ kmax,
    float* __restrict__ ctxP, float* __restrict__ ksumP)
{
  __shared__ __align__(16) char SM[66048];
  short* Ks=(short*)SM;                 // 256 x 64 u16, row-xor-swizzled (32768)
  short* Kb=(short*)(SM+32768);         // 2 x 8 x 512 shorts (16384)
  short* Vb=(short*)(SM+49152);         // 2 x 8 x 512 shorts (16384)
  float* dgb=(float*)(SM+65536);        // 2 x 64 f32
  const int t=threadIdx.x, l=t&63, w=t>>6;
  const int split=blockIdx.x, bh=blockIdx.y;
  const int n00=split*512;
  const int lrow=l&15, lk8=(l>>4)*8;
  const u16* kbase = kb + (size_t)bh*NS*DH;
  const u16* vbase = vT + (size_t)bh*DH*NS;
  short8 bf[4][2];
#pragma unroll
  for(int ml=0;ml<4;++ml)
#pragma unroll
    for(int kh=0;kh<2;++kh)
      bf[ml][kh]=*(const short8*)(pn + (size_t)((w*4+ml)*16+lrow)*DH + kh*32 + lk8);
  const float kM=funkey(kmax[bh]);
  {
#pragma unroll
    for(int p=0;p<2;++p){
      const int u=w+4*p, rb=u>>1, kh=u&1;
      gl16(kbase + (size_t)(n00+rb*16+lrow)*DH + kh*32+lk8, &Kb[u*512]);
    }
#pragma unroll
    for(int p=0;p<2;++p){
      const int u=w+4*p, dt=u>>1, kh=u&1;
      gl16(vbase + (size_t)(dt*16+lrow)*NS + n00+kh*32+lk8, &Vb[u*512]);
    }
    if(t<64) dgb[t]=dkbuf[(size_t)bh*NS+n00+t];
  }
  __syncthreads();
  float ksr=0.f;
  floatx4 acc2[4][4]={};
  for(int c=0;c<8;++c){
    const int cur=c&1, nxt=cur^1;
    if(c<7){
      const int n1=n00+(c+1)*64;
#pragma unroll
      for(int p=0;p<2;++p){
        const int u=w+4*p, rb=u>>1, kh=u&1;
        gl16(kbase + (size_t)(n1+rb*16+lrow)*DH + kh*32+lk8, &Kb[nxt*4096+u*512]);
      }
#pragma unroll
      for(int p=0;p<2;++p){
        const int u=w+4*p, dt=u>>1, kh=u&1;
        gl16(vbase + (size_t)(dt*16+lrow)*NS + n1+kh*32+lk8, &Vb[nxt*4096+u*512]);
      }
    }
    float dgnv=0.f;
    if(c<7 && t<64) dgnv=dkbuf[(size_t)bh*NS+n00+(c+1)*64+t];
    short8 af[4][2];
#pragma unroll
    for(int rb=0;rb<4;++rb){
      af[rb][0]=*(short8*)&Kb[cur*4096+(rb*2+0)*512+l*8];
      af[rb][1]=*(short8*)&Kb[cur*4096+(rb*2+1)*512+l*8];
    }
    float dgl[16];
#pragma unroll
    for(int rb=0;rb<4;++rb){
      const float4 dv=*(const float4*)&dgb[cur*64+rb*16+(l>>4)*4];
      dgl[rb*4+0]=dv.x; dgl[rb*4+1]=dv.y; dgl[rb*4+2]=dv.z; dgl[rb*4+3]=dv.w;
    }
#pragma unroll
    for(int ml=0;ml<4;++ml){
      const int m=(w*4+ml)*16+lrow;
      char* krow=(char*)Ks + m*128;
      const int xr=(m&7)<<4;
#pragma unroll
      for(int rb=0;rb<4;++rb){
        floatx4 a={};
        a=__builtin_amdgcn_mfma_f32_16x16x32_bf16(af[rb][0],bf[ml][0],a,0,0,0);
        a=__builtin_amdgcn_mfma_f32_16x16x32_bf16(af[rb][1],bf[ml][1],a,0,0,0);
        const float v0=RATIO*(__expf(a[0]-dgl[rb*4+0]-kM)+EPSV);
        const float v1=RATIO*(__expf(a[1]-dgl[rb*4+1]-kM)+EPSV);
        const float v2=RATIO*(__expf(a[2]-dgl[rb*4+2]-kM)+EPSV);
        const float v3=RATIO*(__expf(a[3]-dgl[rb*4+3]-kM)+EPSV);
        const int nb=rb*16+(l>>4)*4;
        const u32 bo=((u32)(nb*2)) ^ xr;
        *(u32*)(krow+bo)  =f2b(v0)|(f2b(v1)<<16);
        *(u32*)(krow+bo+4)=f2b(v2)|(f2b(v3)<<16);
      }
    }
    __syncthreads();
    {
      char* krow=(char*)Ks + t*128;
      const int xr=(t&7)<<4;
      float s8=0.f;
#pragma unroll
      for(int j=0;j<8;++j){
        const uint4 kk=*(const uint4*)(krow + ((j*16)^xr));
        s8+=b2f(kk.x&0xffffu)+b2f(kk.x>>16)+b2f(kk.y&0xffffu)+b2f(kk.y>>16)
           +b2f(kk.z&0xffffu)+b2f(kk.z>>16)+b2f(kk.w&0xffffu)+b2f(kk.w>>16);
      }
      ksr+=s8;
    }
#pragma unroll
    for(int i=0;i<4;++i){
      const int row=(w*4+i)*16+lrow;
      char* krow=(char*)Ks + row*128;
      const int xr=(row&7)<<4;
      const short8 a0=*(short8*)(krow + (((l>>4)*16)^xr));
      const short8 a1=*(short8*)(krow + ((64+(l>>4)*16)^xr));
#pragma unroll
      for(int dt=0;dt<4;++dt){
        acc2[i][dt]=__builtin_amdgcn_mfma_f32_16x16x32_bf16(a0,*(short8*)&Vb[cur*4096+(dt*2+0)*512+l*8],acc2[i][dt],0,0,0);
        acc2[i][dt]=__builtin_amdgcn_mfma_f32_16x16x32_bf16(a1,*(short8*)&Vb[cur*4096+(dt*2+1)*512+l*8],acc2[i][dt],0,0,0);
      }
    }
    if(c<7 && t<64) dgb[nxt*64+t]=dgnv;
    __syncthreads();
  }
  {
    float* OUT=(float*)SM;
#pragma unroll
    for(int i=0;i<4;++i){
      const int mb=(w*4+i)*16+(l>>4)*4;
#pragma unroll
      for(int dt=0;dt<4;++dt){
        const int d=dt*16+lrow;
        float4 o; o.x=acc2[i][dt][0]; o.y=acc2[i][dt][1]; o.z=acc2[i][dt][2]; o.w=acc2[i][dt][3];
        *(float4*)((char*)OUT + d*1024 + ((mb*4)^((d&15)<<4))) = o;
      }
    }
    __syncthreads();
    float* gout = ctxP + (size_t)(split*BH+bh)*64*256;
#pragma unroll
    for(int s=0;s<16;++s){
      const int d=s*4+w;
      const uint4 o4=*(const uint4*)((char*)OUT + d*1024 + ((l*16)^((d&15)<<4)));
      *(uint4*)(gout + (size_t)d*256 + l*4)=o4;
    }
    ksumP[(size_t)(split*BH+bh)*256 + t]=ksr;
  }
}

// ---------------- K3b (fallback small path) ----------------------------------
__global__ __launch_bounds__(256) void k_csplit(const float* __restrict__ ctxT,
    u16* __restrict__ chi, u16* __restrict__ clo, float* __restrict__ ecs)
{
  __shared__ float cred[256];
  const int bh=blockIdx.x, t=threadIdx.x;
  const int d=t>>2, part=t&3;
  const size_t base=((size_t)bh*DH+d)*MF + part*64;
  const float* src=ctxT + base;
  u16* ph=chi + base;
  u16* pl=clo + base;
  float cs=0.f;
  for(int m=0;m<64;m+=4){
    float4 v=*(const float4*)(src+m);
    float vv[4]={v.x,v.y,v.z,v.w};
    u32 h_[4], l_[4];
#pragma unroll
    for(int j=0;j<4;++j){
      cs+=vv[j];
      u32 hh=f2b(vv[j]);
      float rr=vv[j]-b2f(hh);
      h_[j]=hh; l_[j]=f2b(rr);
    }
    uint2 sh, sl;
    sh.x=h_[0]|(h_[1]<<16); sh.y=h_[2]|(h_[3]<<16);
    sl.x=l_[0]|(l_[1]<<16); sl.y=l_[2]|(l_[3]<<16);
    *(uint2*)(ph+m)=sh; *(uint2*)(pl+m)=sl;
  }
  cred[t]=cs; __syncthreads();
  if(part==0) ecs[bh*64+d]=EPSV*(cred[t]+cred[t+1]+cred[t+2]+cred[t+3]);
}

// ---------------- K3c: reduce 4 split partials -> chi/clo/ecs/ksum -----------
__global__ __launch_bounds__(256) void k_csplit3(const float* __restrict__ ctxP,
    const float* __restrict__ ksumP,
    u16* __restrict__ chi, u16* __restrict__ clo, float* __restrict__ ecs,
    float* __restrict__ ksum)
{
  __shared__ float wred[16][4];
  const int bh=blockIdx.y, dq=blockIdx.x;
  const int t=threadIdx.x, l=t&63, w=t>>6;
  if(dq==0){
    float kv=0.f;
#pragma unroll
    for(int s=0;s<4;++s) kv+=ksumP[(size_t)(s*BH+bh)*256+t];
    ksum[bh*MF+t]=kv;
  }
#pragma unroll
  for(int d16=0;d16<16;++d16){
    const int d=dq*16+d16;
    float v=0.f;
#pragma unroll
    for(int s=0;s<4;++s) v+=ctxP[((size_t)(s*BH+bh)*64+d)*256+t];
    const u32 hh=f2b(v);
    const float rr=v-b2f(hh);
    const size_t ob=((size_t)bh*DH+d)*MF+t;
    chi[ob]=(u16)hh; clo[ob]=(u16)f2b(rr);
    float s_=v;
    s_+=__shfl_xor(s_,1,64); s_+=__shfl_xor(s_,2,64); s_+=__shfl_xor(s_,4,64);
    s_+=__shfl_xor(s_,8,64); s_+=__shfl_xor(s_,16,64); s_+=__shfl_xor(s_,32,64);
    if(l==0) wred[d16][w]=s_;
  }
  __syncthreads();
  if(t<16) ecs[bh*64+dq*16+t]=EPSV*(wred[t][0]+wred[t][1]+wred[t][2]+wred[t][3]);
}

// ---------------- K4: MFMA fused qp + D_inv + attn ---------------------------
__global__ __launch_bounds__(256) void k_attn2(const u16* __restrict__ qb,
    const u16* __restrict__ pn, const float* __restrict__ dqbuf,
    const float* __restrict__ ksum, const u16* __restrict__ chi, const u16* __restrict__ clo,
    const float* __restrict__ ecs, u16* __restrict__ attn)
{
  __shared__ short At[8*512];
  __shared__ u16 Qf[32*512];
  __shared__ float ksums[256];
  __shared__ float dq_s[64];
  __shared__ float mxs[4][64];
  __shared__ float s1s[4][64];
  __shared__ float a_s[64], dinv_s[64], ec_s[64];
  __shared__ float red4[4];
  __shared__ float epkss;
  const int t=threadIdx.x, l=t&63, w=t>>6;
  const int bh=blockIdx.y, nb0=blockIdx.x*256;
  const int b_=bh/HN, h=bh%HN;
  {
    float kv=ksum[bh*MF+t];
    ksums[t]=kv;
    if(t<64) ec_s[t]=ecs[bh*64+t];
    float s=kv;
#pragma unroll
    for(int o=1;o<64;o<<=1) s+=__shfl_xor(s,o,64);
    if(l==0) red4[w]=s;
  }
  __syncthreads();
  if(t==0) epkss=EPSV*(red4[0]+red4[1]+red4[2]+red4[3]);
  short8 bhf[8], blf[8];
  {
    const int d=w*16+(l&15);
    const size_t base=((size_t)bh*DH+d)*MF;
#pragma unroll
    for(int kc=0;kc<8;++kc){
      const size_t off=base + kc*32+(l>>4)*8;
      bhf[kc]=*(const short8*)(chi+off);
      blf[kc]=*(const short8*)(clo+off);
    }
  }
  for(int c=0;c<4;++c){
    const int n0c=nb0+c*64;
    __syncthreads();
    for(int s=t;s<512;s+=256){
      const int ua=s>>6, l2=s&63, nt=ua>>1, kh=ua&1;
      const int n=n0c+nt*16+(l2&15), kc=kh*32+(l2>>4)*8;
      *(uint4*)&At[ua*512+l2*8]=*(const uint4*)(qb + ((size_t)bh*NS+n)*DH + kc);
    }
    if(t<64) dq_s[t]=dqbuf[(size_t)bh*NS+n0c+t];
    __syncthreads();
    float mxl[4]={-3.4e38f,-3.4e38f,-3.4e38f,-3.4e38f};
    float s1l[4]={0.f,0.f,0.f,0.f};
#pragma unroll
    for(int mt=0;mt<4;++mt){
      const int gm=w*4+mt;
      const u16* pr=pn + ((gm*16+(l&15))<<6) + (l>>4)*8;
      const short8 a0=*(const short8*)(pr);
      const short8 a1=*(const short8*)(pr+32);
      float k4[4];
#pragma unroll
      for(int r=0;r<4;++r) k4[r]=ksums[gm*16+(l>>4)*4+r];
      const int mbase=(gm&1)*16+(l>>4)*4;
      const int lane2=((mbase>>3)*16+(l&15))*8 + (mbase&7);
#pragma unroll
      for(int nt=0;nt<4;++nt){
        floatx4 xp={};
        xp=__builtin_amdgcn_mfma_f32_16x16x32_bf16(a0,*(short8*)&At[(nt*2+0)*512+l*8],xp,0,0,0);
        xp=__builtin_amdgcn_mfma_f32_16x16x32_bf16(a1,*(short8*)&At[(nt*2+1)*512+l*8],xp,0,0,0);
        const float dq=dq_s[nt*16+(l&15)];
        float ev[4];
#pragma unroll
        for(int r=0;r<4;++r){
          const float xv=xp[r];
          mxl[nt]=fmaxf(mxl[nt],xv);
          ev[r]=__expf(xv-dq);
          s1l[nt]+=ev[r]*k4[r];
        }
        u16* qp_=&Qf[(nt*8+(gm>>1))*512 + lane2];
        *(u32*)qp_    =f2b(ev[0])|(f2b(ev[1])<<16);
        *(u32*)(qp_+2)=f2b(ev[2])|(f2b(ev[3])<<16);
      }
    }
#pragma unroll
    for(int nt=0;nt<4;++nt){
      float m_=mxl[nt], s_=s1l[nt];
      m_=fmaxf(m_,__shfl_xor(m_,16,64)); s_+=__shfl_xor(s_,16,64);
      m_=fmaxf(m_,__shfl_xor(m_,32,64)); s_+=__shfl_xor(s_,32,64);
      if(l<16){ mxs[w][nt*16+l]=m_; s1s[w][nt*16+l]=s_; }
    }
    __syncthreads();
    if(t<64){
      float m_=fmaxf(fmaxf(mxs[0][t],mxs[1][t]),fmaxf(mxs[2][t],mxs[3][t]));
      float s_=s1s[0][t]+s1s[1][t]+s1s[2][t]+s1s[3][t];
      float a=__expf(-m_);
      a_s[t]=a;
      dinv_s[t]=1.0f/(a*s_+epkss);
    }
    __syncthreads();
    const int d=w*16+(l&15);
    const float ec=ec_s[d];
#pragma unroll
    for(int nt=0;nt<4;++nt){
      floatx4 y={};
#pragma unroll
      for(int kc=0;kc<8;++kc){
        const short8 e=*(short8*)&Qf[(nt*8+kc)*512+l*8];
        y=__builtin_amdgcn_mfma_f32_16x16x32_bf16(e,bhf[kc],y,0,0,0);
        y=__builtin_amdgcn_mfma_f32_16x16x32_bf16(e,blf[kc],y,0,0,0);
      }
#pragma unroll
      for(int r=0;r<4;++r){
        const int nl=nt*16+(l>>4)*4+r;
        const float val=(a_s[nl]*y[r]+ec)*dinv_s[nl];
        attn[((size_t)(b_*NS+n0c+nl))*DM + h*DH + d]=(u16)f2b(val);
      }
    }
  }
}

extern "C" void kernel_launch(void* const* d_in, const int* in_sizes, int n_in,
                              void* d_out, int out_size, void* d_ws, size_t ws_size,
                              hipStream_t stream)
{
  (void)in_sizes; (void)n_in; (void)out_size;
  const void* x =d_in[0];
  const void* Wq=d_in[1]; const void* bq=d_in[2];
  const void* Wk=d_in[3]; const void* bk=d_in[4];
  const void* Wv=d_in[5]; const void* bv=d_in[6];
  const void* Wo=d_in[7]; const void* bo=d_in[8];
  const void* proj=d_in[9];

  char* ws=(char*)d_ws;
  const size_t SZ=(size_t)BN*DM*2;               // 25,165,824 B
  const size_t AUXSZ=19030528;
  const bool big = ws_size >= 4*SZ + AUXSZ;      // ~119.7 MB
  u16*   qb  =(u16*)(ws);
  u16*   kb  =(u16*)(ws+SZ);
  u16*   vb  =(u16*)(ws+2*SZ);                   // v^T [bh][d][n]
  u16*   xb  =(u16*)(ws+3*SZ);                   // bf16 x (big path only)
  char*  aux = big ? (ws+4*SZ) : (ws+3*SZ);
  u16*   wb   =(u16*)(aux);                      // 3,538,944
  u16*   wob  =(u16*)(aux+3538944);              // -> 4,718,592
  float* ctxT =(float*)(aux+4718592);            // -> 11,010,048
  float* ksum =(float*)(aux+11010048);           // -> 11,108,352
  u32*   kmax =(u32*)(aux+11108352);             // -> 11,108,736
  int*   flag =(int*)(aux+11108736);             // -> 11,108,864
  float* dk   =(float*)(aux+11108864);           // -> 11,895,296
  float* dqq  =(float*)(aux+11895296);           // -> 12,681,728
  u16*   pn   =(u16*)(aux+12681728);             // -> 12,714,496
  u16*   chi  =(u16*)(aux+12714496);             // -> 15,860,224
  u16*   clo  =(u16*)(aux+15860224);             // -> 19,005,952
  float* ecs  =(float*)(aux+19005952);           // -> 19,030,528
  u16*   attnb = big ? xb : kb;                  // dead buffer reuse

  k_detect<<<1,64,0,stream>>>((const u16*)x, flag);
  if(big) hipMemsetAsync(kmax, 0, 384, stream);
  else    hipMemsetAsync(ctxT, 0, 6291456+98304+384, stream);
  k_cvtw <<<1152, 256, 0, stream>>>(Wq,Wk,Wv,Wo,wb,wob,flag);
  k_cvtp <<<8, 256, 0, stream>>>(proj, pn, flag);
  if(big){
    k_cvtx <<<(BN*DM)/2048, 256, 0, stream>>>(x, xb, flag);
    k_gemm8<<<dim3(BN/256,2304/256), 512, 0, stream>>>(xb, wb, bq,bk,bv, qb,kb,vb, nullptr, flag, 0, dqq, dk);
  }else{
    k_gemm_f<<<dim3(BN/128,2304/128), 256, 0, stream>>>(x, wb, bq,bk,bv, qb,kb,vb, nullptr, flag, 0);
    k_diag <<<(BH*NS)/256, 256, 0, stream>>>(kb, dk);
    k_diag <<<(BH*NS)/256, 256, 0, stream>>>(qb, dqq);
  }
  k_xpk2 <<<dim3(NS/256,BH), 256, 0, stream>>>(kb, pn, kmax);
  if(big){
    float* ctxP =(float*)xb;     // xb dead between qkv-gemm and attn2
    float* ksumP=ctxT;           // reuse aux ctxT region
    k_ctx3 <<<dim3(4,BH), 256, 0, stream>>>(kb, vb, pn, dk, kmax, ctxP, ksumP);
    k_csplit3<<<dim3(4,BH), 256, 0, stream>>>(ctxP, ksumP, chi, clo, ecs, ksum);
  }else{
    k_ctx2 <<<dim3(4,BH), 256, 0, stream>>>(kb, vb, pn, dk, kmax, ctxT, ksum);
    k_csplit<<<BH, 256, 0, stream>>>(ctxT, chi, clo, ecs);
  }
  k_attn2<<<dim3(NS/256,BH), 256, 0, stream>>>(qb, pn, dqq, ksum, chi, clo, ecs, attnb);
  if(big){
    k_gemm8<<<dim3(BN/256,DM/256), 512, 0, stream>>>(attnb, wob, bo,bo,bo, nullptr,nullptr,nullptr, d_out, flag, 1, nullptr, nullptr);
  }else{
    k_gemm2<<<dim3(BN/128,DM/128), 256, 0, stream>>>(attnb, wob, bo,bo,bo, nullptr,nullptr,nullptr, d_out, flag, 1);
  }
}

// Round 6
// 396.421 us; speedup vs baseline: 1.3861x; 1.0415x over previous
//
#include <hip/hip_runtime.h>
#include <stdint.h>

typedef unsigned short u16;
typedef unsigned int u32;
typedef __attribute__((ext_vector_type(8))) short short8;
typedef __attribute__((ext_vector_type(4))) float floatx4;

#define HN 12
#define DH 64
#define DM 768
#define NS 2048
#define NB 8
#define MF 256
#define BN (NB*NS)
#define BH (NB*HN)

#define NRM 0.35355339059327373f  /* 64^-0.25 */
#define RATIO 0.0625f             /* 256^-0.5 */
#define EPSV 1e-4f

__device__ __forceinline__ float b2f(u32 u){ union{u32 i; float f;} x; x.i=u<<16; return x.f; }
__device__ __forceinline__ u32 f2b(float v){ union{float f; u32 u;} x; x.f=v; return (x.u + 0x7FFFu + ((x.u>>16)&1u))>>16; }
__device__ __forceinline__ u32 fkey(float v){ union{float f; u32 u;} x; x.f=v; return (x.u&0x80000000u)? ~x.u : (x.u|0x80000000u); }
__device__ __forceinline__ float funkey(u32 k){ union{u32 u; float f;} x; x.u=(k&0x80000000u)? (k^0x80000000u) : ~k; return x.f; }
__device__ __forceinline__ void bld8(uint4 r, float s, float* f){
  f[0]=b2f(r.x&0xffffu)*s; f[1]=b2f(r.x>>16)*s;
  f[2]=b2f(r.y&0xffffu)*s; f[3]=b2f(r.y>>16)*s;
  f[4]=b2f(r.z&0xffffu)*s; f[5]=b2f(r.z>>16)*s;
  f[6]=b2f(r.w&0xffffu)*s; f[7]=b2f(r.w>>16)*s;
}
__device__ __forceinline__ void load8(const void* base, size_t idx, int isf32, float s, float* f){
  if(isf32){
    const float* p=(const float*)base + idx;
    const float4 u=((const float4*)p)[0], v=((const float4*)p)[1];
    f[0]=u.x*s; f[1]=u.y*s; f[2]=u.z*s; f[3]=u.w*s;
    f[4]=v.x*s; f[5]=v.y*s; f[6]=v.z*s; f[7]=v.w*s;
  }else{
    uint4 r=*(const uint4*)((const u16*)base+idx);
    bld8(r,s,f);
  }
}
__device__ __forceinline__ float ld1(const void* base, int idx, int isf32){
  return isf32 ? ((const float*)base)[idx] : b2f((u32)((const u16*)base)[idx]);
}
// async global->LDS, 16B/lane; l must be wave-uniform, data lands at l + lane*16B
__device__ __forceinline__ void gl16(const void* g, void* l){
  __builtin_amdgcn_global_load_lds(
    (const __attribute__((address_space(1))) u32*)g,
    (__attribute__((address_space(3))) u32*)l, 16, 0, 0);
}

// ---------------- K0: detect input dtype (0=bf16, 1=f32) ---------------------
__global__ __launch_bounds__(64) void k_detect(const u16* __restrict__ x, int* __restrict__ flag)
{
  __shared__ int w[64], z[64];
  const int t=threadIdx.x;
  int wild=0, zero=0;
  for(int i=t;i<256;i+=64){
    u32 u=(u32)x[2*i];
    u32 e=(u>>7)&0xFFu;
    if(e>=0x90u) wild++;
    if((u&0x7FFFu)==0u) zero++;
  }
  w[t]=wild; z[t]=zero; __syncthreads();
  if(t==0){
    int W=0,Z=0;
    for(int i=0;i<64;++i){W+=w[i];Z+=z[i];}
    flag[0]=(W>16||Z>200)?1:0;
  }
}

// ---------------- K0b: convert weights to bf16 (wb=[Wq;Wk;Wv], wob=Wo) ------
__global__ __launch_bounds__(256) void k_cvtw(const void* __restrict__ Wq,
    const void* __restrict__ Wk, const void* __restrict__ Wv, const void* __restrict__ Wo,
    u16* __restrict__ wb, u16* __restrict__ wob, const int* __restrict__ flagp)
{
  const int isf32=*flagp;
  const size_t WSZ=(size_t)DM*DM;
  size_t idx=((size_t)blockIdx.x*256+threadIdx.x)*8;
  const void* src; size_t off; u16* dst;
  if(idx<3*WSZ){ int w=(int)(idx/WSZ); src=(w==0)?Wq:((w==1)?Wk:Wv); off=idx-(size_t)w*WSZ; dst=wb+idx; }
  else { src=Wo; off=idx-3*WSZ; dst=wob+off; }
  if(isf32){
    const float* p=(const float*)src+off;
    float4 u=((const float4*)p)[0], v=((const float4*)p)[1];
    uint4 st;
    st.x=f2b(u.x)|(f2b(u.y)<<16); st.y=f2b(u.z)|(f2b(u.w)<<16);
    st.z=f2b(v.x)|(f2b(v.y)<<16); st.w=f2b(v.z)|(f2b(v.w)<<16);
    *(uint4*)dst=st;
  }else{
    *(uint4*)dst=*(const uint4*)((const u16*)src+off);
  }
}

// ---------------- K0c: pn = proj * NRM, bf16 [256][64] -----------------------
__global__ __launch_bounds__(256) void k_cvtp(const void* __restrict__ proj,
    u16* __restrict__ pn, const int* __restrict__ flagp)
{
  const int isf32=*flagp;
  const size_t idx=((size_t)blockIdx.x*256+threadIdx.x)*8;
  float pf[8];
  load8(proj, idx, isf32, NRM, pf);
  uint4 st;
  st.x=f2b(pf[0])|(f2b(pf[1])<<16); st.y=f2b(pf[2])|(f2b(pf[3])<<16);
  st.z=f2b(pf[4])|(f2b(pf[5])<<16); st.w=f2b(pf[6])|(f2b(pf[7])<<16);
  *(uint4*)(pn+idx)=st;
}

// ---------------- K0e: xb = bf16(x) ------------------------------------------
__global__ __launch_bounds__(256) void k_cvtx(const void* __restrict__ x,
    u16* __restrict__ xb, const int* __restrict__ flagp)
{
  const int isf32=*flagp;
  const size_t idx=((size_t)blockIdx.x*256+threadIdx.x)*8;   // over BN*DM
  float f[8];
  load8(x, idx, isf32, 1.0f, f);
  uint4 st;
  st.x=f2b(f[0])|(f2b(f[1])<<16); st.y=f2b(f[2])|(f2b(f[3])<<16);
  st.z=f2b(f[4])|(f2b(f[5])<<16); st.w=f2b(f[6])|(f2b(f[7])<<16);
  *(uint4*)(xb+idx)=st;
}

// ---------------- K0d: dk[row] = 0.5*NRM^2*sum(v^2) over DH (fallback path) --
__global__ __launch_bounds__(256) void k_diag(const u16* __restrict__ src, float* __restrict__ dk)
{
  const size_t row=(size_t)blockIdx.x*256+threadIdx.x;
  const u16* p=src+row*DH;
  float s=0.f;
#pragma unroll
  for(int c=0;c<DH;c+=8){
    uint4 r=*(const uint4*)(p+c);
    float f[8]; bld8(r,1.0f,f);
#pragma unroll
    for(int j=0;j<8;++j) s+=f[j]*f[j];
  }
  dk[row]=0.5f*NRM*NRM*s;
}

// ======== shared epilogue for the two 128-tile fallback MFMA GEMMs ===========
__device__ __forceinline__ void gemm_epilogue(const floatx4 acc[4][4], int mode, int oflag,
    int m0, int n0, int l, int wr4, int wc4,
    const void* bias0, const void* bias1, const void* bias2,
    u16* q, u16* k, u16* v, void* outv)
{
  const int rbase=(l>>4)*4, cl=l&15;
  if(mode==0){
    const int which=n0/DM;
    const void* bias=(which==0)?bias0:((which==1)?bias1:bias2);
    u16* outp=(which==0)?q:((which==1)?k:v);
    const int cb=n0-which*DM;
#pragma unroll
    for(int j=0;j<4;++j){
      const int col=cb+(wc4+j)*16+cl;
      const int h=col>>6, dd=col&63;
      const float bb=ld1(bias,col,oflag);
#pragma unroll
      for(int i=0;i<4;++i){
#pragma unroll
        for(int r=0;r<4;++r){
          const int grow=m0+(wr4+i)*16+rbase+r;
          const int b_=grow>>11, n=grow&2047;
          const u16 val=(u16)f2b(acc[i][j][r]+bb);
          if(which==2) outp[((size_t)(b_*HN+h)*DH+dd)*NS + n]=val;       // vT [bh][d][n]
          else         outp[((size_t)((b_*HN+h)*NS+n))*DH + dd]=val;     // [bh][n][d]
        }
      }
    }
  }else{
#pragma unroll
    for(int j=0;j<4;++j){
      const int col=n0+(wc4+j)*16+cl;
      const float bb=ld1(bias0,col,oflag);
#pragma unroll
      for(int i=0;i<4;++i){
#pragma unroll
        for(int r=0;r<4;++r){
          const int grow=m0+(wr4+i)*16+rbase+r;
          const float val=acc[i][j][r]+bb;
          if(oflag) ((float*)outv)[(size_t)grow*DM+col]=val;
          else      ((u16*)outv)[(size_t)grow*DM+col]=(u16)f2b(val);
        }
      }
    }
  }
}

// ---------------- K1: MFMA GEMM, 128-tile (fallback) -------------------------
__global__ __launch_bounds__(256) void k_gemm2(const u16* __restrict__ A16,
    const u16* __restrict__ B16,
    const void* __restrict__ bias0, const void* __restrict__ bias1, const void* __restrict__ bias2,
    u16* __restrict__ q, u16* __restrict__ k, u16* __restrict__ v,
    void* __restrict__ outv, const int* __restrict__ flagp, const int mode)
{
  __shared__ short At[16*512];
  __shared__ short Bt[16*512];
  const int oflag=*flagp;
  const int t=threadIdx.x, l=t&63, w=t>>6;
  const int m0=blockIdx.x*128, n0=blockIdx.y*128;
  const int wr4=(w>>1)*4, wc4=(w&1)*4;
  const int srow=l&15, skg=l>>4;
  floatx4 acc[4][4]={};
  for(int k0=0;k0<DM;k0+=64){
    __syncthreads();
#pragma unroll
    for(int s=0;s<4;++s){
      const int bi=w*4+s, rb=bi>>1, kh=bi&1;
      const int kc=k0+kh*32+skg*8;
      gl16(A16 + (size_t)(m0+rb*16+srow)*DM + kc, &At[bi*512]);
      gl16(B16 + (size_t)(n0+rb*16+srow)*DM + kc, &Bt[bi*512]);
    }
    __syncthreads();
#pragma unroll
    for(int kh=0;kh<2;++kh){
      short8 af[4], bf[4];
#pragma unroll
      for(int i=0;i<4;++i) af[i]=*(short8*)&At[((wr4+i)*2+kh)*512+l*8];
#pragma unroll
      for(int j=0;j<4;++j) bf[j]=*(short8*)&Bt[((wc4+j)*2+kh)*512+l*8];
#pragma unroll
      for(int i=0;i<4;++i)
#pragma unroll
        for(int j=0;j<4;++j)
          acc[i][j]=__builtin_amdgcn_mfma_f32_16x16x32_bf16(af[i],bf[j],acc[i][j],0,0,0);
    }
  }
  gemm_epilogue(acc,mode,oflag,m0,n0,l,wr4,wc4,bias0,bias1,bias2,q,k,v,outv);
}

// ---------------- K1f: fallback MFMA GEMM, f32-capable A ---------------------
__global__ __launch_bounds__(256) void k_gemm_f(const void* __restrict__ Araw,
    const u16* __restrict__ B16,
    const void* __restrict__ bias0, const void* __restrict__ bias1, const void* __restrict__ bias2,
    u16* __restrict__ q, u16* __restrict__ k, u16* __restrict__ v,
    void* __restrict__ outv, const int* __restrict__ flagp, const int mode)
{
  __shared__ short At[16*512];
  __shared__ short Bt[16*512];
  const int oflag=*flagp;
  const int isf32=(mode==0)?oflag:0;
  const int t=threadIdx.x, l=t&63, w=t>>6;
  const int m0=blockIdx.x*128, n0=blockIdx.y*128;
  const int wr4=(w>>1)*4, wc4=(w&1)*4;
  const int srow=l&15, skg=l>>4;
  floatx4 acc[4][4]={};
  for(int k0=0;k0<DM;k0+=64){
    __syncthreads();
#pragma unroll
    for(int s=0;s<4;++s){
      const int bi=w*4+s, rb=bi>>1, kh=bi&1;
      const int kc=k0+kh*32+skg*8;
      uint4 va;
      if(isf32){
        const float* ap=(const float*)Araw + (size_t)(m0+rb*16+srow)*DM + kc;
        float4 u=((const float4*)ap)[0], vv=((const float4*)ap)[1];
        va.x=f2b(u.x)|(f2b(u.y)<<16);  va.y=f2b(u.z)|(f2b(u.w)<<16);
        va.z=f2b(vv.x)|(f2b(vv.y)<<16); va.w=f2b(vv.z)|(f2b(vv.w)<<16);
      }else{
        va=*(const uint4*)((const u16*)Araw + (size_t)(m0+rb*16+srow)*DM + kc);
      }
      const uint4 vb=*(const uint4*)(B16 + (size_t)(n0+rb*16+srow)*DM + kc);
      *(uint4*)&At[bi*512+l*8]=va;
      *(uint4*)&Bt[bi*512+l*8]=vb;
    }
    __syncthreads();
#pragma unroll
    for(int kh=0;kh<2;++kh){
      short8 af[4], bf[4];
#pragma unroll
      for(int i=0;i<4;++i) af[i]=*(short8*)&At[((wr4+i)*2+kh)*512+l*8];
#pragma unroll
      for(int j=0;j<4;++j) bf[j]=*(short8*)&Bt[((wc4+j)*2+kh)*512+l*8];
#pragma unroll
      for(int i=0;i<4;++i)
#pragma unroll
        for(int j=0;j<4;++j)
          acc[i][j]=__builtin_amdgcn_mfma_f32_16x16x32_bf16(af[i],bf[j],acc[i][j],0,0,0);
    }
  }
  gemm_epilogue(acc,mode,oflag,m0,n0,l,wr4,wc4,bias0,bias1,bias2,q,k,v,outv);
}

// ================= K1h: 256x128 MFMA GEMM, 3-slot pipeline, 2 blocks/CU ======
// BM=256 BN=128 BK=32, 512 thr (8 waves, wave-tile 64x64, acc=64 regs).
// LDS 72 KiB (3 slots x 24 KB: A units 0-15, B units 16-23) -> 2 blocks/CU.
// Lead-2 staging: phase t reads tile t (verified at t-1), stages t+2, WV3
// drains tile t+1; slot (t+2)%3 restaged only after its readers' exit barrier.
#define G9OFF(s,u) (((s)*24+(u))*512)
#define G9STA(kt,s) do{ \
  const size_t g_=(size_t)(kt)*32; \
  gl16(Ar0+g_, &LD[G9OFF(s,w)]); \
  gl16(Ar0+(size_t)128*768+g_, &LD[G9OFF(s,8+w)]); \
  gl16(Br0+g_, &LD[G9OFF(s,16+w)]); \
}while(0)
#define G9LD(s) do{ \
  _Pragma("unroll") for(int i_=0;i_<4;++i_) a[i_]=*(short8*)&LD[G9OFF(s,wr4+i_)+l*8]; \
  _Pragma("unroll") for(int j_=0;j_<4;++j_) b[j_]=*(short8*)&LD[G9OFF(s,16+wc4+j_)+l*8]; \
}while(0)
#define G9MM do{ _Pragma("unroll") for(int i_=0;i_<4;++i_){ \
  _Pragma("unroll") for(int j_=0;j_<4;++j_) \
    acc[i_][j_]=__builtin_amdgcn_mfma_f32_16x16x32_bf16(a[i_],b[j_],acc[i_][j_],0,0,0); } }while(0)
#define FEN asm volatile("" ::: "memory")
#define BARR do{ FEN; __builtin_amdgcn_s_barrier(); FEN; }while(0)
#define WV3 asm volatile("s_waitcnt vmcnt(3)" ::: "memory")
#define WV0 asm volatile("s_waitcnt vmcnt(0)" ::: "memory")
#define WL0 do{ asm volatile("s_waitcnt lgkmcnt(0)" ::: "memory"); __builtin_amdgcn_sched_barrier(0); }while(0)
#define G9PH(kt,s,SST,WST) do{ G9LD(s); SST; WST; BARR; WL0; \
  __builtin_amdgcn_s_setprio(1); G9MM; __builtin_amdgcn_s_setprio(0); BARR; }while(0)

__global__ __launch_bounds__(512,4) void k_gemm9(const u16* __restrict__ A16,
    const u16* __restrict__ B16,
    const void* __restrict__ bias0, const void* __restrict__ bias1, const void* __restrict__ bias2,
    u16* __restrict__ q, u16* __restrict__ k, u16* __restrict__ v,
    void* __restrict__ outv, const int* __restrict__ flagp, const int mode,
    float* __restrict__ dq_, float* __restrict__ dk_)
{
  __shared__ short LD[3*24*512];     // 73,728 B
  const int oflag=*flagp;
  const int t=threadIdx.x, l=t&63, w=t>>6;
  const int wr=w>>1, wc=w&1;
  const int wr4=wr*4, wc4=wc*4;
  const int lrow=l&15, lk8=(l>>4)*8;
  // bijective XCD swizzle, n-fast within chunk
  int bid = blockIdx.y*gridDim.x + blockIdx.x;
  const int nwg = gridDim.x*gridDim.y;       // 1152 (mode0) / 384 (mode1), %8==0
  const int nN  = gridDim.y;                 // 18 / 6
  bid = (bid&7)*(nwg>>3) + (bid>>3);
  const int mi = bid/nN;
  const int m0 = mi*256;
  const int n0 = (bid - mi*nN)*128;

  const u16* Ar0 = A16 + (size_t)(m0 + w*16 + lrow)*768 + lk8;
  const u16* Br0 = B16 + (size_t)(n0 + w*16 + lrow)*768 + lk8;
  floatx4 acc[4][4]={};
  short8 a[4], b[4];

  // prologue: stage tiles 0,1; verify tile 0
  G9STA(0,0); G9STA(1,1);
  WV3; BARR;

  for(int it=0; it<7; ++it){
    const int kt=3*it;
    G9PH(kt+0,0, G9STA(kt+2,2), WV3);
    G9PH(kt+1,1, G9STA(kt+3,0), WV3);
    G9PH(kt+2,2, G9STA(kt+4,1), WV3);
  }
  G9PH(21,0, G9STA(23,2), WV3);
  G9PH(22,1, (void)0, WV0);
  G9PH(23,2, (void)0, (void)0);

  // ============ epilogue: LDS restage -> coalesced wide stores ===============
  char* LB=(char*)LD;
  const int cl=l&15, q4=l>>4;
  const int wrm=wr*64, wcn=wc*64;
  if(mode==0){
    const int which=n0/DM;
    const int cb0=n0-which*DM;
    const int hb=cb0>>6;                       // 2 heads per block: hb, hb+1
    const void* bias=(which==0)?bias0:((which==1)?bias1:bias2);
    u16* outp=(which==0)?q:((which==1)?k:v);
    if(which==2){
      // ---- v: col-major restage [col][256 rows], XOR (col&7)<<4 ----
#pragma unroll
      for(int j=0;j<4;++j){
        const int col=wcn+j*16+cl;
        const float bb=ld1(bias,cb0+col,oflag);
        const int X=(col&7)<<4;
#pragma unroll
        for(int i=0;i<4;++i){
          const int rowb=wrm+i*16+q4*4;
          uint2 pk;
          pk.x=f2b(acc[i][j][0]+bb)|(f2b(acc[i][j][1]+bb)<<16);
          pk.y=f2b(acc[i][j][2]+bb)|(f2b(acc[i][j][3]+bb)<<16);
          *(uint2*)(LB + col*512 + ((rowb*2)^X)) = pk;
        }
      }
      __syncthreads();
      const int b_=m0>>11, nbase=m0&2047;
#pragma unroll
      for(int s8=0;s8<8;++s8){
        const int c=s8*512+t;
        const int col=c>>5, off=(c&31)*16;
        const uint4 d4=*(const uint4*)(LB + col*512 + (off^((col&7)<<4)));
        const int h=hb+(col>>6), dd=col&63;
        *(uint4*)&outp[((size_t)(b_*HN+h)*DH+dd)*NS + nbase + (off>>1)]=d4;  // vT
      }
    } else {
      // ---- q/k: row-major restage [row][128 cols], XOR (row&7)<<4; fused diag
      float bb4[4];
#pragma unroll
      for(int j=0;j<4;++j) bb4[j]=ld1(bias, cb0+wcn+j*16+cl, oflag);
      float* dptr=(which==0)? dq_ : dk_;
#pragma unroll
      for(int i=0;i<4;++i){
#pragma unroll
        for(int r=0;r<4;++r){
          const int row=wrm+i*16+q4*4+r;
          const int X=(row&7)<<4;
          float s=0.f;
#pragma unroll
          for(int j=0;j<4;++j){
            const int col=wcn+j*16+cl;
            const u16 hv=(u16)f2b(acc[i][j][r]+bb4[j]);
            *(u16*)(LB + row*256 + ((col*2)^X)) = hv;
            const float fv=b2f(hv);
            s+=fv*fv;
          }
          s+=__shfl_xor(s,1,64); s+=__shfl_xor(s,2,64);
          s+=__shfl_xor(s,4,64); s+=__shfl_xor(s,8,64);
          if(cl==0){
            const int grow=m0+row, b_=grow>>11, n=grow&2047;
            dptr[(size_t)(b_*HN + hb + wc)*NS + n]=0.5f*NRM*NRM*s;
          }
        }
      }
      __syncthreads();
#pragma unroll
      for(int s8=0;s8<8;++s8){
        const int c=s8*512+t;
        const int row=c>>4, off=(c&15)*16;
        const uint4 d4=*(const uint4*)(LB + row*256 + (off^((row&7)<<4)));
        const int grow=m0+row, b_=grow>>11, n=grow&2047;
        *(uint4*)&outp[((size_t)((b_*HN+hb+(off>>7))*NS+n))*DH + ((off>>1)&63)]=d4;
      }
    }
  } else {
    if(oflag){
      // ---- f32 out, two half passes (128 rows x 128 cols x 4B = 64 KB) ----
#pragma unroll
      for(int p=0;p<2;++p){
        if((wr>>1)==p){
          const int rl0=(wr&1)*64;
#pragma unroll
          for(int j=0;j<4;++j){
            const int col=wcn+j*16+cl;
            const float bb=ld1(bias0,n0+col,oflag);
#pragma unroll
            for(int i=0;i<4;++i){
#pragma unroll
              for(int r=0;r<4;++r){
                const int rl=rl0+i*16+q4*4+r;   // 0..127
                *(float*)(LB + rl*512 + ((col*4)^((rl&7)<<4))) = acc[i][j][r]+bb;
              }
            }
          }
        }
        __syncthreads();
#pragma unroll
        for(int s8=0;s8<8;++s8){
          const int c=s8*512+t;
          const int rl=c>>5, off=(c&31)*16;
          const uint4 d4=*(const uint4*)(LB + rl*512 + (off^((rl&7)<<4)));
          const size_t grow=(size_t)m0+p*128+rl;
          *(uint4*)((char*)outv + (grow*DM+n0)*4 + off)=d4;
        }
        __syncthreads();
      }
    } else {
      // ---- bf16 out, single pass ----
#pragma unroll
      for(int j=0;j<4;++j){
        const int col=wcn+j*16+cl;
        const float bb=ld1(bias0,n0+col,oflag);
#pragma unroll
        for(int i=0;i<4;++i){
#pragma unroll
          for(int r=0;r<4;++r){
            const int row=wrm+i*16+q4*4+r;
            *(u16*)(LB + row*256 + ((col*2)^((row&7)<<4))) = (u16)f2b(acc[i][j][r]+bb);
          }
        }
      }
      __syncthreads();
#pragma unroll
      for(int s8=0;s8<8;++s8){
        const int c=s8*512+t;
        const int row=c>>4, off=(c&15)*16;
        const uint4 d4=*(const uint4*)(LB + row*256 + (off^((row&7)<<4)));
        *(uint4*)((u16*)outv + (size_t)(m0+row)*DM + n0 + (off>>1))=d4;
      }
    }
  }
}

// ---------------- K2: MFMA xp_k + global max per bh --------------------------
__global__ __launch_bounds__(256) void k_xpk2(const u16* __restrict__ kb,
    const u16* __restrict__ pn, u32* __restrict__ kmax)
{
  __shared__ short Bt[32*512];
  __shared__ short At[8*512];
  __shared__ float red[256];
  const int t=threadIdx.x, l=t&63, w=t>>6;
  const int bh=blockIdx.y, nb0=blockIdx.x*256;
  for(int s=t;s<2048;s+=256){
    const int ub=s>>6, l2=s&63, mt=ub>>1, kh=ub&1;
    const int row=mt*16+(l2&15), kc=kh*32+(l2>>4)*8;
    *(uint4*)&Bt[ub*512+l2*8]=*(const uint4*)(pn + (size_t)row*DH + kc);
  }
  float vmax=-3.4e38f;
  for(int c=0;c<4;++c){
    const int n0=nb0+c*64;
    __syncthreads();
    for(int s=t;s<512;s+=256){
      const int ua=s>>6, l2=s&63, rb=ua>>1, kh=ua&1;
      const int n=n0+rb*16+(l2&15), kc=kh*32+(l2>>4)*8;
      *(uint4*)&At[ua*512+l2*8]=*(const uint4*)(kb + ((size_t)bh*NS+n)*DH + kc);
    }
    __syncthreads();
    const short8 af0=*(short8*)&At[(w*2+0)*512+l*8];
    const short8 af1=*(short8*)&At[(w*2+1)*512+l*8];
#pragma unroll
    for(int mt=0;mt<16;++mt){
      floatx4 a={};
      a=__builtin_amdgcn_mfma_f32_16x16x32_bf16(af0,*(short8*)&Bt[(mt*2+0)*512+l*8],a,0,0,0);
      a=__builtin_amdgcn_mfma_f32_16x16x32_bf16(af1,*(short8*)&Bt[(mt*2+1)*512+l*8],a,0,0,0);
      vmax=fmaxf(vmax,fmaxf(fmaxf(a[0],a[1]),fmaxf(a[2],a[3])));
    }
  }
  red[t]=vmax; __syncthreads();
  for(int s=128;s>0;s>>=1){ if(t<s) red[t]=fmaxf(red[t],red[t+s]); __syncthreads(); }
  if(t==0) atomicMax(kmax+bh, fkey(red[0]));
}

// ---------------- K3 (fallback small path): atomic ctx -----------------------
__global__ __launch_bounds__(256) void k_ctx2(const u16* __restrict__ kb,
    const u16* __restrict__ vT, const u16* __restrict__ pn,
    const float* __restrict__ dkbuf, const u32* __restrict__ kmax,
    float* __restrict__ ctxT, float* __restrict__ ksum)
{
  __shared__ short Bt[32*512];
  __shared__ u16   Ks[256*72];
  __shared__ short AtV[8*512];
  __shared__ float dg[64];
  const int t=threadIdx.x, l=t&63, w=t>>6;
  const int split=blockIdx.x, bh=blockIdx.y;
  for(int s=t;s<2048;s+=256){
    const int ub=s>>6, l2=s&63, mt=ub>>1, kh=ub&1;
    const int row=mt*16+(l2&15), kc=kh*32+(l2>>4)*8;
    *(uint4*)&Bt[ub*512+l2*8]=*(const uint4*)(pn + (size_t)row*DH + kc);
  }
  const float kM=funkey(kmax[bh]);
  float ksr=0.f;
  floatx4 acc2[4][4]={};
  for(int c=0;c<8;++c){
    const int n0=split*512+c*64;
    __syncthreads();
    for(int s=t;s<512;s+=256){
      const int ua=s>>6, l2=s&63, rb=ua>>1, kh=ua&1;
      const int n=n0+rb*16+(l2&15), kc=kh*32+(l2>>4)*8;
      *(uint4*)&AtV[ua*512+l2*8]=*(const uint4*)(kb + ((size_t)bh*NS+n)*DH + kc);
    }
    if(t<64) dg[t]=dkbuf[(size_t)bh*NS+n0+t];
    __syncthreads();
    short8 af[4][2];
#pragma unroll
    for(int rb=0;rb<4;++rb){
      af[rb][0]=*(short8*)&AtV[(rb*2+0)*512+l*8];
      af[rb][1]=*(short8*)&AtV[(rb*2+1)*512+l*8];
    }
    float dgl[16];
#pragma unroll
    for(int rb=0;rb<4;++rb)
#pragma unroll
      for(int r=0;r<4;++r) dgl[rb*4+r]=dg[rb*16+(l>>4)*4+r];
#pragma unroll
    for(int ml=0;ml<4;++ml){
      const int mt=w*4+ml;
      const short8 bf0=*(short8*)&Bt[(mt*2+0)*512+l*8];
      const short8 bf1=*(short8*)&Bt[(mt*2+1)*512+l*8];
      const int m=mt*16+(l&15);
#pragma unroll
      for(int rb=0;rb<4;++rb){
        floatx4 a={};
        a=__builtin_amdgcn_mfma_f32_16x16x32_bf16(af[rb][0],bf0,a,0,0,0);
        a=__builtin_amdgcn_mfma_f32_16x16x32_bf16(af[rb][1],bf1,a,0,0,0);
        const int nb=rb*16+(l>>4)*4;
        const float v0=RATIO*(__expf(a[0]-dgl[rb*4+0]-kM)+EPSV);
        const float v1=RATIO*(__expf(a[1]-dgl[rb*4+1]-kM)+EPSV);
        const float v2=RATIO*(__expf(a[2]-dgl[rb*4+2]-kM)+EPSV);
        const float v3=RATIO*(__expf(a[3]-dgl[rb*4+3]-kM)+EPSV);
        *(u32*)&Ks[m*72+nb]  =f2b(v0)|(f2b(v1)<<16);
        *(u32*)&Ks[m*72+nb+2]=f2b(v2)|(f2b(v3)<<16);
      }
    }
    __syncthreads();
    for(int s=t;s<512;s+=256){
      const int uv=s>>6, l2=s&63, dt=uv>>1, kh=uv&1;
      const int d=dt*16+(l2&15), nn=n0+kh*32+(l2>>4)*8;
      *(uint4*)&AtV[uv*512+l2*8]=*(const uint4*)(vT + ((size_t)bh*DH+d)*NS + nn);
    }
    {
      float s8=0.f;
#pragma unroll
      for(int j=0;j<8;++j){
        const uint4 kk=*(const uint4*)&Ks[t*72+j*8];
        s8+=b2f(kk.x&0xffffu)+b2f(kk.x>>16)+b2f(kk.y&0xffffu)+b2f(kk.y>>16)
           +b2f(kk.z&0xffffu)+b2f(kk.z>>16)+b2f(kk.w&0xffffu)+b2f(kk.w>>16);
      }
      ksr+=s8;
    }
    __syncthreads();
#pragma unroll
    for(int i=0;i<4;++i){
      const int row=(w*4+i)*16+(l&15);
      const short8 a0=*(short8*)&Ks[row*72 + 0*32+(l>>4)*8];
      const short8 a1=*(short8*)&Ks[row*72 + 1*32+(l>>4)*8];
#pragma unroll
      for(int dt=0;dt<4;++dt){
        acc2[i][dt]=__builtin_amdgcn_mfma_f32_16x16x32_bf16(a0,*(short8*)&AtV[(dt*2+0)*512+l*8],acc2[i][dt],0,0,0);
        acc2[i][dt]=__builtin_amdgcn_mfma_f32_16x16x32_bf16(a1,*(short8*)&AtV[(dt*2+1)*512+l*8],acc2[i][dt],0,0,0);
      }
    }
  }
#pragma unroll
  for(int i=0;i<4;++i){
#pragma unroll
    for(int dt=0;dt<4;++dt){
#pragma unroll
      for(int r=0;r<4;++r){
        const int m=(w*4+i)*16+(l>>4)*4+r;
        const int d=dt*16+(l&15);
        atomicAdd(&ctxT[((size_t)bh*DH+d)*MF+m], acc2[i][dt][r]);
      }
    }
  }
  atomicAdd(ksum+bh*MF+t, ksr);
}

// ========== K3n: pipelined non-atomic ctx (big path) =========================
__global__ __launch_bounds__(256,2) void k_ctx3(const u16* __restrict__ kb,
    const u16* __restrict__ vT, const u16* __restrict__ pn,
    const float* __restrict__ dkbuf, const u32* __restrict__ kmax,
    float* __restrict__ ctxP, float* __restrict__ ksumP)
{
  __shared__ __align__(16) char SM[66048];
  short* Ks=(short*)SM;                 // 256 x 64 u16, row-xor-swizzled (32768)
  short* Kb=(short*)(SM+32768);         // 2 x 8 x 512 shorts (16384)
  short* Vb=(short*)(SM+49152);         // 2 x 8 x 512 shorts (16384)
  float* dgb=(float*)(SM+65536);        // 2 x 64 f32
  const int t=threadIdx.x, l=t&63, w=t>>6;
  const int split=blockIdx.x, bh=blockIdx.y;
  const int n00=split*512;
  const int lrow=l&15, lk8=(l>>4)*8;
  const u16* kbase = kb + (size_t)bh*NS*DH;
  const u16* vbase = vT + (size_t)bh*DH*NS;
  short8 bf[4][2];
#pragma unroll
  for(int ml=0;ml<4;++ml)
#pragma unroll
    for(int kh=0;kh<2;++kh)
      bf[ml][kh]=*(const short8*)(pn + (size_t)((w*4+ml)*16+lrow)*DH + kh*32 + lk8);
  const float kM=funkey(kmax[bh]);
  {
#pragma unroll
    for(int p=0;p<2;++p){
      const int u=w+4*p, rb=u>>1, kh=u&1;
      gl16(kbase + (size_t)(n00+rb*16+lrow)*DH + kh*32+lk8, &Kb[u*512]);
    }
#pragma unroll
    for(int p=0;p<2;++p){
      const int u=w+4*p, dt=u>>1, kh=u&1;
      gl16(vbase + (size_t)(dt*16+lrow)*NS + n00+kh*32+lk8, &Vb[u*512]);
    }
    if(t<64) dgb[t]=dkbuf[(size_t)bh*NS+n00+t];
  }
  __syncthreads();
  float ksr=0.f;
  floatx4 acc2[4][4]={};
  for(int c=0;c<8;++c){
    const int cur=c&1, nxt=cur^1;
    if(c<7){
      const int n1=n00+(c+1)*64;
#pragma unroll
      for(int p=0;p<2;++p){
        const int u=w+4*p, rb=u>>1, kh=u&1;
        gl16(kbase + (size_t)(n1+rb*16+lrow)*DH + kh*32+lk8, &Kb[nxt*4096+u*512]);
      }
#pragma unroll
      for(int p=0;p<2;++p){
        const int u=w+4*p, dt=u>>1, kh=u&1;
        gl16(vbase + (size_t)(dt*16+lrow)*NS + n1+kh*32+lk8, &Vb[nxt*4096+u*512]);
      }
    }
    float dgnv=0.f;
    if(c<7 && t<64) dgnv=dkbuf[(size_t)bh*NS+n00+(c+1)*64+t];
    short8 af[4][2];
#pragma unroll
    for(int rb=0;rb<4;++rb){
      af[rb][0]=*(short8*)&Kb[cur*4096+(rb*2+0)*512+l*8];
      af[rb][1]=*(short8*)&Kb[cur*4096+(rb*2+1)*512+l*8];
    }
    float dgl[16];
#pragma unroll
    for(int rb=0;rb<4;++rb){
      const float4 dv=*(const float4*)&dgb[cur*64+rb*16+(l>>4)*4];
      dgl[rb*4+0]=dv.x; dgl[rb*4+1]=dv.y; dgl[rb*4+2]=dv.z; dgl[rb*4+3]=dv.w;
    }
#pragma unroll
    for(int ml=0;ml<4;++ml){
      const int m=(w*4+ml)*16+lrow;
      char* krow=(char*)Ks + m*128;
      const int xr=(m&7)<<4;
#pragma unroll
      for(int rb=0;rb<4;++rb){
        floatx4 a={};
        a=__builtin_amdgcn_mfma_f32_16x16x32_bf16(af[rb][0],bf[ml][0],a,0,0,0);
        a=__builtin_amdgcn_mfma_f32_16x16x32_bf16(af[rb][1],bf[ml][1],a,0,0,0);
        const float v0=RATIO*(__expf(a[0]-dgl[rb*4+0]-kM)+EPSV);
        const float v1=RATIO*(__expf(a[1]-dgl[rb*4+1]-kM)+EPSV);
        const float v2=RATIO*(__expf(a[2]-dgl[rb*4+2]-kM)+EPSV);
        const float v3=RATIO*(__expf(a[3]-dgl[rb*4+3]-kM)+EPSV);
        const int nb=rb*16+(l>>4)*4;
        const u32 bo=((u32)(nb*2)) ^ xr;
        *(u32*)(krow+bo)  =f2b(v0)|(f2b(v1)<<16);
        *(u32*)(krow+bo+4)=f2b(v2)|(f2b(v3)<<16);
      }
    }
    __syncthreads();
    {
      char* krow=(char*)Ks + t*128;
      const int xr=(t&7)<<4;
      float s8=0.f;
#pragma unroll
      for(int j=0;j<8;++j){
        const uint4 kk=*(const uint4*)(krow + ((j*16)^xr));
        s8+=b2f(kk.x&0xffffu)+b2f(kk.x>>16)+b2f(kk.y&0xffffu)+b2f(kk.y>>16)
           +b2f(kk.z&0xffffu)+b2f(kk.z>>16)+b2f(kk.w&0xffffu)+b2f(kk.w>>16);
      }
      ksr+=s8;
    }
#pragma unroll
    for(int i=0;i<4;++i){
      const int row=(w*4+i)*16+lrow;
      char* krow=(char*)Ks + row*128;
      const int xr=(row&7)<<4;
      const short8 a0=*(short8*)(krow + (((l>>4)*16)^xr));
      const short8 a1=*(short8*)(krow + ((64+(l>>4)*16)^xr));
#pragma unroll
      for(int dt=0;dt<4;++dt){
        acc2[i][dt]=__builtin_amdgcn_mfma_f32_16x16x32_bf16(a0,*(short8*)&Vb[cur*4096+(dt*2+0)*512+l*8],acc2[i][dt],0,0,0);
        acc2[i][dt]=__builtin_amdgcn_mfma_f32_16x16x32_bf16(a1,*(short8*)&Vb[cur*4096+(dt*2+1)*512+l*8],acc2[i][dt],0,0,0);
      }
    }
    if(c<7 && t<64) dgb[nxt*64+t]=dgnv;
    __syncthreads();
  }
  {
    float* OUT=(float*)SM;
#pragma unroll
    for(int i=0;i<4;++i){
      const int mb=(w*4+i)*16+(l>>4)*4;
#pragma unroll
      for(int dt=0;dt<4;++dt){
        const int d=dt*16+lrow;
        float4 o; o.x=acc2[i][dt][0]; o.y=acc2[i][dt][1]; o.z=acc2[i][dt][2]; o.w=acc2[i][dt][3];
        *(float4*)((char*)OUT + d*1024 + ((mb*4)^((d&15)<<4))) = o;
      }
    }
    __syncthreads();
    float* gout = ctxP + (size_t)(split*BH+bh)*64*256;
#pragma unroll
    for(int s=0;s<16;++s){
      const int d=s*4+w;
      const uint4 o4=*(const uint4*)((char*)OUT + d*1024 + ((l*16)^((d&15)<<4)));
      *(uint4*)(gout + (size_t)d*256 + l*4)=o4;
    }
    ksumP[(size_t)(split*BH+bh)*256 + t]=ksr;
  }
}

// ---------------- K3b (fallback small path) ----------------------------------
__global__ __launch_bounds__(256) void k_csplit(const float* __restrict__ ctxT,
    u16* __restrict__ chi, u16* __restrict__ clo, float* __restrict__ ecs)
{
  __shared__ float cred[256];
  const int bh=blockIdx.x, t=threadIdx.x;
  const int d=t>>2, part=t&3;
  const size_t base=((size_t)bh*DH+d)*MF + part*64;
  const float* src=ctxT + base;
  u16* ph=chi + base;
  u16* pl=clo + base;
  float cs=0.f;
  for(int m=0;m<64;m+=4){
    float4 v=*(const float4*)(src+m);
    float vv[4]={v.x,v.y,v.z,v.w};
    u32 h_[4], l_[4];
#pragma unroll
    for(int j=0;j<4;++j){
      cs+=vv[j];
      u32 hh=f2b(vv[j]);
      float rr=vv[j]-b2f(hh);
      h_[j]=hh; l_[j]=f2b(rr);
    }
    uint2 sh, sl;
    sh.x=h_[0]|(h_[1]<<16); sh.y=h_[2]|(h_[3]<<16);
    sl.x=l_[0]|(l_[1]<<16); sl.y=l_[2]|(l_[3]<<16);
    *(uint2*)(ph+m)=sh; *(uint2*)(pl+m)=sl;
  }
  cred[t]=cs; __syncthreads();
  if(part==0) ecs[bh*64+d]=EPSV*(cred[t]+cred[t+1]+cred[t+2]+cred[t+3]);
}

// ---------------- K3c: reduce 4 split partials -> chi/clo/ecs/ksum -----------
__global__ __launch_bounds__(256) void k_csplit3(const float* __restrict__ ctxP,
    const float* __restrict__ ksumP,
    u16* __restrict__ chi, u16* __restrict__ clo, float* __restrict__ ecs,
    float* __restrict__ ksum)
{
  __shared__ float wred[16][4];
  const int bh=blockIdx.y, dq=blockIdx.x;
  const int t=threadIdx.x, l=t&63, w=t>>6;
  if(dq==0){
    float kv=0.f;
#pragma unroll
    for(int s=0;s<4;++s) kv+=ksumP[(size_t)(s*BH+bh)*256+t];
    ksum[bh*MF+t]=kv;
  }
#pragma unroll
  for(int d16=0;d16<16;++d16){
    const int d=dq*16+d16;
    float v=0.f;
#pragma unroll
    for(int s=0;s<4;++s) v+=ctxP[((size_t)(s*BH+bh)*64+d)*256+t];
    const u32 hh=f2b(v);
    const float rr=v-b2f(hh);
    const size_t ob=((size_t)bh*DH+d)*MF+t;
    chi[ob]=(u16)hh; clo[ob]=(u16)f2b(rr);
    float s_=v;
    s_+=__shfl_xor(s_,1,64); s_+=__shfl_xor(s_,2,64); s_+=__shfl_xor(s_,4,64);
    s_+=__shfl_xor(s_,8,64); s_+=__shfl_xor(s_,16,64); s_+=__shfl_xor(s_,32,64);
    if(l==0) wred[d16][w]=s_;
  }
  __syncthreads();
  if(t<16) ecs[bh*64+dq*16+t]=EPSV*(wred[t][0]+wred[t][1]+wred[t][2]+wred[t][3]);
}

// ---------------- K4: MFMA fused qp + D_inv + attn ---------------------------
__global__ __launch_bounds__(256) void k_attn2(const u16* __restrict__ qb,
    const u16* __restrict__ pn, const float* __restrict__ dqbuf,
    const float* __restrict__ ksum, const u16* __restrict__ chi, const u16* __restrict__ clo,
    const float* __restrict__ ecs, u16* __restrict__ attn)
{
  __shared__ short At[8*512];
  __shared__ u16 Qf[32*512];
  __shared__ float ksums[256];
  __shared__ float dq_s[64];
  __shared__ float mxs[4][64];
  __shared__ float s1s[4][64];
  __shared__ float a_s[64], dinv_s[64], ec_s[64];
  __shared__ float red4[4];
  __shared__ float epkss;
  const int t=threadIdx.x, l=t&63, w=t>>6;
  const int bh=blockIdx.y, nb0=blockIdx.x*256;
  const int b_=bh/HN, h=bh%HN;
  {
    float kv=ksum[bh*MF+t];
    ksums[t]=kv;
    if(t<64) ec_s[t]=ecs[bh*64+t];
    float s=kv;
#pragma unroll
    for(int o=1;o<64;o<<=1) s+=__shfl_xor(s,o,64);
    if(l==0) red4[w]=s;
  }
  __syncthreads();
  if(t==0) epkss=EPSV*(red4[0]+red4[1]+red4[2]+red4[3]);
  short8 bhf[8], blf[8];
  {
    const int d=w*16+(l&15);
    const size_t base=((size_t)bh*DH+d)*MF;
#pragma unroll
    for(int kc=0;kc<8;++kc){
      const size_t off=base + kc*32+(l>>4)*8;
      bhf[kc]=*(const short8*)(chi+off);
      blf[kc]=*(const short8*)(clo+off);
    }
  }
  for(int c=0;c<4;++c){
    const int n0c=nb0+c*64;
    __syncthreads();
    for(int s=t;s<512;s+=256){
      const int ua=s>>6, l2=s&63, nt=ua>>1, kh=ua&1;
      const int n=n0c+nt*16+(l2&15), kc=kh*32+(l2>>4)*8;
      *(uint4*)&At[ua*512+l2*8]=*(const uint4*)(qb + ((size_t)bh*NS+n)*DH + kc);
    }
    if(t<64) dq_s[t]=dqbuf[(size_t)bh*NS+n0c+t];
    __syncthreads();
    float mxl[4]={-3.4e38f,-3.4e38f,-3.4e38f,-3.4e38f};
    float s1l[4]={0.f,0.f,0.f,0.f};
#pragma unroll
    for(int mt=0;mt<4;++mt){
      const int gm=w*4+mt;
      const u16* pr=pn + ((gm*16+(l&15))<<6) + (l>>4)*8;
      const short8 a0=*(const short8*)(pr);
      const short8 a1=*(const short8*)(pr+32);
      float k4[4];
#pragma unroll
      for(int r=0;r<4;++r) k4[r]=ksums[gm*16+(l>>4)*4+r];
      const int mbase=(gm&1)*16+(l>>4)*4;
      const int lane2=((mbase>>3)*16+(l&15))*8 + (mbase&7);
#pragma unroll
      for(int nt=0;nt<4;++nt){
        floatx4 xp={};
        xp=__builtin_amdgcn_mfma_f32_16x16x32_bf16(a0,*(short8*)&At[(nt*2+0)*512+l*8],xp,0,0,0);
        xp=__builtin_amdgcn_mfma_f32_16x16x32_bf16(a1,*(short8*)&At[(nt*2+1)*512+l*8],xp,0,0,0);
        const float dq=dq_s[nt*16+(l&15)];
        float ev[4];
#pragma unroll
        for(int r=0;r<4;++r){
          const float xv=xp[r];
          mxl[nt]=fmaxf(mxl[nt],xv);
          ev[r]=__expf(xv-dq);
          s1l[nt]+=ev[r]*k4[r];
        }
        u16* qp_=&Qf[(nt*8+(gm>>1))*512 + lane2];
        *(u32*)qp_    =f2b(ev[0])|(f2b(ev[1])<<16);
        *(u32*)(qp_+2)=f2b(ev[2])|(f2b(ev[3])<<16);
      }
    }
#pragma unroll
    for(int nt=0;nt<4;++nt){
      float m_=mxl[nt], s_=s1l[nt];
      m_=fmaxf(m_,__shfl_xor(m_,16,64)); s_+=__shfl_xor(s_,16,64);
      m_=fmaxf(m_,__shfl_xor(m_,32,64)); s_+=__shfl_xor(s_,32,64);
      if(l<16){ mxs[w][nt*16+l]=m_; s1s[w][nt*16+l]=s_; }
    }
    __syncthreads();
    if(t<64){
      float m_=fmaxf(fmaxf(mxs[0][t],mxs[1][t]),fmaxf(mxs[2][t],mxs[3][t]));
      float s_=s1s[0][t]+s1s[1][t]+s1s[2][t]+s1s[3][t];
      float a=__expf(-m_);
      a_s[t]=a;
      dinv_s[t]=1.0f/(a*s_+epkss);
    }
    __syncthreads();
    const int d=w*16+(l&15);
    const float ec=ec_s[d];
#pragma unroll
    for(int nt=0;nt<4;++nt){
      floatx4 y={};
#pragma unroll
      for(int kc=0;kc<8;++kc){
        const short8 e=*(short8*)&Qf[(nt*8+kc)*512+l*8];
        y=__builtin_amdgcn_mfma_f32_16x16x32_bf16(e,bhf[kc],y,0,0,0);
        y=__builtin_amdgcn_mfma_f32_16x16x32_bf16(e,blf[kc],y,0,0,0);
      }
#pragma unroll
      for(int r=0;r<4;++r){
        const int nl=nt*16+(l>>4)*4+r;
        const float val=(a_s[nl]*y[r]+ec)*dinv_s[nl];
        attn[((size_t)(b_*NS+n0c+nl))*DM + h*DH + d]=(u16)f2b(val);
      }
    }
  }
}

extern "C" void kernel_launch(void* const* d_in, const int* in_sizes, int n_in,
                              void* d_out, int out_size, void* d_ws, size_t ws_size,
                              hipStream_t stream)
{
  (void)in_sizes; (void)n_in; (void)out_size;
  const void* x =d_in[0];
  const void* Wq=d_in[1]; const void* bq=d_in[2];
  const void* Wk=d_in[3]; const void* bk=d_in[4];
  const void* Wv=d_in[5]; const void* bv=d_in[6];
  const void* Wo=d_in[7]; const void* bo=d_in[8];
  const void* proj=d_in[9];

  char* ws=(char*)d_ws;
  const size_t SZ=(size_t)BN*DM*2;               // 25,165,824 B
  const size_t AUXSZ=19030528;
  const bool big = ws_size >= 4*SZ + AUXSZ;      // ~119.7 MB
  u16*   qb  =(u16*)(ws);
  u16*   kb  =(u16*)(ws+SZ);
  u16*   vb  =(u16*)(ws+2*SZ);                   // v^T [bh][d][n]
  u16*   xb  =(u16*)(ws+3*SZ);                   // bf16 x (big path only)
  char*  aux = big ? (ws+4*SZ) : (ws+3*SZ);
  u16*   wb   =(u16*)(aux);                      // 3,538,944
  u16*   wob  =(u16*)(aux+3538944);              // -> 4,718,592
  float* ctxT =(float*)(aux+4718592);            // -> 11,010,048
  float* ksum =(float*)(aux+11010048);           // -> 11,108,352
  u32*   kmax =(u32*)(aux+11108352);             // -> 11,108,736
  int*   flag =(int*)(aux+11108736);             // -> 11,108,864
  float* dk   =(float*)(aux+11108864);           // -> 11,895,296
  float* dqq  =(float*)(aux+11895296);           // -> 12,681,728
  u16*   pn   =(u16*)(aux+12681728);             // -> 12,714,496
  u16*   chi  =(u16*)(aux+12714496);             // -> 15,860,224
  u16*   clo  =(u16*)(aux+15860224);             // -> 19,005,952
  float* ecs  =(float*)(aux+19005952);           // -> 19,030,528
  u16*   attnb = big ? xb : kb;                  // dead buffer reuse

  k_detect<<<1,64,0,stream>>>((const u16*)x, flag);
  if(big) hipMemsetAsync(kmax, 0, 384, stream);
  else    hipMemsetAsync(ctxT, 0, 6291456+98304+384, stream);
  k_cvtw <<<1152, 256, 0, stream>>>(Wq,Wk,Wv,Wo,wb,wob,flag);
  k_cvtp <<<8, 256, 0, stream>>>(proj, pn, flag);
  if(big){
    k_cvtx <<<(BN*DM)/2048, 256, 0, stream>>>(x, xb, flag);
    k_gemm9<<<dim3(64,18), 512, 0, stream>>>(xb, wb, bq,bk,bv, qb,kb,vb, nullptr, flag, 0, dqq, dk);
  }else{
    k_gemm_f<<<dim3(BN/128,2304/128), 256, 0, stream>>>(x, wb, bq,bk,bv, qb,kb,vb, nullptr, flag, 0);
    k_diag <<<(BH*NS)/256, 256, 0, stream>>>(kb, dk);
    k_diag <<<(BH*NS)/256, 256, 0, stream>>>(qb, dqq);
  }
  k_xpk2 <<<dim3(NS/256,BH), 256, 0, stream>>>(kb, pn, kmax);
  if(big){
    float* ctxP =(float*)xb;     // xb dead between qkv-gemm and attn2
    float* ksumP=ctxT;           // reuse aux ctxT region
    k_ctx3 <<<dim3(4,BH), 256, 0, stream>>>(kb, vb, pn, dk, kmax, ctxP, ksumP);
    k_csplit3<<<dim3(4,BH), 256, 0, stream>>>(ctxP, ksumP, chi, clo, ecs, ksum);
  }else{
    k_ctx2 <<<dim3(4,BH), 256, 0, stream>>>(kb, vb, pn, dk, kmax, ctxT, ksum);
    k_csplit<<<BH, 256, 0, stream>>>(ctxT, chi, clo, ecs);
  }
  k_attn2<<<dim3(NS/256,BH), 256, 0, stream>>>(qb, pn, dqq, ksum, chi, clo, ecs, attnb);
  if(big){
    k_gemm9<<<dim3(64,6), 512, 0, stream>>>(attnb, wob, bo,bo,bo, nullptr,nullptr,nullptr, d_out, flag, 1, nullptr, nullptr);
  }else{
    k_gemm2<<<dim3(BN/128,DM/128), 256, 0, stream>>>(attnb, wob, bo,bo,bo, nullptr,nullptr,nullptr, d_out, flag, 1);
  }
}